// Round 5
// baseline (2764.015 us; speedup 1.0000x reference)
//
#include <hip/hip_runtime.h>
#include <hip/hip_bf16.h>
#include <cstdint>
#include <cstddef>

typedef unsigned short ushortT;
typedef unsigned int uintT;

static constexpr int NN  = 8192;    // total nodes
static constexpr int EE  = 131072;  // edges
static constexpr float SLOPE  = 0.2f;
static constexpr float LN_EPS = 1e-5f;

#define DEVI __device__ __forceinline__

DEVI float red32(float v) {   // sum within 32-lane half
  #pragma unroll
  for (int m = 16; m >= 1; m >>= 1) v += __shfl_xor(v, m, 64);
  return v;
}
DEVI float max32(float v) {
  #pragma unroll
  for (int m = 16; m >= 1; m >>= 1) v = fmaxf(v, __shfl_xor(v, m, 64));
  return v;
}
DEVI float blo(uintT u) { union { uintT i; float f; } c; c.i = u << 16; return c.f; }
DEVI float bhi(uintT u) { union { uintT i; float f; } c; c.i = u & 0xffff0000u; return c.f; }
DEVI float b2f(ushortT u) { union { uintT i; float f; } c; c.i = ((uintT)u) << 16; return c.f; }
DEVI ushortT f2bu(float f) {
  __hip_bfloat16 h = __float2bfloat16(f);
  return *reinterpret_cast<ushortT*>(&h);
}
DEVI void storeC(float* p, float v) { *p = v; }
DEVI void storeC(ushortT* p, float v) { *p = f2bu(v); }

// ---------------------------------------------------------------------------
// FC: gh[n] = feat_t[n] @ Wfc_t + bfc_t ; out[n,0:256] = l2n(gh[n])
// ---------------------------------------------------------------------------
__global__ __launch_bounds__(256) void fc_kernel(
    const float* __restrict__ f0, const float* __restrict__ f1,
    const float* __restrict__ f2, const float* __restrict__ f3,
    const float* __restrict__ w0, const float* __restrict__ w1,
    const float* __restrict__ w2, const float* __restrict__ w3,
    const float* __restrict__ b0, const float* __restrict__ b1,
    const float* __restrict__ b2, const float* __restrict__ b3,
    float* __restrict__ gh, float* __restrict__ out)
{
  const int nb = blockIdx.x * 32;
  const int t  = threadIdx.x;
  int base, D;
  const float *F, *W, *Bv;
  if (nb < 4096)      { base = 0;    D = 128; F = f0; W = w0; Bv = b0; }
  else if (nb < 6144) { base = 4096; D = 64;  F = f1; W = w1; Bv = b1; }
  else if (nb < 7168) { base = 6144; D = 32;  F = f2; W = w2; Bv = b2; }
  else                { base = 7168; D = 16;  F = f3; W = w3; Bv = b3; }

  __shared__ float Fs[32 * 128];
  __shared__ float red[32][4];
  __shared__ float nrm[32];

  const int total = 32 * D;
  for (int i = t; i < total; i += 256) Fs[i] = F[(size_t)(nb - base) * D + i];
  __syncthreads();

  float acc[32];
  #pragma unroll
  for (int r = 0; r < 32; ++r) acc[r] = Bv[t];
  for (int d = 0; d < D; ++d) {
    float w = W[(size_t)d * 256 + t];
    #pragma unroll
    for (int r = 0; r < 32; ++r) acc[r] = fmaf(Fs[r * D + d], w, acc[r]);
  }

  const int lane = t & 63, wid = t >> 6;
  #pragma unroll
  for (int r = 0; r < 32; ++r) {
    float v = acc[r] * acc[r];
    for (int o = 32; o > 0; o >>= 1) v += __shfl_down(v, o, 64);
    if (lane == 0) red[r][wid] = v;
  }
  __syncthreads();
  if (t < 32) {
    float s = red[t][0] + red[t][1] + red[t][2] + red[t][3];
    nrm[t] = 1.0f / fmaxf(sqrtf(s), 1e-12f);
  }
  __syncthreads();
  #pragma unroll
  for (int r = 0; r < 32; ++r) {
    gh[(size_t)(nb + r) * 256 + t]  = acc[r];
    out[(size_t)(nb + r) * 768 + t] = acc[r] * nrm[r];
  }
}

// ---------------------------------------------------------------------------
// degree / CSR build
// ---------------------------------------------------------------------------
__global__ __launch_bounds__(256) void zero_counts(int* outc, int* inc) {
  int g = blockIdx.x * 256 + threadIdx.x;
  if (g < NN) outc[g] = 0; else inc[g - NN] = 0;
}
__global__ __launch_bounds__(256) void count_deg(const int* __restrict__ src,
                                                 const int* __restrict__ dst,
                                                 int* outc, int* inc) {
  int g = blockIdx.x * 256 + threadIdx.x;
  atomicAdd(&outc[src[g]], 1);
  atomicAdd(&inc[dst[g]], 1);
}
__global__ __launch_bounds__(256) void norm_kernel(const int* __restrict__ outc,
                                                   const int* __restrict__ inc,
                                                   float* n_out, float* n_in) {
  int g = blockIdx.x * 256 + threadIdx.x;
  n_out[g] = rsqrtf((float)outc[g] + 1.0f);
  n_in[g]  = rsqrtf((float)inc[g] + 1.0f);
}
__global__ __launch_bounds__(1024) void scan_kernel(const int* __restrict__ inc,
                                                    int* __restrict__ offs) {
  __shared__ int sums[1024];
  const int t = threadIdx.x;
  int x[8];
  const int base = t * 8;
  int s = 0;
  #pragma unroll
  for (int i = 0; i < 8; ++i) { int v = inc[base + i] + 1; x[i] = s; s += v; }
  sums[t] = s;
  __syncthreads();
  for (int off = 1; off < 1024; off <<= 1) {
    int a = (t >= off) ? sums[t - off] : 0;
    __syncthreads();
    sums[t] += a;
    __syncthreads();
  }
  const int pre = (t > 0) ? sums[t - 1] : 0;
  #pragma unroll
  for (int i = 0; i < 8; ++i) offs[base + i] = pre + x[i];
  if (t == 1023) offs[NN] = sums[1023];
}
__global__ __launch_bounds__(256) void copy_cur(const int* __restrict__ offs, int* cur) {
  int g = blockIdx.x * 256 + threadIdx.x;
  cur[g] = offs[g];
}
__global__ __launch_bounds__(256) void fill_csr(const int* __restrict__ src,
                                                const int* __restrict__ dst,
                                                int* cur, int* __restrict__ csr) {
  int g = blockIdx.x * 256 + threadIdx.x;   // EE + NN total
  int s, d;
  if (g < EE) { s = src[g]; d = dst[g]; }
  else        { s = g - EE; d = g - EE; }   // self-loops
  int pos = atomicAdd(&cur[d], 1);
  csr[pos] = s;
}
__global__ __launch_bounds__(256) void init_R(const float* __restrict__ type_emb,
                                              const int* __restrict__ nt,
                                              float* __restrict__ R) {
  int g = blockIdx.x * 256 + threadIdx.x;   // NN*4
  int n = g >> 2, c = g & 3;
  R[g] = type_emb[nt[n] * 4 + c];
}

// ---------------------------------------------------------------------------
// [M,256] @ [256,256] f32 register-tiled GEMM, 64x64 tile, 256 thr.
// ---------------------------------------------------------------------------
template<bool ROWSCALE, bool STORE, bool RED, typename CT>
__global__ __launch_bounds__(256) void gemm64_kernel(
    const float* __restrict__ A,
    const float* __restrict__ W,
    const float* __restrict__ rowscale,
    CT* __restrict__ C,
    const float* __restrict__ avec,
    float* __restrict__ SSo)
{
  const int m0 = blockIdx.x * 64;
  const int n0 = blockIdx.y * 64;
  const int t  = threadIdx.x;
  const int tr = t & 15, tc = t >> 4;
  __shared__ alignas(16) float As[32][68];
  __shared__ alignas(16) float Bs[32][68];
  __shared__ float red[64][2];
  float acc[4][4] = {};

  for (int ks = 0; ks < 8; ++ks) {
    const int k0 = ks * 32;
    #pragma unroll
    for (int rep = 0; rep < 8; ++rep) {
      int flat = rep * 256 + t;
      int r = flat >> 5, c = flat & 31;
      As[c][r] = A[(size_t)(m0 + r) * 256 + (k0 + c)];
      int rb = flat >> 6, cb = flat & 63;
      Bs[rb][cb] = W[(size_t)(k0 + rb) * 256 + (n0 + cb)];
    }
    __syncthreads();
    #pragma unroll
    for (int k = 0; k < 32; ++k) {
      const float4 a4 = *reinterpret_cast<const float4*>(&As[k][tr * 4]);
      const float4 b4 = *reinterpret_cast<const float4*>(&Bs[k][tc * 4]);
      const float av[4] = {a4.x, a4.y, a4.z, a4.w};
      const float bv[4] = {b4.x, b4.y, b4.z, b4.w};
      #pragma unroll
      for (int u = 0; u < 4; ++u)
        #pragma unroll
        for (int v = 0; v < 4; ++v)
          acc[u][v] = fmaf(av[u], bv[v], acc[u][v]);
    }
    __syncthreads();
  }

  if constexpr (ROWSCALE) {
    #pragma unroll
    for (int u = 0; u < 4; ++u) {
      float s = rowscale[m0 + tr * 4 + u];
      #pragma unroll
      for (int v = 0; v < 4; ++v) acc[u][v] *= s;
    }
  }
  if constexpr (STORE) {
    #pragma unroll
    for (int u = 0; u < 4; ++u) {
      size_t row = (size_t)(m0 + tr * 4 + u);
      #pragma unroll
      for (int v = 0; v < 4; ++v)
        storeC(&C[row * 256 + (n0 + tc * 4 + v)], acc[u][v]);
    }
  }
  if constexpr (RED) {
    if (t < 128) red[t >> 1][t & 1] = 0.f;
    __syncthreads();
    #pragma unroll
    for (int u = 0; u < 4; ++u) {
      float s = 0.f;
      #pragma unroll
      for (int v = 0; v < 4; ++v) {
        float x = acc[u][v];
        float lr = x > 0.f ? x : SLOPE * x;
        s += lr * avec[(tc * 4 + v) & 31];
      }
      atomicAdd(&red[tr * 4 + u][tc >> 3], s);
    }
    __syncthreads();
    if (t < 128) {
      int r = t >> 1, hh = t & 1;
      SSo[(size_t)(m0 + r) * 8 + blockIdx.y * 2 + hh] = red[r][hh];
    }
  }
}

// ---------------------------------------------------------------------------
// GCN aggregate / REConv / RKQ
// ---------------------------------------------------------------------------
__global__ __launch_bounds__(256) void agg_kernel(
    const int* __restrict__ offs, const int* __restrict__ csr,
    const float* __restrict__ X, const float* __restrict__ n_in,
    const float* __restrict__ bias, float* __restrict__ ghn)
{
  const int n = blockIdx.x, t = threadIdx.x;
  const int s0 = offs[n], s1 = offs[n + 1];
  float acc = 0.f;
  for (int i = s0; i < s1; ++i) acc += X[(size_t)csr[i] * 256 + t];
  ghn[(size_t)n * 256 + t] = fmaxf(fmaf(acc, n_in[n], bias[t]), 0.f);
}
__global__ __launch_bounds__(256) void re_proj(
    const float* __restrict__ R, const float* __restrict__ n_out,
    const float* __restrict__ Wre, const float* __restrict__ wtre,
    const int* __restrict__ nt, float* __restrict__ rtmp)
{
  int g = blockIdx.x * 256 + threadIdx.x;  // NN*4
  int n = g >> 2, j = g & 3;
  float s = 0.f;
  #pragma unroll
  for (int c = 0; c < 4; ++c) s += R[n * 4 + c] * Wre[c * 4 + j];
  rtmp[g] = s * n_out[n] * wtre[nt[n]];
}
__global__ __launch_bounds__(256) void re_agg(
    const int* __restrict__ offs, const int* __restrict__ csr,
    const float* __restrict__ rtmp, const float* __restrict__ n_in,
    const float* __restrict__ bre, float* __restrict__ Rn)
{
  int g = blockIdx.x * 256 + threadIdx.x;  // NN*4
  int n = g >> 2, j = g & 3;
  float a = 0.f;
  for (int i = offs[n]; i < offs[n + 1]; ++i) a += rtmp[csr[i] * 4 + j];
  Rn[g] = fmaxf(fmaf(a, n_in[n], bre[j]), 0.f);
}
__global__ __launch_bounds__(256) void rkq_kernel(
    const float* __restrict__ R, const float* __restrict__ Wrs,
    const float* __restrict__ Wrt, float* __restrict__ RKQ)
{
  int g = blockIdx.x * 256 + threadIdx.x;  // NN*128
  int n = g >> 7, c = g & 127;
  int which = c >> 5, cc = c & 31;
  const float* Wp = (which == 0) ? Wrs : (which == 1) ? Wrt
                   : (which == 2) ? (Wrs + 128) : (Wrt + 128);
  float s = 0.f;
  #pragma unroll
  for (int r = 0; r < 4; ++r) s += R[n * 4 + r] * Wp[r * 32 + cc];
  RKQ[g] = s;
}

// ---------------------------------------------------------------------------
// weight prep: Wg2 = diag(g1)Wr2, Wgl2 = diag(g1)Wl2
// ---------------------------------------------------------------------------
__global__ __launch_bounds__(256) void scale_w_kernel(
    const float* __restrict__ ln_g, const float* __restrict__ Wr2,
    const float* __restrict__ Wl2, float* __restrict__ Wg2,
    float* __restrict__ Wgl2)
{
  int g = blockIdx.x * 256 + threadIdx.x;  // 65536
  float s = ln_g[g >> 8];
  Wg2[g]  = s * Wr2[g];
  Wgl2[g] = s * Wl2[g];
}
// vecs[0]=g1@Wr2, [1]=b1@Wr2, [2]=g1@Wl2, [3]=b1@Wl2
__global__ __launch_bounds__(256) void vec4_kernel(
    const float* __restrict__ ln_g, const float* __restrict__ ln_b,
    const float* __restrict__ Wr2, const float* __restrict__ Wl2,
    float* __restrict__ vecs)
{
  const int which = blockIdx.x, t = threadIdx.x;
  const float* W = (which < 2) ? Wr2 : Wl2;
  const float* s = (which & 1) ? ln_b : ln_g;
  float a = 0.f;
  for (int k = 0; k < 256; ++k) a = fmaf(s[k], W[(size_t)k * 256 + t], a);
  vecs[which * 256 + t] = a;
}

// ---------------------------------------------------------------------------
// MEGA2 v2: phase-split so x and y accumulators are never live together
// (fixes register spill); GW/GW2 share one LDS stage buffer; RQs reused
// for RQ2. ~50 KB LDS -> 3 blocks/CU.
// ---------------------------------------------------------------------------
__global__ __launch_bounds__(256, 3) void mega2_kernel(
    const int* __restrict__ seqs,
    const float* __restrict__ gh,
    const ushortT* __restrict__ GW, const ushortT* __restrict__ GW2,
    const ushortT* __restrict__ GWL, const ushortT* __restrict__ GHG,
    const ushortT* __restrict__ GHL,
    const float* __restrict__ SLg, const float* __restrict__ SRg,
    const float* __restrict__ RKQ,
    const float* __restrict__ vecs,           // v1,v2,vl1,vl2
    const float* __restrict__ al2, const float* __restrict__ ar2,
    const float* __restrict__ ln_g, const float* __restrict__ ln_b,
    float* __restrict__ h1r0buf, float* __restrict__ ctx2buf,
    float* __restrict__ out)
{
  __shared__ int     idx[32];
  __shared__ ushortT GWs[32][264];   // stage: GW, then GW2
  __shared__ ushortT FR2s[32][268];
  __shared__ float SLs[8][32], SRs[8][32];
  __shared__ float RKs[32][36];
  __shared__ float RQs[32][36];      // RQ1, then RQ2
  __shared__ float rk2s[32];
  __shared__ float p1r0[8][32];
  __shared__ float part[32][8];
  __shared__ float mu_s[32], rs_s[32];
  __shared__ float SR2s[8][32];
  __shared__ float sl2s[8];
  __shared__ float scp[8][32];
  __shared__ float h1r0s[256];
  __shared__ float nrm1s;

  const int b = blockIdx.x, t = threadIdx.x;
  const int h8 = t >> 5, lo = t & 31;
  const int c0 = h8 * 32;
  const float* v1  = vecs;
  const float* v2  = vecs + 256;
  const float* vl1 = vecs + 512;
  const float* vl2 = vecs + 768;

  if (t < 32) idx[t] = seqs[b * 32 + t];
  __syncthreads();                                             // B1

  for (int s = 0; s < 32; ++s) GWs[s][t] = GW[(size_t)idx[s] * 256 + t];
  SLs[h8][lo] = SLg[(size_t)idx[lo] * 8 + h8];
  SRs[h8][lo] = SRg[(size_t)idx[lo] * 8 + h8];
  #pragma unroll
  for (int rep = 0; rep < 4; ++rep) {
    int flat = rep * 256 + t, s3 = flat >> 5, c3 = flat & 31;
    RKs[s3][c3] = RKQ[(size_t)idx[s3] * 128 + c3];
    RQs[s3][c3] = RKQ[(size_t)idx[s3] * 128 + 32 + c3];
  }
  if (t < 32) rk2s[t] = RKQ[(size_t)idx[0] * 128 + 64 + t];
  __syncthreads();                                             // B2

  // ---- attn1 scores+softmax: thread = (head h8, query row lo) ----
  float p1[32];
  {
    const float rk0 = RKs[lo][h8 * 4 + 0], rk1 = RKs[lo][h8 * 4 + 1],
                rk2 = RKs[lo][h8 * 4 + 2], rk3 = RKs[lo][h8 * 4 + 3];
    const float sli = SLs[h8][lo];
    float m = -1e30f;
    #pragma unroll
    for (int j = 0; j < 32; ++j) {
      float sc = sli + SRs[h8][j]
               + rk0 * RQs[j][h8 * 4 + 0] + rk1 * RQs[j][h8 * 4 + 1]
               + rk2 * RQs[j][h8 * 4 + 2] + rk3 * RQs[j][h8 * 4 + 3];
      p1[j] = sc; m = fmaxf(m, sc);
    }
    float sum = 0.f;
    #pragma unroll
    for (int j = 0; j < 32; ++j) { p1[j] = __expf(p1[j] - m); sum += p1[j]; }
    const float inv = 1.f / sum;
    #pragma unroll
    for (int j = 0; j < 32; ++j) p1[j] *= inv;
  }
  if (lo == 0) {
    #pragma unroll
    for (int j = 0; j < 32; ++j) p1r0[h8][j] = p1[j];
  }

  // ---- combine x = p1◦GW + gh[idx_lo] ; row-sum partial ----
  float x[32];
  #pragma unroll
  for (int d = 0; d < 32; ++d) x[d] = 0.f;
  #pragma unroll
  for (int j = 0; j < 32; ++j) {
    const float pj = p1[j];
    const uintT* rx = reinterpret_cast<const uintT*>(&GWs[j][c0]);
    #pragma unroll
    for (int q = 0; q < 16; ++q) {
      const uintT ax = rx[q];
      x[2 * q + 0] = fmaf(pj, blo(ax), x[2 * q + 0]);
      x[2 * q + 1] = fmaf(pj, bhi(ax), x[2 * q + 1]);
    }
  }
  {
    const float* gp = &gh[(size_t)idx[lo] * 256 + c0];
    #pragma unroll
    for (int d = 0; d < 32; ++d) x[d] += gp[d];
  }
  {
    float s = 0.f;
    #pragma unroll
    for (int d = 0; d < 32; ++d) s += x[d];
    part[lo][h8] = s;
  }
  __syncthreads();                                             // B3

  if (t < 32) {
    float m = 0.f;
    #pragma unroll
    for (int h = 0; h < 8; ++h) m += part[t][h];
    mu_s[t] = m * (1.f / 256.f);
  }
  __syncthreads();                                             // B4

  // ---- stage GW2 into GWs, RQ2 into RQs; var partial from x ----
  for (int s = 0; s < 32; ++s) GWs[s][t] = GW2[(size_t)idx[s] * 256 + t];
  #pragma unroll
  for (int rep = 0; rep < 4; ++rep) {
    int flat = rep * 256 + t, s3 = flat >> 5, c3 = flat & 31;
    RQs[s3][c3] = RKQ[(size_t)idx[s3] * 128 + 96 + c3];
  }
  const float mu = mu_s[lo];
  {
    float v = 0.f;
    #pragma unroll
    for (int d = 0; d < 32; ++d) { float dd = x[d] - mu; v += dd * dd; }
    part[lo][h8] = v;
  }
  __syncthreads();                                             // B5

  if (t < 32) {
    float m = 0.f;
    #pragma unroll
    for (int h = 0; h < 8; ++h) m += part[t][h];
    rs_s[t] = rsqrtf(m * (1.f / 256.f) + LN_EPS);
  }
  __syncthreads();                                             // B6

  const float rs = rs_s[lo];
  const float rm = rs * mu;

  // ---- h1 row 0 (LN) from x; then x dies ----
  if (lo == 0) {
    float sq = 0.f;
    #pragma unroll
    for (int d = 0; d < 32; ++d) {
      const int c = c0 + d;
      float hv = fmaf((x[d] - mu) * rs, ln_g[c], ln_b[c]);
      h1r0s[c] = hv;
      h1r0buf[(size_t)b * 256 + c] = hv;
      sq += hv * hv;
    }
    part[0][h8] = sq;
  }

  // ---- combine y = p1◦GW2 + GHG[idx_lo] (x no longer live) ----
  float y[32];
  #pragma unroll
  for (int d = 0; d < 32; ++d) y[d] = 0.f;
  #pragma unroll
  for (int j = 0; j < 32; ++j) {
    const float pj = p1[j];
    const uintT* ry = reinterpret_cast<const uintT*>(&GWs[j][c0]);
    #pragma unroll
    for (int q = 0; q < 16; ++q) {
      const uintT ay = ry[q];
      y[2 * q + 0] = fmaf(pj, blo(ay), y[2 * q + 0]);
      y[2 * q + 1] = fmaf(pj, bhi(ay), y[2 * q + 1]);
    }
  }
  {
    const ushortT* hp = &GHG[(size_t)idx[lo] * 256 + c0];
    #pragma unroll
    for (int d = 0; d < 32; ++d) y[d] += b2f(hp[d]);
  }

  // ---- FR2 (bf16 to LDS) + SR2 per (head,row) ----
  {
    float sr2 = 0.f;
    uintT* fw = reinterpret_cast<uintT*>(&FR2s[lo][0]) + (c0 >> 1);
    #pragma unroll
    for (int q = 0; q < 16; ++q) {
      const int c = c0 + 2 * q;
      float fa = fmaf(rs, y[2 * q + 0], fmaf(-rm, v1[c],     v2[c]));
      float fb = fmaf(rs, y[2 * q + 1], fmaf(-rm, v1[c + 1], v2[c + 1]));
      fw[q] = (uintT)f2bu(fa) | ((uintT)f2bu(fb) << 16);
      float la = fa > 0.f ? fa : SLOPE * fa;
      float lb = fb > 0.f ? fb : SLOPE * fb;
      sr2 = fmaf(la, ar2[2 * q], fmaf(lb, ar2[2 * q + 1], sr2));
    }
    SR2s[h8][lo] = sr2;
  }

  // ---- fl2 row0 via tables: z0 = p1r0◦GWL + GHL[idx0] ; sl2 per head ----
  {
    float z0 = 0.f;
    #pragma unroll 8
    for (int j = 0; j < 32; ++j)
      z0 = fmaf(p1r0[h8][j], b2f(GWL[(size_t)idx[j] * 256 + t]), z0);
    z0 += b2f(GHL[(size_t)idx[0] * 256 + t]);
    const float rs0 = rs_s[0], rm0 = rs_s[0] * mu_s[0];
    float fl = fmaf(rs0, z0, fmaf(-rm0, vl1[t], vl2[t]));
    float lr = (fl > 0.f ? fl : SLOPE * fl) * al2[lo];
    lr = red32(lr);
    if (lo == 0) sl2s[h8] = lr;
  }
  __syncthreads();                                             // B7

  // ---- attn2 row0 scores (thread = (h8, key lo)); t==0: ret1 norm ----
  if (t == 0) {
    float s = 0.f;
    #pragma unroll
    for (int h = 0; h < 8; ++h) s += part[0][h];
    nrm1s = 1.f / fmaxf(sqrtf(s), 1e-12f);
  }
  {
    float s2 = sl2s[h8] + SR2s[h8][lo]
             + rk2s[h8 * 4 + 0] * RQs[lo][h8 * 4 + 0]
             + rk2s[h8 * 4 + 1] * RQs[lo][h8 * 4 + 1]
             + rk2s[h8 * 4 + 2] * RQs[lo][h8 * 4 + 2]
             + rk2s[h8 * 4 + 3] * RQs[lo][h8 * 4 + 3];
    float m2 = max32(s2);
    float e = __expf(s2 - m2);
    float su = red32(e);
    scp[h8][lo] = e / su;
  }
  __syncthreads();                                             // B8

  // ---- ctx2 = p2 ◦ FR2 (thread = col t) ; ret1 write ----
  {
    float a = 0.f;
    #pragma unroll
    for (int j = 0; j < 32; ++j) a = fmaf(scp[h8][j], b2f(FR2s[j][t]), a);
    ctx2buf[(size_t)b * 256 + t] = a;
  }
  out[(size_t)b * 768 + 256 + t] = h1r0s[t] * nrm1s;
}

// ---------------------------------------------------------------------------
// Epilogue: ret2 = l2n(LN(h1row0 + ctx2 @ Wfin2))  — 64 rows/block
// ---------------------------------------------------------------------------
__global__ __launch_bounds__(256) void final_ln_kernel(
    const float* __restrict__ A,       // ctx2buf [8192,256]
    const float* __restrict__ W,       // Wfin2
    const float* __restrict__ res,     // h1r0buf [8192,256]
    const float* __restrict__ lng, const float* __restrict__ lnb,
    float* __restrict__ out)
{
  const int m0 = blockIdx.x * 64;
  const int t  = threadIdx.x;
  const int tr = t & 15, tc = t >> 4;
  __shared__ alignas(16) float As[32][68];
  __shared__ alignas(16) float Bs[32][264];
  __shared__ float red[64][16];
  __shared__ float stat[64];
  float acc[4][16] = {};

  for (int ks = 0; ks < 8; ++ks) {
    const int k0 = ks * 32;
    #pragma unroll
    for (int rep = 0; rep < 8; ++rep) {
      int flat = rep * 256 + t;
      int r = flat >> 5, c = flat & 31;
      As[c][r] = A[(size_t)(m0 + r) * 256 + (k0 + c)];
    }
    #pragma unroll
    for (int rep = 0; rep < 32; ++rep) {
      int flat = rep * 256 + t;
      int rb = flat >> 8, cb = flat & 255;
      Bs[rb][cb] = W[(size_t)(k0 + rb) * 256 + cb];
    }
    __syncthreads();
    #pragma unroll
    for (int k = 0; k < 32; ++k) {
      const float4 a4 = *reinterpret_cast<const float4*>(&As[k][tr * 4]);
      const float av[4] = {a4.x, a4.y, a4.z, a4.w};
      #pragma unroll
      for (int q = 0; q < 4; ++q) {
        const float4 b4 = *reinterpret_cast<const float4*>(&Bs[k][tc * 16 + q * 4]);
        const float bv[4] = {b4.x, b4.y, b4.z, b4.w};
        #pragma unroll
        for (int u = 0; u < 4; ++u)
          #pragma unroll
          for (int v = 0; v < 4; ++v)
            acc[u][q * 4 + v] = fmaf(av[u], bv[v], acc[u][q * 4 + v]);
      }
    }
    __syncthreads();
  }

  int rows[4];
  #pragma unroll
  for (int u = 0; u < 4; ++u) rows[u] = m0 + tr * 4 + u;

  #pragma unroll
  for (int u = 0; u < 4; ++u) {
    const float* rp = &res[(size_t)rows[u] * 256 + tc * 16];
    #pragma unroll
    for (int v = 0; v < 16; ++v) acc[u][v] += rp[v];
  }
  #pragma unroll
  for (int u = 0; u < 4; ++u) {
    float s = 0.f;
    #pragma unroll
    for (int v = 0; v < 16; ++v) s += acc[u][v];
    red[tr * 4 + u][tc] = s;
  }
  __syncthreads();
  if (t < 64) {
    float s = 0.f;
    #pragma unroll
    for (int g = 0; g < 16; ++g) s += red[t][g];
    stat[t] = s * (1.0f / 256.0f);
  }
  __syncthreads();
  float mu[4];
  #pragma unroll
  for (int u = 0; u < 4; ++u) mu[u] = stat[tr * 4 + u];
  #pragma unroll
  for (int u = 0; u < 4; ++u) {
    float s = 0.f;
    #pragma unroll
    for (int v = 0; v < 16; ++v) { float d = acc[u][v] - mu[u]; s += d * d; }
    red[tr * 4 + u][tc] = s;
  }
  __syncthreads();
  if (t < 64) {
    float s = 0.f;
    #pragma unroll
    for (int g = 0; g < 16; ++g) s += red[t][g];
    stat[t] = rsqrtf(s * (1.0f / 256.0f) + LN_EPS);
  }
  __syncthreads();
  float rst[4];
  #pragma unroll
  for (int u = 0; u < 4; ++u) rst[u] = stat[tr * 4 + u];
  #pragma unroll
  for (int u = 0; u < 4; ++u) {
    float s = 0.f;
    #pragma unroll
    for (int v = 0; v < 16; ++v) {
      int col = tc * 16 + v;
      float yv = fmaf((acc[u][v] - mu[u]) * rst[u], lng[col], lnb[col]);
      acc[u][v] = yv;
      s += yv * yv;
    }
    red[tr * 4 + u][tc] = s;
  }
  __syncthreads();
  if (t < 64) {
    float s = 0.f;
    #pragma unroll
    for (int g = 0; g < 16; ++g) s += red[t][g];
    stat[t] = 1.0f / fmaxf(sqrtf(s), 1e-12f);
  }
  __syncthreads();
  #pragma unroll
  for (int u = 0; u < 4; ++u) {
    float rn = stat[tr * 4 + u];
    #pragma unroll
    for (int v = 0; v < 16; ++v)
      out[(size_t)rows[u] * 768 + 512 + tc * 16 + v] = acc[u][v] * rn;
  }
}

// ---------------------------------------------------------------------------
extern "C" void kernel_launch(void* const* d_in, const int* in_sizes, int n_in,
                              void* d_out, int out_size, void* d_ws, size_t ws_size,
                              hipStream_t stream)
{
  (void)in_sizes; (void)n_in; (void)out_size; (void)ws_size;

  const float* feat[4]; const float* wfc[4]; const float* bfc[4];
  for (int i = 0; i < 4; ++i) {
    feat[i] = (const float*)d_in[i * 3 + 0];
    wfc[i]  = (const float*)d_in[i * 3 + 1];
    bfc[i]  = (const float*)d_in[i * 3 + 2];
  }
  const float* type_emb = (const float*)d_in[12];
  const float* Wgcn = (const float*)d_in[13];
  const float* bgcn = (const float*)d_in[14];
  const float* Wre  = (const float*)d_in[15];
  const float* bre  = (const float*)d_in[16];
  const float* wtre = (const float*)d_in[17];
  const float* Wl   = (const float*)d_in[18];
  const float* Wr   = (const float*)d_in[19];
  const float* al   = (const float*)d_in[20];
  const float* ar   = (const float*)d_in[21];
  const float* Wrs  = (const float*)d_in[22];
  const float* Wrt  = (const float*)d_in[23];
  const float* Wfin = (const float*)d_in[24];
  const float* ln_g = (const float*)d_in[25];
  const float* ln_b = (const float*)d_in[26];
  const int* src       = (const int*)d_in[27];
  const int* dst       = (const int*)d_in[28];
  const int* node_type = (const int*)d_in[29];
  const int* seqs      = (const int*)d_in[30];
  float* out = (float*)d_out;

  // workspace carve-up (~50 MB)
  char* p = (char*)d_ws;
  auto take = [&](size_t n) { char* q = p; p += (n + 255) & ~(size_t)255; return q; };
  float* gh    = (float*)take((size_t)NN * 256 * 4);
  float* Xbuf  = (float*)take((size_t)NN * 256 * 4);   // GCN scratch, then ctx2buf
  float* GR1   = (float*)take((size_t)NN * 256 * 4);   // gh@Wr1, then h1r0buf
  float* RKQ   = (float*)take((size_t)NN * 128 * 4);
  float* SLg   = (float*)take((size_t)NN * 8 * 4);
  float* SRg   = (float*)take((size_t)NN * 8 * 4);
  float* n_out = (float*)take((size_t)NN * 4);
  float* n_in_ = (float*)take((size_t)NN * 4);
  int*   outc  = (int*)take((size_t)NN * 4);
  int*   inc   = (int*)take((size_t)NN * 4);
  int*   offs  = (int*)take((size_t)(NN + 1) * 4);
  int*   cur   = (int*)take((size_t)NN * 4);
  int*   csr   = (int*)take((size_t)(EE + NN) * 4);
  float* R     = (float*)take((size_t)NN * 4 * 4);
  float* rtmp  = (float*)take((size_t)NN * 4 * 4);
  ushortT* GW  = (ushortT*)take((size_t)NN * 256 * 2);
  ushortT* GW2 = (ushortT*)take((size_t)NN * 256 * 2);
  ushortT* GWL = (ushortT*)take((size_t)NN * 256 * 2);
  ushortT* GHG = (ushortT*)take((size_t)NN * 256 * 2);
  ushortT* GHL = (ushortT*)take((size_t)NN * 256 * 2);
  float* Wg2   = (float*)take((size_t)65536 * 4);
  float* Wgl2  = (float*)take((size_t)65536 * 4);
  float* Wc2   = (float*)take((size_t)65536 * 4);
  float* Wcl   = (float*)take((size_t)65536 * 4);
  float* vecs  = (float*)take((size_t)4 * 256 * 4);
  float* ctx2buf = Xbuf;   // alias: Xbuf dead after GCN
  float* h1r0buf = GR1;    // alias: GR1 dead after table GEMMs

  const float* Wr2 = Wr + 65536;
  const float* Wl2 = Wl + 65536;

  // 1) FC + ret0
  fc_kernel<<<256, 256, 0, stream>>>(feat[0], feat[1], feat[2], feat[3],
                                     wfc[0], wfc[1], wfc[2], wfc[3],
                                     bfc[0], bfc[1], bfc[2], bfc[3], gh, out);
  // 2) degrees + CSR
  zero_counts<<<64, 256, 0, stream>>>(outc, inc);
  count_deg<<<512, 256, 0, stream>>>(src, dst, outc, inc);
  norm_kernel<<<32, 256, 0, stream>>>(outc, inc, n_out, n_in_);
  scan_kernel<<<1, 1024, 0, stream>>>(inc, offs);
  copy_cur<<<32, 256, 0, stream>>>(offs, cur);
  fill_csr<<<544, 256, 0, stream>>>(src, dst, cur, csr);
  init_R<<<128, 256, 0, stream>>>(type_emb, node_type, R);

  // weight prep (independent of graph work)
  scale_w_kernel<<<256, 256, 0, stream>>>(ln_g, Wr2, Wl2, Wg2, Wgl2);
  vec4_kernel<<<4, 256, 0, stream>>>(ln_g, ln_b, Wr2, Wl2, vecs);
  gemm64_kernel<false, true, false, float>
      <<<dim3(4, 4), 256, 0, stream>>>(Wfin, Wg2, nullptr, Wc2, nullptr, nullptr);
  gemm64_kernel<false, true, false, float>
      <<<dim3(4, 4), 256, 0, stream>>>(Wfin, Wgl2, nullptr, Wcl, nullptr, nullptr);

  // 3) GCN + REConv, K=2
  for (int k = 0; k < 2; ++k) {
    gemm64_kernel<true, true, false, float>
        <<<dim3(128, 4), 256, 0, stream>>>(gh, Wgcn + (size_t)k * 65536,
                                           n_out, Xbuf, nullptr, nullptr);
    agg_kernel<<<NN, 256, 0, stream>>>(offs, csr, Xbuf, n_in_, bgcn + k * 256, gh);
    re_proj<<<128, 256, 0, stream>>>(R, n_out, Wre + k * 16, wtre + k * 4, node_type, rtmp);
    re_agg<<<128, 256, 0, stream>>>(offs, csr, rtmp, n_in_, bre + k * 4, R);
  }

  // 4) attention precomputes + node tables
  rkq_kernel<<<4096, 256, 0, stream>>>(R, Wrs, Wrt, RKQ);
  gemm64_kernel<false, false, true, float>
      <<<dim3(128, 4), 256, 0, stream>>>(gh, Wl, nullptr, (float*)nullptr, al, SLg);
  gemm64_kernel<false, true, true, float>
      <<<dim3(128, 4), 256, 0, stream>>>(gh, Wr, nullptr, GR1, ar, SRg);
  gemm64_kernel<false, true, false, ushortT>
      <<<dim3(128, 4), 256, 0, stream>>>(GR1, Wfin, nullptr, GW, nullptr, nullptr);
  gemm64_kernel<false, true, false, ushortT>
      <<<dim3(128, 4), 256, 0, stream>>>(GR1, Wc2, nullptr, GW2, nullptr, nullptr);
  gemm64_kernel<false, true, false, ushortT>
      <<<dim3(128, 4), 256, 0, stream>>>(GR1, Wcl, nullptr, GWL, nullptr, nullptr);
  gemm64_kernel<false, true, false, ushortT>
      <<<dim3(128, 4), 256, 0, stream>>>(gh, Wg2, nullptr, GHG, nullptr, nullptr);
  gemm64_kernel<false, true, false, ushortT>
      <<<dim3(128, 4), 256, 0, stream>>>(gh, Wgl2, nullptr, GHL, nullptr, nullptr);

  // 5) fused transformer (tables) -> ret1, h1r0, ctx2
  mega2_kernel<<<NN, 256, 0, stream>>>(seqs, gh, GW, GW2, GWL, GHG, GHL,
                                       SLg, SRg, RKQ, vecs,
                                       al + 32, ar + 32, ln_g, ln_b,
                                       h1r0buf, ctx2buf, out);

  // 6) epilogue: ret2 = l2n(LN(h1r0 + ctx2@Wfin2))
  final_ln_kernel<<<128, 256, 0, stream>>>(ctx2buf, Wfin + 65536, h1r0buf,
                                           ln_g + 256, ln_b + 256, out);
}

// Round 6
// 774.316 us; speedup vs baseline: 3.5696x; 3.5696x over previous
//
#include <hip/hip_runtime.h>
#include <hip/hip_bf16.h>
#include <cstdint>
#include <cstddef>

typedef unsigned short ushortT;
typedef unsigned int uintT;

static constexpr int NN  = 8192;    // total nodes
static constexpr int EE  = 131072;  // edges
static constexpr float SLOPE  = 0.2f;
static constexpr float LN_EPS = 1e-5f;

#define DEVI __device__ __forceinline__

DEVI float red32(float v) {   // sum within 32-lane half
  #pragma unroll
  for (int m = 16; m >= 1; m >>= 1) v += __shfl_xor(v, m, 64);
  return v;
}
DEVI float red64(float v) {   // sum over full wave
  #pragma unroll
  for (int m = 32; m >= 1; m >>= 1) v += __shfl_xor(v, m, 64);
  return v;
}
DEVI float max32(float v) {
  #pragma unroll
  for (int m = 16; m >= 1; m >>= 1) v = fmaxf(v, __shfl_xor(v, m, 64));
  return v;
}
DEVI float blo(uintT u) { union { uintT i; float f; } c; c.i = u << 16; return c.f; }
DEVI float bhi(uintT u) { union { uintT i; float f; } c; c.i = u & 0xffff0000u; return c.f; }
DEVI float b2f(ushortT u) { union { uintT i; float f; } c; c.i = ((uintT)u) << 16; return c.f; }
DEVI ushortT f2bu(float f) {
  __hip_bfloat16 h = __float2bfloat16(f);
  return *reinterpret_cast<ushortT*>(&h);
}
DEVI void storeC(float* p, float v) { *p = v; }
DEVI void storeC(ushortT* p, float v) { *p = f2bu(v); }

// ---------------------------------------------------------------------------
// FC: gh[n] = feat_t[n] @ Wfc_t + bfc_t ; out[n,0:256] = l2n(gh[n])
// ---------------------------------------------------------------------------
__global__ __launch_bounds__(256) void fc_kernel(
    const float* __restrict__ f0, const float* __restrict__ f1,
    const float* __restrict__ f2, const float* __restrict__ f3,
    const float* __restrict__ w0, const float* __restrict__ w1,
    const float* __restrict__ w2, const float* __restrict__ w3,
    const float* __restrict__ b0, const float* __restrict__ b1,
    const float* __restrict__ b2, const float* __restrict__ b3,
    float* __restrict__ gh, float* __restrict__ out)
{
  const int nb = blockIdx.x * 32;
  const int t  = threadIdx.x;
  int base, D;
  const float *F, *W, *Bv;
  if (nb < 4096)      { base = 0;    D = 128; F = f0; W = w0; Bv = b0; }
  else if (nb < 6144) { base = 4096; D = 64;  F = f1; W = w1; Bv = b1; }
  else if (nb < 7168) { base = 6144; D = 32;  F = f2; W = w2; Bv = b2; }
  else                { base = 7168; D = 16;  F = f3; W = w3; Bv = b3; }

  __shared__ float Fs[32 * 128];
  __shared__ float red[32][4];
  __shared__ float nrm[32];

  const int total = 32 * D;
  for (int i = t; i < total; i += 256) Fs[i] = F[(size_t)(nb - base) * D + i];
  __syncthreads();

  float acc[32];
  #pragma unroll
  for (int r = 0; r < 32; ++r) acc[r] = Bv[t];
  for (int d = 0; d < D; ++d) {
    float w = W[(size_t)d * 256 + t];
    #pragma unroll
    for (int r = 0; r < 32; ++r) acc[r] = fmaf(Fs[r * D + d], w, acc[r]);
  }

  const int lane = t & 63, wid = t >> 6;
  #pragma unroll
  for (int r = 0; r < 32; ++r) {
    float v = acc[r] * acc[r];
    for (int o = 32; o > 0; o >>= 1) v += __shfl_down(v, o, 64);
    if (lane == 0) red[r][wid] = v;
  }
  __syncthreads();
  if (t < 32) {
    float s = red[t][0] + red[t][1] + red[t][2] + red[t][3];
    nrm[t] = 1.0f / fmaxf(sqrtf(s), 1e-12f);
  }
  __syncthreads();
  #pragma unroll
  for (int r = 0; r < 32; ++r) {
    gh[(size_t)(nb + r) * 256 + t]  = acc[r];
    out[(size_t)(nb + r) * 768 + t] = acc[r] * nrm[r];
  }
}

// ---------------------------------------------------------------------------
// degree / CSR build
// ---------------------------------------------------------------------------
__global__ __launch_bounds__(256) void zero_counts(int* outc, int* inc) {
  int g = blockIdx.x * 256 + threadIdx.x;
  if (g < NN) outc[g] = 0; else inc[g - NN] = 0;
}
__global__ __launch_bounds__(256) void count_deg(const int* __restrict__ src,
                                                 const int* __restrict__ dst,
                                                 int* outc, int* inc) {
  int g = blockIdx.x * 256 + threadIdx.x;
  atomicAdd(&outc[src[g]], 1);
  atomicAdd(&inc[dst[g]], 1);
}
__global__ __launch_bounds__(256) void norm_kernel(const int* __restrict__ outc,
                                                   const int* __restrict__ inc,
                                                   float* n_out, float* n_in) {
  int g = blockIdx.x * 256 + threadIdx.x;
  n_out[g] = rsqrtf((float)outc[g] + 1.0f);
  n_in[g]  = rsqrtf((float)inc[g] + 1.0f);
}
__global__ __launch_bounds__(1024) void scan_kernel(const int* __restrict__ inc,
                                                    int* __restrict__ offs) {
  __shared__ int sums[1024];
  const int t = threadIdx.x;
  int x[8];
  const int base = t * 8;
  int s = 0;
  #pragma unroll
  for (int i = 0; i < 8; ++i) { int v = inc[base + i] + 1; x[i] = s; s += v; }
  sums[t] = s;
  __syncthreads();
  for (int off = 1; off < 1024; off <<= 1) {
    int a = (t >= off) ? sums[t - off] : 0;
    __syncthreads();
    sums[t] += a;
    __syncthreads();
  }
  const int pre = (t > 0) ? sums[t - 1] : 0;
  #pragma unroll
  for (int i = 0; i < 8; ++i) offs[base + i] = pre + x[i];
  if (t == 1023) offs[NN] = sums[1023];
}
__global__ __launch_bounds__(256) void copy_cur(const int* __restrict__ offs, int* cur) {
  int g = blockIdx.x * 256 + threadIdx.x;
  cur[g] = offs[g];
}
__global__ __launch_bounds__(256) void fill_csr(const int* __restrict__ src,
                                                const int* __restrict__ dst,
                                                int* cur, int* __restrict__ csr) {
  int g = blockIdx.x * 256 + threadIdx.x;   // EE + NN total
  int s, d;
  if (g < EE) { s = src[g]; d = dst[g]; }
  else        { s = g - EE; d = g - EE; }   // self-loops
  int pos = atomicAdd(&cur[d], 1);
  csr[pos] = s;
}
__global__ __launch_bounds__(256) void init_R(const float* __restrict__ type_emb,
                                              const int* __restrict__ nt,
                                              float* __restrict__ R) {
  int g = blockIdx.x * 256 + threadIdx.x;   // NN*4
  int n = g >> 2, c = g & 3;
  R[g] = type_emb[nt[n] * 4 + c];
}

// ---------------------------------------------------------------------------
// [M,256] @ [256,256] f32 register-tiled GEMM, 64x64 tile, 256 thr.
// ---------------------------------------------------------------------------
template<bool ROWSCALE, bool STORE, bool RED, typename CT>
__global__ __launch_bounds__(256) void gemm64_kernel(
    const float* __restrict__ A,
    const float* __restrict__ W,
    const float* __restrict__ rowscale,
    CT* __restrict__ C,
    const float* __restrict__ avec,
    float* __restrict__ SSo)
{
  const int m0 = blockIdx.x * 64;
  const int n0 = blockIdx.y * 64;
  const int t  = threadIdx.x;
  const int tr = t & 15, tc = t >> 4;
  __shared__ alignas(16) float As[32][68];
  __shared__ alignas(16) float Bs[32][68];
  __shared__ float red[64][2];
  float acc[4][4] = {};

  for (int ks = 0; ks < 8; ++ks) {
    const int k0 = ks * 32;
    #pragma unroll
    for (int rep = 0; rep < 8; ++rep) {
      int flat = rep * 256 + t;
      int r = flat >> 5, c = flat & 31;
      As[c][r] = A[(size_t)(m0 + r) * 256 + (k0 + c)];
      int rb = flat >> 6, cb = flat & 63;
      Bs[rb][cb] = W[(size_t)(k0 + rb) * 256 + (n0 + cb)];
    }
    __syncthreads();
    #pragma unroll
    for (int k = 0; k < 32; ++k) {
      const float4 a4 = *reinterpret_cast<const float4*>(&As[k][tr * 4]);
      const float4 b4 = *reinterpret_cast<const float4*>(&Bs[k][tc * 4]);
      const float av[4] = {a4.x, a4.y, a4.z, a4.w};
      const float bv[4] = {b4.x, b4.y, b4.z, b4.w};
      #pragma unroll
      for (int u = 0; u < 4; ++u)
        #pragma unroll
        for (int v = 0; v < 4; ++v)
          acc[u][v] = fmaf(av[u], bv[v], acc[u][v]);
    }
    __syncthreads();
  }

  if constexpr (ROWSCALE) {
    #pragma unroll
    for (int u = 0; u < 4; ++u) {
      float s = rowscale[m0 + tr * 4 + u];
      #pragma unroll
      for (int v = 0; v < 4; ++v) acc[u][v] *= s;
    }
  }
  if constexpr (STORE) {
    #pragma unroll
    for (int u = 0; u < 4; ++u) {
      size_t row = (size_t)(m0 + tr * 4 + u);
      #pragma unroll
      for (int v = 0; v < 4; ++v)
        storeC(&C[row * 256 + (n0 + tc * 4 + v)], acc[u][v]);
    }
  }
  if constexpr (RED) {
    if (t < 128) red[t >> 1][t & 1] = 0.f;
    __syncthreads();
    #pragma unroll
    for (int u = 0; u < 4; ++u) {
      float s = 0.f;
      #pragma unroll
      for (int v = 0; v < 4; ++v) {
        float x = acc[u][v];
        float lr = x > 0.f ? x : SLOPE * x;
        s += lr * avec[(tc * 4 + v) & 31];
      }
      atomicAdd(&red[tr * 4 + u][tc >> 3], s);
    }
    __syncthreads();
    if (t < 128) {
      int r = t >> 1, hh = t & 1;
      SSo[(size_t)(m0 + r) * 8 + blockIdx.y * 2 + hh] = red[r][hh];
    }
  }
}

// ---------------------------------------------------------------------------
// GCN aggregate / REConv / RKQ
// ---------------------------------------------------------------------------
__global__ __launch_bounds__(256) void agg_kernel(
    const int* __restrict__ offs, const int* __restrict__ csr,
    const float* __restrict__ X, const float* __restrict__ n_in,
    const float* __restrict__ bias, float* __restrict__ ghn)
{
  const int n = blockIdx.x, t = threadIdx.x;
  const int s0 = offs[n], s1 = offs[n + 1];
  float acc = 0.f;
  for (int i = s0; i < s1; ++i) acc += X[(size_t)csr[i] * 256 + t];
  ghn[(size_t)n * 256 + t] = fmaxf(fmaf(acc, n_in[n], bias[t]), 0.f);
}
__global__ __launch_bounds__(256) void re_proj(
    const float* __restrict__ R, const float* __restrict__ n_out,
    const float* __restrict__ Wre, const float* __restrict__ wtre,
    const int* __restrict__ nt, float* __restrict__ rtmp)
{
  int g = blockIdx.x * 256 + threadIdx.x;  // NN*4
  int n = g >> 2, j = g & 3;
  float s = 0.f;
  #pragma unroll
  for (int c = 0; c < 4; ++c) s += R[n * 4 + c] * Wre[c * 4 + j];
  rtmp[g] = s * n_out[n] * wtre[nt[n]];
}
__global__ __launch_bounds__(256) void re_agg(
    const int* __restrict__ offs, const int* __restrict__ csr,
    const float* __restrict__ rtmp, const float* __restrict__ n_in,
    const float* __restrict__ bre, float* __restrict__ Rn)
{
  int g = blockIdx.x * 256 + threadIdx.x;  // NN*4
  int n = g >> 2, j = g & 3;
  float a = 0.f;
  for (int i = offs[n]; i < offs[n + 1]; ++i) a += rtmp[csr[i] * 4 + j];
  Rn[g] = fmaxf(fmaf(a, n_in[n], bre[j]), 0.f);
}
__global__ __launch_bounds__(256) void rkq_kernel(
    const float* __restrict__ R, const float* __restrict__ Wrs,
    const float* __restrict__ Wrt, float* __restrict__ RKQ)
{
  int g = blockIdx.x * 256 + threadIdx.x;  // NN*128
  int n = g >> 7, c = g & 127;
  int which = c >> 5, cc = c & 31;
  const float* Wp = (which == 0) ? Wrs : (which == 1) ? Wrt
                   : (which == 2) ? (Wrs + 128) : (Wrt + 128);
  float s = 0.f;
  #pragma unroll
  for (int r = 0; r < 4; ++r) s += R[n * 4 + r] * Wp[r * 32 + cc];
  RKQ[g] = s;
}

// ---------------------------------------------------------------------------
// weight prep: Wg2 = diag(g1)Wr2, Wgl2 = diag(g1)Wl2
// ---------------------------------------------------------------------------
__global__ __launch_bounds__(256) void scale_w_kernel(
    const float* __restrict__ ln_g, const float* __restrict__ Wr2,
    const float* __restrict__ Wl2, float* __restrict__ Wg2,
    float* __restrict__ Wgl2)
{
  int g = blockIdx.x * 256 + threadIdx.x;  // 65536
  float s = ln_g[g >> 8];
  Wg2[g]  = s * Wr2[g];
  Wgl2[g] = s * Wl2[g];
}
// vecs[0]=g1@Wr2, [1]=b1@Wr2, [2]=g1@Wl2, [3]=b1@Wl2
__global__ __launch_bounds__(256) void vec4_kernel(
    const float* __restrict__ ln_g, const float* __restrict__ ln_b,
    const float* __restrict__ Wr2, const float* __restrict__ Wl2,
    float* __restrict__ vecs)
{
  const int which = blockIdx.x, t = threadIdx.x;
  const float* W = (which < 2) ? Wr2 : Wl2;
  const float* s = (which & 1) ? ln_b : ln_g;
  float a = 0.f;
  for (int k = 0; k < 256; ++k) a = fmaf(s[k], W[(size_t)k * 256 + t], a);
  vecs[which * 256 + t] = a;
}

// ---------------------------------------------------------------------------
// MEGA2 v3: chunked accumulation (8 cols at a time) — no 32-wide per-thread
// arrays except p1. x only feeds LN stats (running sum/sumsq) + row 0;
// y converts to bf16 FR2 chunk-by-chunk. No launch-bounds reg cap.
// ---------------------------------------------------------------------------
__global__ __launch_bounds__(256) void mega2_kernel(
    const int* __restrict__ seqs,
    const float* __restrict__ gh,
    const ushortT* __restrict__ GW, const ushortT* __restrict__ GW2,
    const ushortT* __restrict__ GWL, const ushortT* __restrict__ GHG,
    const ushortT* __restrict__ GHL,
    const float* __restrict__ SLg, const float* __restrict__ SRg,
    const float* __restrict__ RKQ,
    const float* __restrict__ vecs,           // v1,v2,vl1,vl2
    const float* __restrict__ al2, const float* __restrict__ ar2,
    const float* __restrict__ ln_g, const float* __restrict__ ln_b,
    float* __restrict__ h1r0buf, float* __restrict__ ctx2buf,
    float* __restrict__ out)
{
  __shared__ int     idx[32];
  __shared__ ushortT GWs[32][264];   // stage: GW, then GW2
  __shared__ ushortT FR2s[32][268];
  __shared__ float SLs[8][32], SRs[8][32];
  __shared__ float RKs[32][36];
  __shared__ float RQs[32][36];      // RQ1, then RQ2
  __shared__ float rk2s[32];
  __shared__ float p1r0[8][32];
  __shared__ float part[32][8], partq[32][8];
  __shared__ float mu_s[32], rs_s[32];
  __shared__ float SR2s[8][32];
  __shared__ float sl2s[8];
  __shared__ float scp[8][32];
  __shared__ float h1r0s[256];
  __shared__ float vs[1024];         // staged vecs
  __shared__ float wred4[4];
  __shared__ float nrm1s;

  const int b = blockIdx.x, t = threadIdx.x;
  const int h8 = t >> 5, lo = t & 31;
  const int c0 = h8 * 32;

  if (t < 32) idx[t] = seqs[b * 32 + t];
  __syncthreads();                                             // B1

  // ---- stage GW (uint-vectorized), SL/SR, RK/RQ1, rk2, vecs ----
  {
    const uintT* GWu = reinterpret_cast<const uintT*>(GW);
    #pragma unroll
    for (int rep = 0; rep < 16; ++rep) {
      int flat = rep * 256 + t;             // 4096 uints
      int r = flat >> 7, c = flat & 127;
      *(reinterpret_cast<uintT*>(&GWs[r][0]) + c) = GWu[(size_t)idx[r] * 128 + c];
    }
  }
  SLs[h8][lo] = SLg[(size_t)idx[lo] * 8 + h8];
  SRs[h8][lo] = SRg[(size_t)idx[lo] * 8 + h8];
  #pragma unroll
  for (int rep = 0; rep < 4; ++rep) {
    int flat = rep * 256 + t, s3 = flat >> 5, c3 = flat & 31;
    RKs[s3][c3] = RKQ[(size_t)idx[s3] * 128 + c3];
    RQs[s3][c3] = RKQ[(size_t)idx[s3] * 128 + 32 + c3];
    vs[flat] = vecs[flat];
  }
  if (t < 32) rk2s[t] = RKQ[(size_t)idx[0] * 128 + 64 + t];
  __syncthreads();                                             // B2

  // ---- attn1 scores+softmax: thread = (head h8, query row lo) ----
  float p1[32];
  {
    const float rk0 = RKs[lo][h8 * 4 + 0], rk1 = RKs[lo][h8 * 4 + 1],
                rk2 = RKs[lo][h8 * 4 + 2], rk3 = RKs[lo][h8 * 4 + 3];
    const float sli = SLs[h8][lo];
    float m = -1e30f;
    #pragma unroll
    for (int j = 0; j < 32; ++j) {
      float sc = sli + SRs[h8][j]
               + rk0 * RQs[j][h8 * 4 + 0] + rk1 * RQs[j][h8 * 4 + 1]
               + rk2 * RQs[j][h8 * 4 + 2] + rk3 * RQs[j][h8 * 4 + 3];
      p1[j] = sc; m = fmaxf(m, sc);
    }
    float sum = 0.f;
    #pragma unroll
    for (int j = 0; j < 32; ++j) { p1[j] = __expf(p1[j] - m); sum += p1[j]; }
    const float inv = 1.f / sum;
    #pragma unroll
    for (int j = 0; j < 32; ++j) p1[j] *= inv;
  }
  if (lo == 0) {
    #pragma unroll
    for (int j = 0; j < 32; ++j) p1r0[h8][j] = p1[j];
  }

  // ---- x phase (chunked): stats only; row 0 stashed pre-LN ----
  {
    float xsum = 0.f, xsq = 0.f;
    const float4* gp4 = reinterpret_cast<const float4*>(&gh[(size_t)idx[lo] * 256 + c0]);
    #pragma unroll
    for (int ch = 0; ch < 4; ++ch) {
      float a[8];
      #pragma unroll
      for (int q = 0; q < 8; ++q) a[q] = 0.f;
      #pragma unroll 8
      for (int j = 0; j < 32; ++j) {
        const float pj = p1[j];
        const uintT* rx = reinterpret_cast<const uintT*>(&GWs[j][c0 + ch * 8]);
        #pragma unroll
        for (int q = 0; q < 4; ++q) {
          const uintT ax = rx[q];
          a[2 * q + 0] = fmaf(pj, blo(ax), a[2 * q + 0]);
          a[2 * q + 1] = fmaf(pj, bhi(ax), a[2 * q + 1]);
        }
      }
      const float4 g0 = gp4[ch * 2], g1 = gp4[ch * 2 + 1];
      a[0] += g0.x; a[1] += g0.y; a[2] += g0.z; a[3] += g0.w;
      a[4] += g1.x; a[5] += g1.y; a[6] += g1.z; a[7] += g1.w;
      #pragma unroll
      for (int q = 0; q < 8; ++q) { xsum += a[q]; xsq = fmaf(a[q], a[q], xsq); }
      if (lo == 0) {
        #pragma unroll
        for (int q = 0; q < 8; ++q) h1r0s[c0 + ch * 8 + q] = a[q];
      }
    }
    part[lo][h8]  = xsum;
    partq[lo][h8] = xsq;
  }
  __syncthreads();                                             // B3

  if (t < 32) {
    float sm = 0.f, sq = 0.f;
    #pragma unroll
    for (int h = 0; h < 8; ++h) { sm += part[t][h]; sq += partq[t][h]; }
    const float m = sm * (1.f / 256.f);
    const float v = fmaxf(sq * (1.f / 256.f) - m * m, 0.f);
    mu_s[t] = m;
    rs_s[t] = rsqrtf(v + LN_EPS);
  }
  __syncthreads();                                             // B4

  // ---- stage GW2 into GWs, RQ2 into RQs; h1 row0 LN + ret1 partials ----
  {
    const uintT* GW2u = reinterpret_cast<const uintT*>(GW2);
    #pragma unroll
    for (int rep = 0; rep < 16; ++rep) {
      int flat = rep * 256 + t;
      int r = flat >> 7, c = flat & 127;
      *(reinterpret_cast<uintT*>(&GWs[r][0]) + c) = GW2u[(size_t)idx[r] * 128 + c];
    }
  }
  #pragma unroll
  for (int rep = 0; rep < 4; ++rep) {
    int flat = rep * 256 + t, s3 = flat >> 5, c3 = flat & 31;
    RQs[s3][c3] = RKQ[(size_t)idx[s3] * 128 + 96 + c3];
  }
  {
    const float mu0 = mu_s[0], rs0 = rs_s[0];
    float hv = fmaf((h1r0s[t] - mu0) * rs0, ln_g[t], ln_b[t]);
    h1r0buf[(size_t)b * 256 + t] = hv;
    float sq = red64(hv * hv);
    h1r0s[t] = hv;                       // own col only; safe overwrite
    if ((t & 63) == 0) wred4[t >> 6] = sq;
  }
  __syncthreads();                                             // B5

  // ---- y phase (chunked): FR2 bf16 + SR2 ----
  {
    const float rs = rs_s[lo];
    const float rm = rs * mu_s[lo];
    float sr2 = 0.f;
    #pragma unroll
    for (int ch = 0; ch < 4; ++ch) {
      float a[8];
      #pragma unroll
      for (int q = 0; q < 8; ++q) a[q] = 0.f;
      #pragma unroll 8
      for (int j = 0; j < 32; ++j) {
        const float pj = p1[j];
        const uintT* ry = reinterpret_cast<const uintT*>(&GWs[j][c0 + ch * 8]);
        #pragma unroll
        for (int q = 0; q < 4; ++q) {
          const uintT ay = ry[q];
          a[2 * q + 0] = fmaf(pj, blo(ay), a[2 * q + 0]);
          a[2 * q + 1] = fmaf(pj, bhi(ay), a[2 * q + 1]);
        }
      }
      const uintT* hg = reinterpret_cast<const uintT*>(&GHG[(size_t)idx[lo] * 256 + c0 + ch * 8]);
      #pragma unroll
      for (int q = 0; q < 4; ++q) {
        const uintT h2 = hg[q];
        a[2 * q + 0] += blo(h2);
        a[2 * q + 1] += bhi(h2);
      }
      uintT* fw = reinterpret_cast<uintT*>(&FR2s[lo][0]) + ((c0 + ch * 8) >> 1);
      #pragma unroll
      for (int q = 0; q < 4; ++q) {
        const int c = c0 + ch * 8 + 2 * q;
        const float fa = fmaf(rs, a[2 * q + 0], fmaf(-rm, vs[c],     vs[256 + c]));
        const float fb = fmaf(rs, a[2 * q + 1], fmaf(-rm, vs[c + 1], vs[256 + c + 1]));
        fw[q] = (uintT)f2bu(fa) | ((uintT)f2bu(fb) << 16);
        const float la = fa > 0.f ? fa : SLOPE * fa;
        const float lb = fb > 0.f ? fb : SLOPE * fb;
        sr2 = fmaf(la, ar2[ch * 8 + 2 * q], fmaf(lb, ar2[ch * 8 + 2 * q + 1], sr2));
      }
    }
    SR2s[h8][lo] = sr2;
  }

  // ---- fl2 row0 via tables: z0 = p1r0◦GWL + GHL[idx0] ; sl2 per head ----
  {
    float z0 = 0.f;
    #pragma unroll 8
    for (int j = 0; j < 32; ++j)
      z0 = fmaf(p1r0[h8][j], b2f(GWL[(size_t)idx[j] * 256 + t]), z0);
    z0 += b2f(GHL[(size_t)idx[0] * 256 + t]);
    const float rs0 = rs_s[0], rm0 = rs_s[0] * mu_s[0];
    const float fl = fmaf(rs0, z0, fmaf(-rm0, vs[512 + t], vs[768 + t]));
    float lr = (fl > 0.f ? fl : SLOPE * fl) * al2[lo];
    lr = red32(lr);
    if (lo == 0) sl2s[h8] = lr;
  }
  if (t == 0) nrm1s = 1.f / fmaxf(sqrtf(wred4[0] + wred4[1] + wred4[2] + wred4[3]), 1e-12f);
  __syncthreads();                                             // B6

  // ---- attn2 row0 scores (thread = (h8, key lo)) ----
  {
    float s2 = sl2s[h8] + SR2s[h8][lo]
             + rk2s[h8 * 4 + 0] * RQs[lo][h8 * 4 + 0]
             + rk2s[h8 * 4 + 1] * RQs[lo][h8 * 4 + 1]
             + rk2s[h8 * 4 + 2] * RQs[lo][h8 * 4 + 2]
             + rk2s[h8 * 4 + 3] * RQs[lo][h8 * 4 + 3];
    const float m2 = max32(s2);
    const float e = __expf(s2 - m2);
    const float su = red32(e);
    scp[h8][lo] = e / su;
  }
  __syncthreads();                                             // B7

  // ---- ctx2 = p2 ◦ FR2 (thread = col t) ; ret1 write ----
  {
    float a = 0.f;
    #pragma unroll
    for (int j = 0; j < 32; ++j) a = fmaf(scp[h8][j], b2f(FR2s[j][t]), a);
    ctx2buf[(size_t)b * 256 + t] = a;
  }
  out[(size_t)b * 768 + 256 + t] = h1r0s[t] * nrm1s;
}

// ---------------------------------------------------------------------------
// Epilogue: ret2 = l2n(LN(h1row0 + ctx2 @ Wfin2))  — 64 rows/block
// ---------------------------------------------------------------------------
__global__ __launch_bounds__(256) void final_ln_kernel(
    const float* __restrict__ A,       // ctx2buf [8192,256]
    const float* __restrict__ W,       // Wfin2
    const float* __restrict__ res,     // h1r0buf [8192,256]
    const float* __restrict__ lng, const float* __restrict__ lnb,
    float* __restrict__ out)
{
  const int m0 = blockIdx.x * 64;
  const int t  = threadIdx.x;
  const int tr = t & 15, tc = t >> 4;
  __shared__ alignas(16) float As[32][68];
  __shared__ alignas(16) float Bs[32][264];
  __shared__ float red[64][16];
  __shared__ float stat[64];
  float acc[4][16] = {};

  for (int ks = 0; ks < 8; ++ks) {
    const int k0 = ks * 32;
    #pragma unroll
    for (int rep = 0; rep < 8; ++rep) {
      int flat = rep * 256 + t;
      int r = flat >> 5, c = flat & 31;
      As[c][r] = A[(size_t)(m0 + r) * 256 + (k0 + c)];
    }
    #pragma unroll
    for (int rep = 0; rep < 32; ++rep) {
      int flat = rep * 256 + t;
      int rb = flat >> 8, cb = flat & 255;
      Bs[rb][cb] = W[(size_t)(k0 + rb) * 256 + cb];
    }
    __syncthreads();
    #pragma unroll
    for (int k = 0; k < 32; ++k) {
      const float4 a4 = *reinterpret_cast<const float4*>(&As[k][tr * 4]);
      const float av[4] = {a4.x, a4.y, a4.z, a4.w};
      #pragma unroll
      for (int q = 0; q < 4; ++q) {
        const float4 b4 = *reinterpret_cast<const float4*>(&Bs[k][tc * 16 + q * 4]);
        const float bv[4] = {b4.x, b4.y, b4.z, b4.w};
        #pragma unroll
        for (int u = 0; u < 4; ++u)
          #pragma unroll
          for (int v = 0; v < 4; ++v)
            acc[u][q * 4 + v] = fmaf(av[u], bv[v], acc[u][q * 4 + v]);
      }
    }
    __syncthreads();
  }

  int rows[4];
  #pragma unroll
  for (int u = 0; u < 4; ++u) rows[u] = m0 + tr * 4 + u;

  #pragma unroll
  for (int u = 0; u < 4; ++u) {
    const float* rp = &res[(size_t)rows[u] * 256 + tc * 16];
    #pragma unroll
    for (int v = 0; v < 16; ++v) acc[u][v] += rp[v];
  }
  #pragma unroll
  for (int u = 0; u < 4; ++u) {
    float s = 0.f;
    #pragma unroll
    for (int v = 0; v < 16; ++v) s += acc[u][v];
    red[tr * 4 + u][tc] = s;
  }
  __syncthreads();
  if (t < 64) {
    float s = 0.f;
    #pragma unroll
    for (int g = 0; g < 16; ++g) s += red[t][g];
    stat[t] = s * (1.0f / 256.0f);
  }
  __syncthreads();
  float mu[4];
  #pragma unroll
  for (int u = 0; u < 4; ++u) mu[u] = stat[tr * 4 + u];
  #pragma unroll
  for (int u = 0; u < 4; ++u) {
    float s = 0.f;
    #pragma unroll
    for (int v = 0; v < 16; ++v) { float d = acc[u][v] - mu[u]; s += d * d; }
    red[tr * 4 + u][tc] = s;
  }
  __syncthreads();
  if (t < 64) {
    float s = 0.f;
    #pragma unroll
    for (int g = 0; g < 16; ++g) s += red[t][g];
    stat[t] = rsqrtf(s * (1.0f / 256.0f) + LN_EPS);
  }
  __syncthreads();
  float rst[4];
  #pragma unroll
  for (int u = 0; u < 4; ++u) rst[u] = stat[tr * 4 + u];
  #pragma unroll
  for (int u = 0; u < 4; ++u) {
    float s = 0.f;
    #pragma unroll
    for (int v = 0; v < 16; ++v) {
      int col = tc * 16 + v;
      float yv = fmaf((acc[u][v] - mu[u]) * rst[u], lng[col], lnb[col]);
      acc[u][v] = yv;
      s += yv * yv;
    }
    red[tr * 4 + u][tc] = s;
  }
  __syncthreads();
  if (t < 64) {
    float s = 0.f;
    #pragma unroll
    for (int g = 0; g < 16; ++g) s += red[t][g];
    stat[t] = 1.0f / fmaxf(sqrtf(s), 1e-12f);
  }
  __syncthreads();
  #pragma unroll
  for (int u = 0; u < 4; ++u) {
    float rn = stat[tr * 4 + u];
    #pragma unroll
    for (int v = 0; v < 16; ++v)
      out[(size_t)rows[u] * 768 + 512 + tc * 16 + v] = acc[u][v] * rn;
  }
}

// ---------------------------------------------------------------------------
extern "C" void kernel_launch(void* const* d_in, const int* in_sizes, int n_in,
                              void* d_out, int out_size, void* d_ws, size_t ws_size,
                              hipStream_t stream)
{
  (void)in_sizes; (void)n_in; (void)out_size; (void)ws_size;

  const float* feat[4]; const float* wfc[4]; const float* bfc[4];
  for (int i = 0; i < 4; ++i) {
    feat[i] = (const float*)d_in[i * 3 + 0];
    wfc[i]  = (const float*)d_in[i * 3 + 1];
    bfc[i]  = (const float*)d_in[i * 3 + 2];
  }
  const float* type_emb = (const float*)d_in[12];
  const float* Wgcn = (const float*)d_in[13];
  const float* bgcn = (const float*)d_in[14];
  const float* Wre  = (const float*)d_in[15];
  const float* bre  = (const float*)d_in[16];
  const float* wtre = (const float*)d_in[17];
  const float* Wl   = (const float*)d_in[18];
  const float* Wr   = (const float*)d_in[19];
  const float* al   = (const float*)d_in[20];
  const float* ar   = (const float*)d_in[21];
  const float* Wrs  = (const float*)d_in[22];
  const float* Wrt  = (const float*)d_in[23];
  const float* Wfin = (const float*)d_in[24];
  const float* ln_g = (const float*)d_in[25];
  const float* ln_b = (const float*)d_in[26];
  const int* src       = (const int*)d_in[27];
  const int* dst       = (const int*)d_in[28];
  const int* node_type = (const int*)d_in[29];
  const int* seqs      = (const int*)d_in[30];
  float* out = (float*)d_out;

  // workspace carve-up (~50 MB)
  char* p = (char*)d_ws;
  auto take = [&](size_t n) { char* q = p; p += (n + 255) & ~(size_t)255; return q; };
  float* gh    = (float*)take((size_t)NN * 256 * 4);
  float* Xbuf  = (float*)take((size_t)NN * 256 * 4);   // GCN scratch, then ctx2buf
  float* GR1   = (float*)take((size_t)NN * 256 * 4);   // gh@Wr1, then h1r0buf
  float* RKQ   = (float*)take((size_t)NN * 128 * 4);
  float* SLg   = (float*)take((size_t)NN * 8 * 4);
  float* SRg   = (float*)take((size_t)NN * 8 * 4);
  float* n_out = (float*)take((size_t)NN * 4);
  float* n_in_ = (float*)take((size_t)NN * 4);
  int*   outc  = (int*)take((size_t)NN * 4);
  int*   inc   = (int*)take((size_t)NN * 4);
  int*   offs  = (int*)take((size_t)(NN + 1) * 4);
  int*   cur   = (int*)take((size_t)NN * 4);
  int*   csr   = (int*)take((size_t)(EE + NN) * 4);
  float* R     = (float*)take((size_t)NN * 4 * 4);
  float* rtmp  = (float*)take((size_t)NN * 4 * 4);
  ushortT* GW  = (ushortT*)take((size_t)NN * 256 * 2);
  ushortT* GW2 = (ushortT*)take((size_t)NN * 256 * 2);
  ushortT* GWL = (ushortT*)take((size_t)NN * 256 * 2);
  ushortT* GHG = (ushortT*)take((size_t)NN * 256 * 2);
  ushortT* GHL = (ushortT*)take((size_t)NN * 256 * 2);
  float* Wg2   = (float*)take((size_t)65536 * 4);
  float* Wgl2  = (float*)take((size_t)65536 * 4);
  float* Wc2   = (float*)take((size_t)65536 * 4);
  float* Wcl   = (float*)take((size_t)65536 * 4);
  float* vecs  = (float*)take((size_t)4 * 256 * 4);
  float* ctx2buf = Xbuf;   // alias: Xbuf dead after GCN
  float* h1r0buf = GR1;    // alias: GR1 dead after table GEMMs

  const float* Wr2 = Wr + 65536;
  const float* Wl2 = Wl + 65536;

  // 1) FC + ret0
  fc_kernel<<<256, 256, 0, stream>>>(feat[0], feat[1], feat[2], feat[3],
                                     wfc[0], wfc[1], wfc[2], wfc[3],
                                     bfc[0], bfc[1], bfc[2], bfc[3], gh, out);
  // 2) degrees + CSR
  zero_counts<<<64, 256, 0, stream>>>(outc, inc);
  count_deg<<<512, 256, 0, stream>>>(src, dst, outc, inc);
  norm_kernel<<<32, 256, 0, stream>>>(outc, inc, n_out, n_in_);
  scan_kernel<<<1, 1024, 0, stream>>>(inc, offs);
  copy_cur<<<32, 256, 0, stream>>>(offs, cur);
  fill_csr<<<544, 256, 0, stream>>>(src, dst, cur, csr);
  init_R<<<128, 256, 0, stream>>>(type_emb, node_type, R);

  // weight prep (independent of graph work)
  scale_w_kernel<<<256, 256, 0, stream>>>(ln_g, Wr2, Wl2, Wg2, Wgl2);
  vec4_kernel<<<4, 256, 0, stream>>>(ln_g, ln_b, Wr2, Wl2, vecs);
  gemm64_kernel<false, true, false, float>
      <<<dim3(4, 4), 256, 0, stream>>>(Wfin, Wg2, nullptr, Wc2, nullptr, nullptr);
  gemm64_kernel<false, true, false, float>
      <<<dim3(4, 4), 256, 0, stream>>>(Wfin, Wgl2, nullptr, Wcl, nullptr, nullptr);

  // 3) GCN + REConv, K=2
  for (int k = 0; k < 2; ++k) {
    gemm64_kernel<true, true, false, float>
        <<<dim3(128, 4), 256, 0, stream>>>(gh, Wgcn + (size_t)k * 65536,
                                           n_out, Xbuf, nullptr, nullptr);
    agg_kernel<<<NN, 256, 0, stream>>>(offs, csr, Xbuf, n_in_, bgcn + k * 256, gh);
    re_proj<<<128, 256, 0, stream>>>(R, n_out, Wre + k * 16, wtre + k * 4, node_type, rtmp);
    re_agg<<<128, 256, 0, stream>>>(offs, csr, rtmp, n_in_, bre + k * 4, R);
  }

  // 4) attention precomputes + node tables
  rkq_kernel<<<4096, 256, 0, stream>>>(R, Wrs, Wrt, RKQ);
  gemm64_kernel<false, false, true, float>
      <<<dim3(128, 4), 256, 0, stream>>>(gh, Wl, nullptr, (float*)nullptr, al, SLg);
  gemm64_kernel<false, true, true, float>
      <<<dim3(128, 4), 256, 0, stream>>>(gh, Wr, nullptr, GR1, ar, SRg);
  gemm64_kernel<false, true, false, ushortT>
      <<<dim3(128, 4), 256, 0, stream>>>(GR1, Wfin, nullptr, GW, nullptr, nullptr);
  gemm64_kernel<false, true, false, ushortT>
      <<<dim3(128, 4), 256, 0, stream>>>(GR1, Wc2, nullptr, GW2, nullptr, nullptr);
  gemm64_kernel<false, true, false, ushortT>
      <<<dim3(128, 4), 256, 0, stream>>>(GR1, Wcl, nullptr, GWL, nullptr, nullptr);
  gemm64_kernel<false, true, false, ushortT>
      <<<dim3(128, 4), 256, 0, stream>>>(gh, Wg2, nullptr, GHG, nullptr, nullptr);
  gemm64_kernel<false, true, false, ushortT>
      <<<dim3(128, 4), 256, 0, stream>>>(gh, Wgl2, nullptr, GHL, nullptr, nullptr);

  // 5) fused transformer (tables) -> ret1, h1r0, ctx2
  mega2_kernel<<<NN, 256, 0, stream>>>(seqs, gh, GW, GW2, GWL, GHG, GHL,
                                       SLg, SRg, RKQ, vecs,
                                       al + 32, ar + 32, ln_g, ln_b,
                                       h1r0buf, ctx2buf, out);

  // 6) epilogue: ret2 = l2n(LN(h1r0 + ctx2@Wfin2))
  final_ln_kernel<<<128, 256, 0, stream>>>(ctx2buf, Wfin + 65536, h1r0buf,
                                           ln_g + 256, ln_b + 256, out);
}

// Round 8
// 744.588 us; speedup vs baseline: 3.7121x; 1.0399x over previous
//
#include <hip/hip_runtime.h>
#include <hip/hip_bf16.h>
#include <cstdint>
#include <cstddef>

typedef unsigned short ushortT;
typedef unsigned int uintT;

static constexpr int NN  = 8192;    // total nodes
static constexpr int EE  = 131072;  // edges
static constexpr float SLOPE  = 0.2f;
static constexpr float LN_EPS = 1e-5f;

#define DEVI __device__ __forceinline__

DEVI float red32(float v) {   // sum within 32-lane half
  #pragma unroll
  for (int m = 16; m >= 1; m >>= 1) v += __shfl_xor(v, m, 64);
  return v;
}
DEVI float red64(float v) {   // sum over full wave
  #pragma unroll
  for (int m = 32; m >= 1; m >>= 1) v += __shfl_xor(v, m, 64);
  return v;
}
DEVI float max32(float v) {
  #pragma unroll
  for (int m = 16; m >= 1; m >>= 1) v = fmaxf(v, __shfl_xor(v, m, 64));
  return v;
}
DEVI float blo(uintT u) { union { uintT i; float f; } c; c.i = u << 16; return c.f; }
DEVI float bhi(uintT u) { union { uintT i; float f; } c; c.i = u & 0xffff0000u; return c.f; }
DEVI float b2f(ushortT u) { union { uintT i; float f; } c; c.i = ((uintT)u) << 16; return c.f; }
DEVI ushortT f2bu(float f) {
  __hip_bfloat16 h = __float2bfloat16(f);
  return *reinterpret_cast<ushortT*>(&h);
}
DEVI void storeC(float* p, float v) { *p = v; }
DEVI void storeC(ushortT* p, float v) { *p = f2bu(v); }

// ---------------------------------------------------------------------------
// FC: gh[n] = feat_t[n] @ Wfc_t + bfc_t ; out[n,0:256] = l2n(gh[n])
// ---------------------------------------------------------------------------
__global__ __launch_bounds__(256) void fc_kernel(
    const float* __restrict__ f0, const float* __restrict__ f1,
    const float* __restrict__ f2, const float* __restrict__ f3,
    const float* __restrict__ w0, const float* __restrict__ w1,
    const float* __restrict__ w2, const float* __restrict__ w3,
    const float* __restrict__ b0, const float* __restrict__ b1,
    const float* __restrict__ b2, const float* __restrict__ b3,
    float* __restrict__ gh, float* __restrict__ out)
{
  const int nb = blockIdx.x * 32;
  const int t  = threadIdx.x;
  int base, D;
  const float *F, *W, *Bv;
  if (nb < 4096)      { base = 0;    D = 128; F = f0; W = w0; Bv = b0; }
  else if (nb < 6144) { base = 4096; D = 64;  F = f1; W = w1; Bv = b1; }
  else if (nb < 7168) { base = 6144; D = 32;  F = f2; W = w2; Bv = b2; }
  else                { base = 7168; D = 16;  F = f3; W = w3; Bv = b3; }

  __shared__ float Fs[32 * 128];
  __shared__ float red[32][4];
  __shared__ float nrm[32];

  const int total = 32 * D;
  for (int i = t; i < total; i += 256) Fs[i] = F[(size_t)(nb - base) * D + i];
  __syncthreads();

  float acc[32];
  #pragma unroll
  for (int r = 0; r < 32; ++r) acc[r] = Bv[t];
  for (int d = 0; d < D; ++d) {
    float w = W[(size_t)d * 256 + t];
    #pragma unroll
    for (int r = 0; r < 32; ++r) acc[r] = fmaf(Fs[r * D + d], w, acc[r]);
  }

  const int lane = t & 63, wid = t >> 6;
  #pragma unroll
  for (int r = 0; r < 32; ++r) {
    float v = acc[r] * acc[r];
    for (int o = 32; o > 0; o >>= 1) v += __shfl_down(v, o, 64);
    if (lane == 0) red[r][wid] = v;
  }
  __syncthreads();
  if (t < 32) {
    float s = red[t][0] + red[t][1] + red[t][2] + red[t][3];
    nrm[t] = 1.0f / fmaxf(sqrtf(s), 1e-12f);
  }
  __syncthreads();
  #pragma unroll
  for (int r = 0; r < 32; ++r) {
    gh[(size_t)(nb + r) * 256 + t]  = acc[r];
    out[(size_t)(nb + r) * 768 + t] = acc[r] * nrm[r];
  }
}

// ---------------------------------------------------------------------------
// degree / CSR build
// ---------------------------------------------------------------------------
__global__ __launch_bounds__(256) void zero_counts(int* outc, int* inc) {
  int g = blockIdx.x * 256 + threadIdx.x;
  if (g < NN) outc[g] = 0; else inc[g - NN] = 0;
}
__global__ __launch_bounds__(256) void count_deg(const int* __restrict__ src,
                                                 const int* __restrict__ dst,
                                                 int* outc, int* inc) {
  int g = blockIdx.x * 256 + threadIdx.x;
  atomicAdd(&outc[src[g]], 1);
  atomicAdd(&inc[dst[g]], 1);
}
__global__ __launch_bounds__(256) void norm_kernel(const int* __restrict__ outc,
                                                   const int* __restrict__ inc,
                                                   float* n_out, float* n_in) {
  int g = blockIdx.x * 256 + threadIdx.x;
  n_out[g] = rsqrtf((float)outc[g] + 1.0f);
  n_in[g]  = rsqrtf((float)inc[g] + 1.0f);
}
__global__ __launch_bounds__(1024) void scan_kernel(const int* __restrict__ inc,
                                                    int* __restrict__ offs) {
  __shared__ int sums[1024];
  const int t = threadIdx.x;
  int x[8];
  const int base = t * 8;
  int s = 0;
  #pragma unroll
  for (int i = 0; i < 8; ++i) { int v = inc[base + i] + 1; x[i] = s; s += v; }
  sums[t] = s;
  __syncthreads();
  for (int off = 1; off < 1024; off <<= 1) {
    int a = (t >= off) ? sums[t - off] : 0;
    __syncthreads();
    sums[t] += a;
    __syncthreads();
  }
  const int pre = (t > 0) ? sums[t - 1] : 0;
  #pragma unroll
  for (int i = 0; i < 8; ++i) offs[base + i] = pre + x[i];
  if (t == 1023) offs[NN] = sums[1023];
}
__global__ __launch_bounds__(256) void copy_cur(const int* __restrict__ offs, int* cur) {
  int g = blockIdx.x * 256 + threadIdx.x;
  cur[g] = offs[g];
}
__global__ __launch_bounds__(256) void fill_csr(const int* __restrict__ src,
                                                const int* __restrict__ dst,
                                                int* cur, int* __restrict__ csr) {
  int g = blockIdx.x * 256 + threadIdx.x;   // EE + NN total
  int s, d;
  if (g < EE) { s = src[g]; d = dst[g]; }
  else        { s = g - EE; d = g - EE; }   // self-loops
  int pos = atomicAdd(&cur[d], 1);
  csr[pos] = s;
}
__global__ __launch_bounds__(256) void init_R(const float* __restrict__ type_emb,
                                              const int* __restrict__ nt,
                                              float* __restrict__ R) {
  int g = blockIdx.x * 256 + threadIdx.x;   // NN*4
  int n = g >> 2, c = g & 3;
  R[g] = type_emb[nt[n] * 4 + c];
}

// ---------------------------------------------------------------------------
// [M,256] @ [256,256] f32 register-tiled GEMM, 64x64 tile, 256 thr.
// ---------------------------------------------------------------------------
template<bool ROWSCALE, bool STORE, bool RED, typename CT>
__global__ __launch_bounds__(256) void gemm64_kernel(
    const float* __restrict__ A,
    const float* __restrict__ W,
    const float* __restrict__ rowscale,
    CT* __restrict__ C,
    const float* __restrict__ avec,
    float* __restrict__ SSo)
{
  const int m0 = blockIdx.x * 64;
  const int n0 = blockIdx.y * 64;
  const int t  = threadIdx.x;
  const int tr = t & 15, tc = t >> 4;
  __shared__ alignas(16) float As[32][68];
  __shared__ alignas(16) float Bs[32][68];
  __shared__ float red[64][2];
  float acc[4][4] = {};

  for (int ks = 0; ks < 8; ++ks) {
    const int k0 = ks * 32;
    #pragma unroll
    for (int rep = 0; rep < 8; ++rep) {
      int flat = rep * 256 + t;
      int r = flat >> 5, c = flat & 31;
      As[c][r] = A[(size_t)(m0 + r) * 256 + (k0 + c)];
      int rb = flat >> 6, cb = flat & 63;
      Bs[rb][cb] = W[(size_t)(k0 + rb) * 256 + (n0 + cb)];
    }
    __syncthreads();
    #pragma unroll
    for (int k = 0; k < 32; ++k) {
      const float4 a4 = *reinterpret_cast<const float4*>(&As[k][tr * 4]);
      const float4 b4 = *reinterpret_cast<const float4*>(&Bs[k][tc * 4]);
      const float av[4] = {a4.x, a4.y, a4.z, a4.w};
      const float bv[4] = {b4.x, b4.y, b4.z, b4.w};
      #pragma unroll
      for (int u = 0; u < 4; ++u)
        #pragma unroll
        for (int v = 0; v < 4; ++v)
          acc[u][v] = fmaf(av[u], bv[v], acc[u][v]);
    }
    __syncthreads();
  }

  if constexpr (ROWSCALE) {
    #pragma unroll
    for (int u = 0; u < 4; ++u) {
      float s = rowscale[m0 + tr * 4 + u];
      #pragma unroll
      for (int v = 0; v < 4; ++v) acc[u][v] *= s;
    }
  }
  if constexpr (STORE) {
    #pragma unroll
    for (int u = 0; u < 4; ++u) {
      size_t row = (size_t)(m0 + tr * 4 + u);
      #pragma unroll
      for (int v = 0; v < 4; ++v)
        storeC(&C[row * 256 + (n0 + tc * 4 + v)], acc[u][v]);
    }
  }
  if constexpr (RED) {
    if (t < 128) red[t >> 1][t & 1] = 0.f;
    __syncthreads();
    #pragma unroll
    for (int u = 0; u < 4; ++u) {
      float s = 0.f;
      #pragma unroll
      for (int v = 0; v < 4; ++v) {
        float x = acc[u][v];
        float lr = x > 0.f ? x : SLOPE * x;
        s += lr * avec[(tc * 4 + v) & 31];
      }
      atomicAdd(&red[tr * 4 + u][tc >> 3], s);
    }
    __syncthreads();
    if (t < 128) {
      int r = t >> 1, hh = t & 1;
      SSo[(size_t)(m0 + r) * 8 + blockIdx.y * 2 + hh] = red[r][hh];
    }
  }
}

// ---------------------------------------------------------------------------
// GCN aggregate / REConv / RKQ
// ---------------------------------------------------------------------------
__global__ __launch_bounds__(256) void agg_kernel(
    const int* __restrict__ offs, const int* __restrict__ csr,
    const float* __restrict__ X, const float* __restrict__ n_in,
    const float* __restrict__ bias, float* __restrict__ ghn)
{
  const int n = blockIdx.x, t = threadIdx.x;
  const int s0 = offs[n], s1 = offs[n + 1];
  float acc = 0.f;
  for (int i = s0; i < s1; ++i) acc += X[(size_t)csr[i] * 256 + t];
  ghn[(size_t)n * 256 + t] = fmaxf(fmaf(acc, n_in[n], bias[t]), 0.f);
}
__global__ __launch_bounds__(256) void re_proj(
    const float* __restrict__ R, const float* __restrict__ n_out,
    const float* __restrict__ Wre, const float* __restrict__ wtre,
    const int* __restrict__ nt, float* __restrict__ rtmp)
{
  int g = blockIdx.x * 256 + threadIdx.x;  // NN*4
  int n = g >> 2, j = g & 3;
  float s = 0.f;
  #pragma unroll
  for (int c = 0; c < 4; ++c) s += R[n * 4 + c] * Wre[c * 4 + j];
  rtmp[g] = s * n_out[n] * wtre[nt[n]];
}
__global__ __launch_bounds__(256) void re_agg(
    const int* __restrict__ offs, const int* __restrict__ csr,
    const float* __restrict__ rtmp, const float* __restrict__ n_in,
    const float* __restrict__ bre, float* __restrict__ Rn)
{
  int g = blockIdx.x * 256 + threadIdx.x;  // NN*4
  int n = g >> 2, j = g & 3;
  float a = 0.f;
  for (int i = offs[n]; i < offs[n + 1]; ++i) a += rtmp[csr[i] * 4 + j];
  Rn[g] = fmaxf(fmaf(a, n_in[n], bre[j]), 0.f);
}
__global__ __launch_bounds__(256) void rkq_kernel(
    const float* __restrict__ R, const float* __restrict__ Wrs,
    const float* __restrict__ Wrt, float* __restrict__ RKQ)
{
  int g = blockIdx.x * 256 + threadIdx.x;  // NN*128
  int n = g >> 7, c = g & 127;
  int which = c >> 5, cc = c & 31;
  const float* Wp = (which == 0) ? Wrs : (which == 1) ? Wrt
                   : (which == 2) ? (Wrs + 128) : (Wrt + 128);
  float s = 0.f;
  #pragma unroll
  for (int r = 0; r < 4; ++r) s += R[n * 4 + r] * Wp[r * 32 + cc];
  RKQ[g] = s;
}

// ---------------------------------------------------------------------------
// weight prep: Wg2 = diag(g1)Wr2, Wgl2 = diag(g1)Wl2
// ---------------------------------------------------------------------------
__global__ __launch_bounds__(256) void scale_w_kernel(
    const float* __restrict__ ln_g, const float* __restrict__ Wr2,
    const float* __restrict__ Wl2, float* __restrict__ Wg2,
    float* __restrict__ Wgl2)
{
  int g = blockIdx.x * 256 + threadIdx.x;  // 65536
  float s = ln_g[g >> 8];
  Wg2[g]  = s * Wr2[g];
  Wgl2[g] = s * Wl2[g];
}
// vecs[0]=g1@Wr2, [1]=b1@Wr2, [2]=g1@Wl2, [3]=b1@Wl2
__global__ __launch_bounds__(256) void vec4_kernel(
    const float* __restrict__ ln_g, const float* __restrict__ ln_b,
    const float* __restrict__ Wr2, const float* __restrict__ Wl2,
    float* __restrict__ vecs)
{
  const int which = blockIdx.x, t = threadIdx.x;
  const float* W = (which < 2) ? Wr2 : Wl2;
  const float* s = (which & 1) ? ln_b : ln_g;
  float a = 0.f;
  for (int k = 0; k < 256; ++k) a = fmaf(s[k], W[(size_t)k * 256 + t], a);
  vecs[which * 256 + t] = a;
}

// ---------------------------------------------------------------------------
// MEGA2 v4: f32 LDS table staging — bf16 unpack happens ONCE at stage time
// (32/thread) instead of per-use (2048/thread). LDS ~72.5 KB, 2 blocks/CU.
// ---------------------------------------------------------------------------
__global__ __launch_bounds__(256) void mega2_kernel(
    const int* __restrict__ seqs,
    const float* __restrict__ gh,
    const ushortT* __restrict__ GW, const ushortT* __restrict__ GW2,
    const ushortT* __restrict__ GWL, const ushortT* __restrict__ GHG,
    const ushortT* __restrict__ GHL,
    const float* __restrict__ SLg, const float* __restrict__ SRg,
    const float* __restrict__ RKQ,
    const float* __restrict__ vecs,           // v1,v2,vl1,vl2
    const float* __restrict__ al2, const float* __restrict__ ar2,
    const float* __restrict__ ln_g, const float* __restrict__ ln_b,
    float* __restrict__ h1r0buf, float* __restrict__ ctx2buf,
    float* __restrict__ out)
{
  __shared__ int     idx[32];
  __shared__ alignas(16) float GWsF[32][260];  // stage: GW, then GW2 (f32)
  __shared__ ushortT FR2s[32][268];
  __shared__ float SLs[8][32], SRs[8][32];
  __shared__ float RKs[32][36];
  __shared__ float RQs[32][36];      // RQ1, then RQ2
  __shared__ float rk2s[32];
  __shared__ float p1r0[8][32];
  __shared__ float part[32][8], partq[32][8];
  __shared__ float mu_s[32], rs_s[32];
  __shared__ float SR2s[8][32];
  __shared__ float sl2s[8];
  __shared__ float scp[8][32];
  __shared__ float h1r0s[256];
  __shared__ float vs[1024];         // staged vecs
  __shared__ float wred4[4];
  __shared__ float nrm1s;

  const int b = blockIdx.x, t = threadIdx.x;
  const int h8 = t >> 5, lo = t & 31;
  const int c0 = h8 * 32;

  if (t < 32) idx[t] = seqs[b * 32 + t];
  __syncthreads();                                             // B1

  // ---- stage GW as f32 (unpack once), SL/SR, RK/RQ1, rk2, vecs ----
  {
    const uintT* GWu = reinterpret_cast<const uintT*>(GW);
    #pragma unroll
    for (int rep = 0; rep < 16; ++rep) {
      int flat = rep * 256 + t;             // 4096 uints
      int r = flat >> 7, c = flat & 127;
      const uintT u = GWu[(size_t)idx[r] * 128 + c];
      float2 f2; f2.x = blo(u); f2.y = bhi(u);
      *reinterpret_cast<float2*>(&GWsF[r][2 * c]) = f2;
    }
  }
  SLs[h8][lo] = SLg[(size_t)idx[lo] * 8 + h8];
  SRs[h8][lo] = SRg[(size_t)idx[lo] * 8 + h8];
  #pragma unroll
  for (int rep = 0; rep < 4; ++rep) {
    int flat = rep * 256 + t, s3 = flat >> 5, c3 = flat & 31;
    RKs[s3][c3] = RKQ[(size_t)idx[s3] * 128 + c3];
    RQs[s3][c3] = RKQ[(size_t)idx[s3] * 128 + 32 + c3];
    vs[flat] = vecs[flat];
  }
  if (t < 32) rk2s[t] = RKQ[(size_t)idx[0] * 128 + 64 + t];
  __syncthreads();                                             // B2

  // ---- attn1 scores+softmax: thread = (head h8, query row lo) ----
  float p1[32];
  {
    const float rk0 = RKs[lo][h8 * 4 + 0], rk1 = RKs[lo][h8 * 4 + 1],
                rk2 = RKs[lo][h8 * 4 + 2], rk3 = RKs[lo][h8 * 4 + 3];
    const float sli = SLs[h8][lo];
    float m = -1e30f;
    #pragma unroll
    for (int j = 0; j < 32; ++j) {
      float sc = sli + SRs[h8][j]
               + rk0 * RQs[j][h8 * 4 + 0] + rk1 * RQs[j][h8 * 4 + 1]
               + rk2 * RQs[j][h8 * 4 + 2] + rk3 * RQs[j][h8 * 4 + 3];
      p1[j] = sc; m = fmaxf(m, sc);
    }
    float sum = 0.f;
    #pragma unroll
    for (int j = 0; j < 32; ++j) { p1[j] = __expf(p1[j] - m); sum += p1[j]; }
    const float inv = 1.f / sum;
    #pragma unroll
    for (int j = 0; j < 32; ++j) p1[j] *= inv;
  }
  if (lo == 0) {
    #pragma unroll
    for (int j = 0; j < 32; ++j) p1r0[h8][j] = p1[j];
  }

  // ---- x phase (chunked, f32 LDS): stats only; row 0 stashed pre-LN ----
  {
    float xsum = 0.f, xsq = 0.f;
    const float4* gp4 = reinterpret_cast<const float4*>(&gh[(size_t)idx[lo] * 256 + c0]);
    #pragma unroll
    for (int ch = 0; ch < 4; ++ch) {
      float a[8];
      #pragma unroll
      for (int q = 0; q < 8; ++q) a[q] = 0.f;
      #pragma unroll 8
      for (int j = 0; j < 32; ++j) {
        const float pj = p1[j];
        const float4* rx = reinterpret_cast<const float4*>(&GWsF[j][c0 + ch * 8]);
        const float4 xa = rx[0], xb = rx[1];
        a[0] = fmaf(pj, xa.x, a[0]); a[1] = fmaf(pj, xa.y, a[1]);
        a[2] = fmaf(pj, xa.z, a[2]); a[3] = fmaf(pj, xa.w, a[3]);
        a[4] = fmaf(pj, xb.x, a[4]); a[5] = fmaf(pj, xb.y, a[5]);
        a[6] = fmaf(pj, xb.z, a[6]); a[7] = fmaf(pj, xb.w, a[7]);
      }
      const float4 g0 = gp4[ch * 2], g1 = gp4[ch * 2 + 1];
      a[0] += g0.x; a[1] += g0.y; a[2] += g0.z; a[3] += g0.w;
      a[4] += g1.x; a[5] += g1.y; a[6] += g1.z; a[7] += g1.w;
      #pragma unroll
      for (int q = 0; q < 8; ++q) { xsum += a[q]; xsq = fmaf(a[q], a[q], xsq); }
      if (lo == 0) {
        #pragma unroll
        for (int q = 0; q < 8; ++q) h1r0s[c0 + ch * 8 + q] = a[q];
      }
    }
    part[lo][h8]  = xsum;
    partq[lo][h8] = xsq;
  }
  __syncthreads();                                             // B3

  if (t < 32) {
    float sm = 0.f, sq = 0.f;
    #pragma unroll
    for (int h = 0; h < 8; ++h) { sm += part[t][h]; sq += partq[t][h]; }
    const float m = sm * (1.f / 256.f);
    const float v = fmaxf(sq * (1.f / 256.f) - m * m, 0.f);
    mu_s[t] = m;
    rs_s[t] = rsqrtf(v + LN_EPS);
  }
  __syncthreads();                                             // B4

  // ---- stage GW2 (f32) into GWsF, RQ2 into RQs; h1 row0 LN + ret1 partials ----
  {
    const uintT* GW2u = reinterpret_cast<const uintT*>(GW2);
    #pragma unroll
    for (int rep = 0; rep < 16; ++rep) {
      int flat = rep * 256 + t;
      int r = flat >> 7, c = flat & 127;
      const uintT u = GW2u[(size_t)idx[r] * 128 + c];
      float2 f2; f2.x = blo(u); f2.y = bhi(u);
      *reinterpret_cast<float2*>(&GWsF[r][2 * c]) = f2;
    }
  }
  #pragma unroll
  for (int rep = 0; rep < 4; ++rep) {
    int flat = rep * 256 + t, s3 = flat >> 5, c3 = flat & 31;
    RQs[s3][c3] = RKQ[(size_t)idx[s3] * 128 + 96 + c3];
  }
  {
    const float mu0 = mu_s[0], rs0 = rs_s[0];
    float hv = fmaf((h1r0s[t] - mu0) * rs0, ln_g[t], ln_b[t]);
    h1r0buf[(size_t)b * 256 + t] = hv;
    float sq = red64(hv * hv);
    h1r0s[t] = hv;                       // own col only; safe overwrite
    if ((t & 63) == 0) wred4[t >> 6] = sq;
  }
  __syncthreads();                                             // B5

  // ---- y phase (chunked, f32 LDS): FR2 bf16 + SR2 ----
  {
    const float rs = rs_s[lo];
    const float rm = rs * mu_s[lo];
    float sr2 = 0.f;
    #pragma unroll
    for (int ch = 0; ch < 4; ++ch) {
      float a[8];
      #pragma unroll
      for (int q = 0; q < 8; ++q) a[q] = 0.f;
      #pragma unroll 8
      for (int j = 0; j < 32; ++j) {
        const float pj = p1[j];
        const float4* ry = reinterpret_cast<const float4*>(&GWsF[j][c0 + ch * 8]);
        const float4 ya = ry[0], yb = ry[1];
        a[0] = fmaf(pj, ya.x, a[0]); a[1] = fmaf(pj, ya.y, a[1]);
        a[2] = fmaf(pj, ya.z, a[2]); a[3] = fmaf(pj, ya.w, a[3]);
        a[4] = fmaf(pj, yb.x, a[4]); a[5] = fmaf(pj, yb.y, a[5]);
        a[6] = fmaf(pj, yb.z, a[6]); a[7] = fmaf(pj, yb.w, a[7]);
      }
      const uintT* hg = reinterpret_cast<const uintT*>(&GHG[(size_t)idx[lo] * 256 + c0 + ch * 8]);
      #pragma unroll
      for (int q = 0; q < 4; ++q) {
        const uintT h2 = hg[q];
        a[2 * q + 0] += blo(h2);
        a[2 * q + 1] += bhi(h2);
      }
      uintT* fw = reinterpret_cast<uintT*>(&FR2s[lo][0]) + ((c0 + ch * 8) >> 1);
      #pragma unroll
      for (int q = 0; q < 4; ++q) {
        const int c = c0 + ch * 8 + 2 * q;
        const float fa = fmaf(rs, a[2 * q + 0], fmaf(-rm, vs[c],     vs[256 + c]));
        const float fb = fmaf(rs, a[2 * q + 1], fmaf(-rm, vs[c + 1], vs[256 + c + 1]));
        fw[q] = (uintT)f2bu(fa) | ((uintT)f2bu(fb) << 16);
        const float la = fa > 0.f ? fa : SLOPE * fa;
        const float lb = fb > 0.f ? fb : SLOPE * fb;
        sr2 = fmaf(la, ar2[ch * 8 + 2 * q], fmaf(lb, ar2[ch * 8 + 2 * q + 1], sr2));
      }
    }
    SR2s[h8][lo] = sr2;
  }

  // ---- fl2 row0 via tables: z0 = p1r0◦GWL + GHL[idx0] ; sl2 per head ----
  {
    float z0 = 0.f;
    #pragma unroll 8
    for (int j = 0; j < 32; ++j)
      z0 = fmaf(p1r0[h8][j], b2f(GWL[(size_t)idx[j] * 256 + t]), z0);
    z0 += b2f(GHL[(size_t)idx[0] * 256 + t]);
    const float rs0 = rs_s[0], rm0 = rs_s[0] * mu_s[0];
    const float fl = fmaf(rs0, z0, fmaf(-rm0, vs[512 + t], vs[768 + t]));
    float lr = (fl > 0.f ? fl : SLOPE * fl) * al2[lo];
    lr = red32(lr);
    if (lo == 0) sl2s[h8] = lr;
  }
  if (t == 0) nrm1s = 1.f / fmaxf(sqrtf(wred4[0] + wred4[1] + wred4[2] + wred4[3]), 1e-12f);
  __syncthreads();                                             // B6

  // ---- attn2 row0 scores (thread = (h8, key lo)) ----
  {
    float s2 = sl2s[h8] + SR2s[h8][lo]
             + rk2s[h8 * 4 + 0] * RQs[lo][h8 * 4 + 0]
             + rk2s[h8 * 4 + 1] * RQs[lo][h8 * 4 + 1]
             + rk2s[h8 * 4 + 2] * RQs[lo][h8 * 4 + 2]
             + rk2s[h8 * 4 + 3] * RQs[lo][h8 * 4 + 3];
    const float m2 = max32(s2);
    const float e = __expf(s2 - m2);
    const float su = red32(e);
    scp[h8][lo] = e / su;
  }
  __syncthreads();                                             // B7

  // ---- ctx2 = p2 ◦ FR2 (thread = col t) ; ret1 write ----
  {
    float a = 0.f;
    #pragma unroll
    for (int j = 0; j < 32; ++j) a = fmaf(scp[h8][j], b2f(FR2s[j][t]), a);
    ctx2buf[(size_t)b * 256 + t] = a;
  }
  out[(size_t)b * 768 + 256 + t] = h1r0s[t] * nrm1s;
}

// ---------------------------------------------------------------------------
// Epilogue: ret2 = l2n(LN(h1row0 + ctx2 @ Wfin2))  — 64 rows/block
// ---------------------------------------------------------------------------
__global__ __launch_bounds__(256) void final_ln_kernel(
    const float* __restrict__ A,       // ctx2buf [8192,256]
    const float* __restrict__ W,       // Wfin2
    const float* __restrict__ res,     // h1r0buf [8192,256]
    const float* __restrict__ lng, const float* __restrict__ lnb,
    float* __restrict__ out)
{
  const int m0 = blockIdx.x * 64;
  const int t  = threadIdx.x;
  const int tr = t & 15, tc = t >> 4;
  __shared__ alignas(16) float As[32][68];
  __shared__ alignas(16) float Bs[32][264];
  __shared__ float red[64][16];
  __shared__ float stat[64];
  float acc[4][16] = {};

  for (int ks = 0; ks < 8; ++ks) {
    const int k0 = ks * 32;
    #pragma unroll
    for (int rep = 0; rep < 8; ++rep) {
      int flat = rep * 256 + t;
      int r = flat >> 5, c = flat & 31;
      As[c][r] = A[(size_t)(m0 + r) * 256 + (k0 + c)];
    }
    #pragma unroll
    for (int rep = 0; rep < 32; ++rep) {
      int flat = rep * 256 + t;
      int rb = flat >> 8, cb = flat & 255;
      Bs[rb][cb] = W[(size_t)(k0 + rb) * 256 + cb];
    }
    __syncthreads();
    #pragma unroll
    for (int k = 0; k < 32; ++k) {
      const float4 a4 = *reinterpret_cast<const float4*>(&As[k][tr * 4]);
      const float av[4] = {a4.x, a4.y, a4.z, a4.w};
      #pragma unroll
      for (int q = 0; q < 4; ++q) {
        const float4 b4 = *reinterpret_cast<const float4*>(&Bs[k][tc * 16 + q * 4]);
        const float bv[4] = {b4.x, b4.y, b4.z, b4.w};
        #pragma unroll
        for (int u = 0; u < 4; ++u)
          #pragma unroll
          for (int v = 0; v < 4; ++v)
            acc[u][q * 4 + v] = fmaf(av[u], bv[v], acc[u][q * 4 + v]);
      }
    }
    __syncthreads();
  }

  int rows[4];
  #pragma unroll
  for (int u = 0; u < 4; ++u) rows[u] = m0 + tr * 4 + u;

  #pragma unroll
  for (int u = 0; u < 4; ++u) {
    const float* rp = &res[(size_t)rows[u] * 256 + tc * 16];
    #pragma unroll
    for (int v = 0; v < 16; ++v) acc[u][v] += rp[v];
  }
  #pragma unroll
  for (int u = 0; u < 4; ++u) {
    float s = 0.f;
    #pragma unroll
    for (int v = 0; v < 16; ++v) s += acc[u][v];
    red[tr * 4 + u][tc] = s;
  }
  __syncthreads();
  if (t < 64) {
    float s = 0.f;
    #pragma unroll
    for (int g = 0; g < 16; ++g) s += red[t][g];
    stat[t] = s * (1.0f / 256.0f);
  }
  __syncthreads();
  float mu[4];
  #pragma unroll
  for (int u = 0; u < 4; ++u) mu[u] = stat[tr * 4 + u];
  #pragma unroll
  for (int u = 0; u < 4; ++u) {
    float s = 0.f;
    #pragma unroll
    for (int v = 0; v < 16; ++v) { float d = acc[u][v] - mu[u]; s += d * d; }
    red[tr * 4 + u][tc] = s;
  }
  __syncthreads();
  if (t < 64) {
    float s = 0.f;
    #pragma unroll
    for (int g = 0; g < 16; ++g) s += red[t][g];
    stat[t] = rsqrtf(s * (1.0f / 256.0f) + LN_EPS);
  }
  __syncthreads();
  float rst[4];
  #pragma unroll
  for (int u = 0; u < 4; ++u) rst[u] = stat[tr * 4 + u];
  #pragma unroll
  for (int u = 0; u < 4; ++u) {
    float s = 0.f;
    #pragma unroll
    for (int v = 0; v < 16; ++v) {
      int col = tc * 16 + v;
      float yv = fmaf((acc[u][v] - mu[u]) * rst[u], lng[col], lnb[col]);
      acc[u][v] = yv;
      s += yv * yv;
    }
    red[tr * 4 + u][tc] = s;
  }
  __syncthreads();
  if (t < 64) {
    float s = 0.f;
    #pragma unroll
    for (int g = 0; g < 16; ++g) s += red[t][g];
    stat[t] = 1.0f / fmaxf(sqrtf(s), 1e-12f);
  }
  __syncthreads();
  #pragma unroll
  for (int u = 0; u < 4; ++u) {
    float rn = stat[tr * 4 + u];
    #pragma unroll
    for (int v = 0; v < 16; ++v)
      out[(size_t)rows[u] * 768 + 512 + tc * 16 + v] = acc[u][v] * rn;
  }
}

// ---------------------------------------------------------------------------
extern "C" void kernel_launch(void* const* d_in, const int* in_sizes, int n_in,
                              void* d_out, int out_size, void* d_ws, size_t ws_size,
                              hipStream_t stream)
{
  (void)in_sizes; (void)n_in; (void)out_size; (void)ws_size;

  const float* feat[4]; const float* wfc[4]; const float* bfc[4];
  for (int i = 0; i < 4; ++i) {
    feat[i] = (const float*)d_in[i * 3 + 0];
    wfc[i]  = (const float*)d_in[i * 3 + 1];
    bfc[i]  = (const float*)d_in[i * 3 + 2];
  }
  const float* type_emb = (const float*)d_in[12];
  const float* Wgcn = (const float*)d_in[13];
  const float* bgcn = (const float*)d_in[14];
  const float* Wre  = (const float*)d_in[15];
  const float* bre  = (const float*)d_in[16];
  const float* wtre = (const float*)d_in[17];
  const float* Wl   = (const float*)d_in[18];
  const float* Wr   = (const float*)d_in[19];
  const float* al   = (const float*)d_in[20];
  const float* ar   = (const float*)d_in[21];
  const float* Wrs  = (const float*)d_in[22];
  const float* Wrt  = (const float*)d_in[23];
  const float* Wfin = (const float*)d_in[24];
  const float* ln_g = (const float*)d_in[25];
  const float* ln_b = (const float*)d_in[26];
  const int* src       = (const int*)d_in[27];
  const int* dst       = (const int*)d_in[28];
  const int* node_type = (const int*)d_in[29];
  const int* seqs      = (const int*)d_in[30];
  float* out = (float*)d_out;

  // workspace carve-up (~50 MB)
  char* p = (char*)d_ws;
  auto take = [&](size_t n) { char* q = p; p += (n + 255) & ~(size_t)255; return q; };
  float* gh    = (float*)take((size_t)NN * 256 * 4);
  float* Xbuf  = (float*)take((size_t)NN * 256 * 4);   // GCN scratch, then ctx2buf
  float* GR1   = (float*)take((size_t)NN * 256 * 4);   // gh@Wr1, then h1r0buf
  float* RKQ   = (float*)take((size_t)NN * 128 * 4);
  float* SLg   = (float*)take((size_t)NN * 8 * 4);
  float* SRg   = (float*)take((size_t)NN * 8 * 4);
  float* n_out = (float*)take((size_t)NN * 4);
  float* n_in_ = (float*)take((size_t)NN * 4);
  int*   outc  = (int*)take((size_t)NN * 4);
  int*   inc   = (int*)take((size_t)NN * 4);
  int*   offs  = (int*)take((size_t)(NN + 1) * 4);
  int*   cur   = (int*)take((size_t)NN * 4);
  int*   csr   = (int*)take((size_t)(EE + NN) * 4);
  float* R     = (float*)take((size_t)NN * 4 * 4);
  float* rtmp  = (float*)take((size_t)NN * 4 * 4);
  ushortT* GW  = (ushortT*)take((size_t)NN * 256 * 2);
  ushortT* GW2 = (ushortT*)take((size_t)NN * 256 * 2);
  ushortT* GWL = (ushortT*)take((size_t)NN * 256 * 2);
  ushortT* GHG = (ushortT*)take((size_t)NN * 256 * 2);
  ushortT* GHL = (ushortT*)take((size_t)NN * 256 * 2);
  float* Wg2   = (float*)take((size_t)65536 * 4);
  float* Wgl2  = (float*)take((size_t)65536 * 4);
  float* Wc2   = (float*)take((size_t)65536 * 4);
  float* Wcl   = (float*)take((size_t)65536 * 4);
  float* vecs  = (float*)take((size_t)4 * 256 * 4);
  float* ctx2buf = Xbuf;   // alias: Xbuf dead after GCN
  float* h1r0buf = GR1;    // alias: GR1 dead after table GEMMs

  const float* Wr2 = Wr + 65536;
  const float* Wl2 = Wl + 65536;

  // 1) FC + ret0
  fc_kernel<<<256, 256, 0, stream>>>(feat[0], feat[1], feat[2], feat[3],
                                     wfc[0], wfc[1], wfc[2], wfc[3],
                                     bfc[0], bfc[1], bfc[2], bfc[3], gh, out);
  // 2) degrees + CSR
  zero_counts<<<64, 256, 0, stream>>>(outc, inc);
  count_deg<<<512, 256, 0, stream>>>(src, dst, outc, inc);
  norm_kernel<<<32, 256, 0, stream>>>(outc, inc, n_out, n_in_);
  scan_kernel<<<1, 1024, 0, stream>>>(inc, offs);
  copy_cur<<<32, 256, 0, stream>>>(offs, cur);
  fill_csr<<<544, 256, 0, stream>>>(src, dst, cur, csr);
  init_R<<<128, 256, 0, stream>>>(type_emb, node_type, R);

  // weight prep (independent of graph work)
  scale_w_kernel<<<256, 256, 0, stream>>>(ln_g, Wr2, Wl2, Wg2, Wgl2);
  vec4_kernel<<<4, 256, 0, stream>>>(ln_g, ln_b, Wr2, Wl2, vecs);
  gemm64_kernel<false, true, false, float>
      <<<dim3(4, 4), 256, 0, stream>>>(Wfin, Wg2, nullptr, Wc2, nullptr, nullptr);
  gemm64_kernel<false, true, false, float>
      <<<dim3(4, 4), 256, 0, stream>>>(Wfin, Wgl2, nullptr, Wcl, nullptr, nullptr);

  // 3) GCN + REConv, K=2
  for (int k = 0; k < 2; ++k) {
    gemm64_kernel<true, true, false, float>
        <<<dim3(128, 4), 256, 0, stream>>>(gh, Wgcn + (size_t)k * 65536,
                                           n_out, Xbuf, nullptr, nullptr);
    agg_kernel<<<NN, 256, 0, stream>>>(offs, csr, Xbuf, n_in_, bgcn + k * 256, gh);
    re_proj<<<128, 256, 0, stream>>>(R, n_out, Wre + k * 16, wtre + k * 4, node_type, rtmp);
    re_agg<<<128, 256, 0, stream>>>(offs, csr, rtmp, n_in_, bre + k * 4, R);
  }

  // 4) attention precomputes + node tables
  rkq_kernel<<<4096, 256, 0, stream>>>(R, Wrs, Wrt, RKQ);
  gemm64_kernel<false, false, true, float>
      <<<dim3(128, 4), 256, 0, stream>>>(gh, Wl, nullptr, (float*)nullptr, al, SLg);
  gemm64_kernel<false, true, true, float>
      <<<dim3(128, 4), 256, 0, stream>>>(gh, Wr, nullptr, GR1, ar, SRg);
  gemm64_kernel<false, true, false, ushortT>
      <<<dim3(128, 4), 256, 0, stream>>>(GR1, Wfin, nullptr, GW, nullptr, nullptr);
  gemm64_kernel<false, true, false, ushortT>
      <<<dim3(128, 4), 256, 0, stream>>>(GR1, Wc2, nullptr, GW2, nullptr, nullptr);
  gemm64_kernel<false, true, false, ushortT>
      <<<dim3(128, 4), 256, 0, stream>>>(GR1, Wcl, nullptr, GWL, nullptr, nullptr);
  gemm64_kernel<false, true, false, ushortT>
      <<<dim3(128, 4), 256, 0, stream>>>(gh, Wg2, nullptr, GHG, nullptr, nullptr);
  gemm64_kernel<false, true, false, ushortT>
      <<<dim3(128, 4), 256, 0, stream>>>(gh, Wgl2, nullptr, GHL, nullptr, nullptr);

  // 5) fused transformer (tables) -> ret1, h1r0, ctx2
  mega2_kernel<<<NN, 256, 0, stream>>>(seqs, gh, GW, GW2, GWL, GHG, GHL,
                                       SLg, SRg, RKQ, vecs,
                                       al + 32, ar + 32, ln_g, ln_b,
                                       h1r0buf, ctx2buf, out);

  // 6) epilogue: ret2 = l2n(LN(h1r0 + ctx2@Wfin2))
  final_ln_kernel<<<128, 256, 0, stream>>>(ctx2buf, Wfin + 65536, h1r0buf,
                                           ln_g + 256, ln_b + 256, out);
}

// Round 9
// 719.802 us; speedup vs baseline: 3.8400x; 1.0344x over previous
//
#include <hip/hip_runtime.h>
#include <hip/hip_bf16.h>
#include <cstdint>
#include <cstddef>

typedef unsigned short ushortT;
typedef unsigned int uintT;

using bf16x8 = __attribute__((ext_vector_type(8))) short;
using f32x4  = __attribute__((ext_vector_type(4))) float;

static constexpr int NN  = 8192;    // total nodes
static constexpr int EE  = 131072;  // edges
static constexpr float SLOPE  = 0.2f;
static constexpr float LN_EPS = 1e-5f;

#define DEVI __device__ __forceinline__

DEVI float red32(float v) {   // sum within 32-lane half
  #pragma unroll
  for (int m = 16; m >= 1; m >>= 1) v += __shfl_xor(v, m, 64);
  return v;
}
DEVI float red64(float v) {   // sum over full wave
  #pragma unroll
  for (int m = 32; m >= 1; m >>= 1) v += __shfl_xor(v, m, 64);
  return v;
}
DEVI float max32(float v) {
  #pragma unroll
  for (int m = 16; m >= 1; m >>= 1) v = fmaxf(v, __shfl_xor(v, m, 64));
  return v;
}
DEVI float blo(uintT u) { union { uintT i; float f; } c; c.i = u << 16; return c.f; }
DEVI float bhi(uintT u) { union { uintT i; float f; } c; c.i = u & 0xffff0000u; return c.f; }
DEVI float b2f(ushortT u) { union { uintT i; float f; } c; c.i = ((uintT)u) << 16; return c.f; }
DEVI ushortT f2bu(float f) {
  __hip_bfloat16 h = __float2bfloat16(f);
  return *reinterpret_cast<ushortT*>(&h);
}
DEVI void storeC(float* p, float v) { *p = v; }
DEVI void storeC(ushortT* p, float v) { *p = f2bu(v); }

// ---------------------------------------------------------------------------
// FC: gh[n] = feat_t[n] @ Wfc_t + bfc_t ; out[n,0:256] = l2n(gh[n])
// ---------------------------------------------------------------------------
__global__ __launch_bounds__(256) void fc_kernel(
    const float* __restrict__ f0, const float* __restrict__ f1,
    const float* __restrict__ f2, const float* __restrict__ f3,
    const float* __restrict__ w0, const float* __restrict__ w1,
    const float* __restrict__ w2, const float* __restrict__ w3,
    const float* __restrict__ b0, const float* __restrict__ b1,
    const float* __restrict__ b2, const float* __restrict__ b3,
    float* __restrict__ gh, float* __restrict__ out)
{
  const int nb = blockIdx.x * 32;
  const int t  = threadIdx.x;
  int base, D;
  const float *F, *W, *Bv;
  if (nb < 4096)      { base = 0;    D = 128; F = f0; W = w0; Bv = b0; }
  else if (nb < 6144) { base = 4096; D = 64;  F = f1; W = w1; Bv = b1; }
  else if (nb < 7168) { base = 6144; D = 32;  F = f2; W = w2; Bv = b2; }
  else                { base = 7168; D = 16;  F = f3; W = w3; Bv = b3; }

  __shared__ float Fs[32 * 128];
  __shared__ float red[32][4];
  __shared__ float nrm[32];

  const int total = 32 * D;
  for (int i = t; i < total; i += 256) Fs[i] = F[(size_t)(nb - base) * D + i];
  __syncthreads();

  float acc[32];
  #pragma unroll
  for (int r = 0; r < 32; ++r) acc[r] = Bv[t];
  for (int d = 0; d < D; ++d) {
    float w = W[(size_t)d * 256 + t];
    #pragma unroll
    for (int r = 0; r < 32; ++r) acc[r] = fmaf(Fs[r * D + d], w, acc[r]);
  }

  const int lane = t & 63, wid = t >> 6;
  #pragma unroll
  for (int r = 0; r < 32; ++r) {
    float v = acc[r] * acc[r];
    for (int o = 32; o > 0; o >>= 1) v += __shfl_down(v, o, 64);
    if (lane == 0) red[r][wid] = v;
  }
  __syncthreads();
  if (t < 32) {
    float s = red[t][0] + red[t][1] + red[t][2] + red[t][3];
    nrm[t] = 1.0f / fmaxf(sqrtf(s), 1e-12f);
  }
  __syncthreads();
  #pragma unroll
  for (int r = 0; r < 32; ++r) {
    gh[(size_t)(nb + r) * 256 + t]  = acc[r];
    out[(size_t)(nb + r) * 768 + t] = acc[r] * nrm[r];
  }
}

// ---------------------------------------------------------------------------
// degree / CSR build
// ---------------------------------------------------------------------------
__global__ __launch_bounds__(256) void zero_counts(int* outc, int* inc) {
  int g = blockIdx.x * 256 + threadIdx.x;
  if (g < NN) outc[g] = 0; else inc[g - NN] = 0;
}
__global__ __launch_bounds__(256) void count_deg(const int* __restrict__ src,
                                                 const int* __restrict__ dst,
                                                 int* outc, int* inc) {
  int g = blockIdx.x * 256 + threadIdx.x;
  atomicAdd(&outc[src[g]], 1);
  atomicAdd(&inc[dst[g]], 1);
}
__global__ __launch_bounds__(256) void norm_kernel(const int* __restrict__ outc,
                                                   const int* __restrict__ inc,
                                                   float* n_out, float* n_in) {
  int g = blockIdx.x * 256 + threadIdx.x;
  n_out[g] = rsqrtf((float)outc[g] + 1.0f);
  n_in[g]  = rsqrtf((float)inc[g] + 1.0f);
}
__global__ __launch_bounds__(1024) void scan_kernel(const int* __restrict__ inc,
                                                    int* __restrict__ offs) {
  __shared__ int sums[1024];
  const int t = threadIdx.x;
  int x[8];
  const int base = t * 8;
  int s = 0;
  #pragma unroll
  for (int i = 0; i < 8; ++i) { int v = inc[base + i] + 1; x[i] = s; s += v; }
  sums[t] = s;
  __syncthreads();
  for (int off = 1; off < 1024; off <<= 1) {
    int a = (t >= off) ? sums[t - off] : 0;
    __syncthreads();
    sums[t] += a;
    __syncthreads();
  }
  const int pre = (t > 0) ? sums[t - 1] : 0;
  #pragma unroll
  for (int i = 0; i < 8; ++i) offs[base + i] = pre + x[i];
  if (t == 1023) offs[NN] = sums[1023];
}
__global__ __launch_bounds__(256) void copy_cur(const int* __restrict__ offs, int* cur) {
  int g = blockIdx.x * 256 + threadIdx.x;
  cur[g] = offs[g];
}
__global__ __launch_bounds__(256) void fill_csr(const int* __restrict__ src,
                                                const int* __restrict__ dst,
                                                int* cur, int* __restrict__ csr) {
  int g = blockIdx.x * 256 + threadIdx.x;   // EE + NN total
  int s, d;
  if (g < EE) { s = src[g]; d = dst[g]; }
  else        { s = g - EE; d = g - EE; }   // self-loops
  int pos = atomicAdd(&cur[d], 1);
  csr[pos] = s;
}
__global__ __launch_bounds__(256) void init_R(const float* __restrict__ type_emb,
                                              const int* __restrict__ nt,
                                              float* __restrict__ R) {
  int g = blockIdx.x * 256 + threadIdx.x;   // NN*4
  int n = g >> 2, c = g & 3;
  R[g] = type_emb[nt[n] * 4 + c];
}

// ---------------------------------------------------------------------------
// [M,256] @ [256,256] f32 register-tiled GEMM, 64x64 tile, 256 thr.
// ---------------------------------------------------------------------------
template<bool ROWSCALE, bool STORE, bool RED, typename CT>
__global__ __launch_bounds__(256) void gemm64_kernel(
    const float* __restrict__ A,
    const float* __restrict__ W,
    const float* __restrict__ rowscale,
    CT* __restrict__ C,
    const float* __restrict__ avec,
    float* __restrict__ SSo)
{
  const int m0 = blockIdx.x * 64;
  const int n0 = blockIdx.y * 64;
  const int t  = threadIdx.x;
  const int tr = t & 15, tc = t >> 4;
  __shared__ alignas(16) float As[32][68];
  __shared__ alignas(16) float Bs[32][68];
  __shared__ float red[64][2];
  float acc[4][4] = {};

  for (int ks = 0; ks < 8; ++ks) {
    const int k0 = ks * 32;
    #pragma unroll
    for (int rep = 0; rep < 8; ++rep) {
      int flat = rep * 256 + t;
      int r = flat >> 5, c = flat & 31;
      As[c][r] = A[(size_t)(m0 + r) * 256 + (k0 + c)];
      int rb = flat >> 6, cb = flat & 63;
      Bs[rb][cb] = W[(size_t)(k0 + rb) * 256 + (n0 + cb)];
    }
    __syncthreads();
    #pragma unroll
    for (int k = 0; k < 32; ++k) {
      const float4 a4 = *reinterpret_cast<const float4*>(&As[k][tr * 4]);
      const float4 b4 = *reinterpret_cast<const float4*>(&Bs[k][tc * 4]);
      const float av[4] = {a4.x, a4.y, a4.z, a4.w};
      const float bv[4] = {b4.x, b4.y, b4.z, b4.w};
      #pragma unroll
      for (int u = 0; u < 4; ++u)
        #pragma unroll
        for (int v = 0; v < 4; ++v)
          acc[u][v] = fmaf(av[u], bv[v], acc[u][v]);
    }
    __syncthreads();
  }

  if constexpr (ROWSCALE) {
    #pragma unroll
    for (int u = 0; u < 4; ++u) {
      float s = rowscale[m0 + tr * 4 + u];
      #pragma unroll
      for (int v = 0; v < 4; ++v) acc[u][v] *= s;
    }
  }
  if constexpr (STORE) {
    #pragma unroll
    for (int u = 0; u < 4; ++u) {
      size_t row = (size_t)(m0 + tr * 4 + u);
      #pragma unroll
      for (int v = 0; v < 4; ++v)
        storeC(&C[row * 256 + (n0 + tc * 4 + v)], acc[u][v]);
    }
  }
  if constexpr (RED) {
    if (t < 128) red[t >> 1][t & 1] = 0.f;
    __syncthreads();
    #pragma unroll
    for (int u = 0; u < 4; ++u) {
      float s = 0.f;
      #pragma unroll
      for (int v = 0; v < 4; ++v) {
        float x = acc[u][v];
        float lr = x > 0.f ? x : SLOPE * x;
        s += lr * avec[(tc * 4 + v) & 31];
      }
      atomicAdd(&red[tr * 4 + u][tc >> 3], s);
    }
    __syncthreads();
    if (t < 128) {
      int r = t >> 1, hh = t & 1;
      SSo[(size_t)(m0 + r) * 8 + blockIdx.y * 2 + hh] = red[r][hh];
    }
  }
}

// ---------------------------------------------------------------------------
// MFMA table GEMMs: C_z[8192,256](bf16) = A_z[8192,256](f32->bf16) @ W_z
// z in [0,5): {GW=GR1@Wfin, GW2=GR1@Wc2, GWL=GR1@Wcl, GHG=gh@Wg2, GHL=gh@Wgl2}
// 64x64 tile, 4 waves, each wave a 32x32 subtile via 16x16x32 bf16 MFMA.
// ---------------------------------------------------------------------------
__global__ __launch_bounds__(256) void mfma_tab_kernel(
    const float* __restrict__ GR1, const float* __restrict__ gh,
    const float* __restrict__ Wfin, const float* __restrict__ Wc2,
    const float* __restrict__ Wcl, const float* __restrict__ Wg2,
    const float* __restrict__ Wgl2,
    ushortT* __restrict__ GWo, ushortT* __restrict__ GW2o,
    ushortT* __restrict__ GWLo, ushortT* __restrict__ GHGo,
    ushortT* __restrict__ GHLo)
{
  const int z = blockIdx.z;
  const float* A = (z < 3) ? GR1 : gh;
  const float* W = (z == 0) ? Wfin : (z == 1) ? Wc2 : (z == 2) ? Wcl
                 : (z == 3) ? Wg2 : Wgl2;
  ushortT* C = (z == 0) ? GWo : (z == 1) ? GW2o : (z == 2) ? GWLo
             : (z == 3) ? GHGo : GHLo;

  const int m0 = blockIdx.x * 64;
  const int n0 = blockIdx.y * 64;
  const int t = threadIdx.x;
  const int w = t >> 6, l = t & 63;
  const int wr = w >> 1, wc = w & 1;       // wave's 32x32 subtile coords
  const int l15 = l & 15, l16 = l >> 4;

  __shared__ alignas(16) ushortT As[64][72];   // [m][k] bf16 (stride 144B)
  __shared__ alignas(16) ushortT Bs[64][72];   // [n][k] bf16 (B transposed)

  f32x4 acc[2][2];
  #pragma unroll
  for (int mh = 0; mh < 2; ++mh)
    #pragma unroll
    for (int nh = 0; nh < 2; ++nh)
      #pragma unroll
      for (int r = 0; r < 4; ++r) acc[mh][nh][r] = 0.f;

  for (int k0 = 0; k0 < 256; k0 += 64) {
    #pragma unroll
    for (int rep = 0; rep < 16; ++rep) {       // A: 4096 elems
      int flat = rep * 256 + t;
      int r = flat >> 6, k = flat & 63;
      As[r][k] = f2bu(A[(size_t)(m0 + r) * 256 + k0 + k]);
    }
    #pragma unroll
    for (int rep = 0; rep < 16; ++rep) {       // W -> Bs transposed
      int flat = rep * 256 + t;
      int k = flat >> 6, n = flat & 63;
      Bs[n][k] = f2bu(W[(size_t)(k0 + k) * 256 + n0 + n]);
    }
    __syncthreads();
    #pragma unroll
    for (int ks = 0; ks < 2; ++ks) {           // two K=32 sub-steps
      const int kb = ks * 32 + l16 * 8;
      bf16x8 afr[2], bfr[2];
      #pragma unroll
      for (int mh = 0; mh < 2; ++mh)
        afr[mh] = *reinterpret_cast<const bf16x8*>(&As[wr * 32 + mh * 16 + l15][kb]);
      #pragma unroll
      for (int nh = 0; nh < 2; ++nh)
        bfr[nh] = *reinterpret_cast<const bf16x8*>(&Bs[wc * 32 + nh * 16 + l15][kb]);
      #pragma unroll
      for (int mh = 0; mh < 2; ++mh)
        #pragma unroll
        for (int nh = 0; nh < 2; ++nh)
          acc[mh][nh] = __builtin_amdgcn_mfma_f32_16x16x32_bf16(
              afr[mh], bfr[nh], acc[mh][nh], 0, 0, 0);
    }
    __syncthreads();
  }
  // C/D layout (m89): col = lane&15, row = (lane>>4)*4 + reg
  #pragma unroll
  for (int mh = 0; mh < 2; ++mh)
    #pragma unroll
    for (int nh = 0; nh < 2; ++nh)
      #pragma unroll
      for (int r = 0; r < 4; ++r) {
        const int row = m0 + wr * 32 + mh * 16 + l16 * 4 + r;
        const int col = n0 + wc * 32 + nh * 16 + l15;
        C[(size_t)row * 256 + col] = f2bu(acc[mh][nh][r]);
      }
}

// ---------------------------------------------------------------------------
// GCN aggregate / REConv / RKQ
// ---------------------------------------------------------------------------
__global__ __launch_bounds__(256) void agg_kernel(
    const int* __restrict__ offs, const int* __restrict__ csr,
    const float* __restrict__ X, const float* __restrict__ n_in,
    const float* __restrict__ bias, float* __restrict__ ghn)
{
  const int n = blockIdx.x, t = threadIdx.x;
  const int s0 = offs[n], s1 = offs[n + 1];
  float acc = 0.f;
  for (int i = s0; i < s1; ++i) acc += X[(size_t)csr[i] * 256 + t];
  ghn[(size_t)n * 256 + t] = fmaxf(fmaf(acc, n_in[n], bias[t]), 0.f);
}
__global__ __launch_bounds__(256) void re_proj(
    const float* __restrict__ R, const float* __restrict__ n_out,
    const float* __restrict__ Wre, const float* __restrict__ wtre,
    const int* __restrict__ nt, float* __restrict__ rtmp)
{
  int g = blockIdx.x * 256 + threadIdx.x;  // NN*4
  int n = g >> 2, j = g & 3;
  float s = 0.f;
  #pragma unroll
  for (int c = 0; c < 4; ++c) s += R[n * 4 + c] * Wre[c * 4 + j];
  rtmp[g] = s * n_out[n] * wtre[nt[n]];
}
__global__ __launch_bounds__(256) void re_agg(
    const int* __restrict__ offs, const int* __restrict__ csr,
    const float* __restrict__ rtmp, const float* __restrict__ n_in,
    const float* __restrict__ bre, float* __restrict__ Rn)
{
  int g = blockIdx.x * 256 + threadIdx.x;  // NN*4
  int n = g >> 2, j = g & 3;
  float a = 0.f;
  for (int i = offs[n]; i < offs[n + 1]; ++i) a += rtmp[csr[i] * 4 + j];
  Rn[g] = fmaxf(fmaf(a, n_in[n], bre[j]), 0.f);
}
__global__ __launch_bounds__(256) void rkq_kernel(
    const float* __restrict__ R, const float* __restrict__ Wrs,
    const float* __restrict__ Wrt, float* __restrict__ RKQ)
{
  int g = blockIdx.x * 256 + threadIdx.x;  // NN*128
  int n = g >> 7, c = g & 127;
  int which = c >> 5, cc = c & 31;
  const float* Wp = (which == 0) ? Wrs : (which == 1) ? Wrt
                   : (which == 2) ? (Wrs + 128) : (Wrt + 128);
  float s = 0.f;
  #pragma unroll
  for (int r = 0; r < 4; ++r) s += R[n * 4 + r] * Wp[r * 32 + cc];
  RKQ[g] = s;
}

// ---------------------------------------------------------------------------
// weight prep: Wg2 = diag(g1)Wr2, Wgl2 = diag(g1)Wl2
// ---------------------------------------------------------------------------
__global__ __launch_bounds__(256) void scale_w_kernel(
    const float* __restrict__ ln_g, const float* __restrict__ Wr2,
    const float* __restrict__ Wl2, float* __restrict__ Wg2,
    float* __restrict__ Wgl2)
{
  int g = blockIdx.x * 256 + threadIdx.x;  // 65536
  float s = ln_g[g >> 8];
  Wg2[g]  = s * Wr2[g];
  Wgl2[g] = s * Wl2[g];
}
// vecs[0]=g1@Wr2, [1]=b1@Wr2, [2]=g1@Wl2, [3]=b1@Wl2
__global__ __launch_bounds__(256) void vec4_kernel(
    const float* __restrict__ ln_g, const float* __restrict__ ln_b,
    const float* __restrict__ Wr2, const float* __restrict__ Wl2,
    float* __restrict__ vecs)
{
  const int which = blockIdx.x, t = threadIdx.x;
  const float* W = (which < 2) ? Wr2 : Wl2;
  const float* s = (which & 1) ? ln_b : ln_g;
  float a = 0.f;
  for (int k = 0; k < 256; ++k) a = fmaf(s[k], W[(size_t)k * 256 + t], a);
  vecs[which * 256 + t] = a;
}

// ---------------------------------------------------------------------------
// MEGA2 v4: f32 LDS table staging — bf16 unpack happens ONCE at stage time
// (32/thread) instead of per-use (2048/thread). LDS ~72.5 KB, 2 blocks/CU.
// ---------------------------------------------------------------------------
__global__ __launch_bounds__(256) void mega2_kernel(
    const int* __restrict__ seqs,
    const float* __restrict__ gh,
    const ushortT* __restrict__ GW, const ushortT* __restrict__ GW2,
    const ushortT* __restrict__ GWL, const ushortT* __restrict__ GHG,
    const ushortT* __restrict__ GHL,
    const float* __restrict__ SLg, const float* __restrict__ SRg,
    const float* __restrict__ RKQ,
    const float* __restrict__ vecs,           // v1,v2,vl1,vl2
    const float* __restrict__ al2, const float* __restrict__ ar2,
    const float* __restrict__ ln_g, const float* __restrict__ ln_b,
    float* __restrict__ h1r0buf, float* __restrict__ ctx2buf,
    float* __restrict__ out)
{
  __shared__ int     idx[32];
  __shared__ alignas(16) float GWsF[32][260];  // stage: GW, then GW2 (f32)
  __shared__ ushortT FR2s[32][268];
  __shared__ float SLs[8][32], SRs[8][32];
  __shared__ float RKs[32][36];
  __shared__ float RQs[32][36];      // RQ1, then RQ2
  __shared__ float rk2s[32];
  __shared__ float p1r0[8][32];
  __shared__ float part[32][8], partq[32][8];
  __shared__ float mu_s[32], rs_s[32];
  __shared__ float SR2s[8][32];
  __shared__ float sl2s[8];
  __shared__ float scp[8][32];
  __shared__ float h1r0s[256];
  __shared__ float vs[1024];         // staged vecs
  __shared__ float wred4[4];
  __shared__ float nrm1s;

  const int b = blockIdx.x, t = threadIdx.x;
  const int h8 = t >> 5, lo = t & 31;
  const int c0 = h8 * 32;

  if (t < 32) idx[t] = seqs[b * 32 + t];
  __syncthreads();                                             // B1

  // ---- stage GW as f32 (unpack once), SL/SR, RK/RQ1, rk2, vecs ----
  {
    const uintT* GWu = reinterpret_cast<const uintT*>(GW);
    #pragma unroll
    for (int rep = 0; rep < 16; ++rep) {
      int flat = rep * 256 + t;             // 4096 uints
      int r = flat >> 7, c = flat & 127;
      const uintT u = GWu[(size_t)idx[r] * 128 + c];
      float2 f2; f2.x = blo(u); f2.y = bhi(u);
      *reinterpret_cast<float2*>(&GWsF[r][2 * c]) = f2;
    }
  }
  SLs[h8][lo] = SLg[(size_t)idx[lo] * 8 + h8];
  SRs[h8][lo] = SRg[(size_t)idx[lo] * 8 + h8];
  #pragma unroll
  for (int rep = 0; rep < 4; ++rep) {
    int flat = rep * 256 + t, s3 = flat >> 5, c3 = flat & 31;
    RKs[s3][c3] = RKQ[(size_t)idx[s3] * 128 + c3];
    RQs[s3][c3] = RKQ[(size_t)idx[s3] * 128 + 32 + c3];
    vs[flat] = vecs[flat];
  }
  if (t < 32) rk2s[t] = RKQ[(size_t)idx[0] * 128 + 64 + t];
  __syncthreads();                                             // B2

  // ---- attn1 scores+softmax: thread = (head h8, query row lo) ----
  float p1[32];
  {
    const float rk0 = RKs[lo][h8 * 4 + 0], rk1 = RKs[lo][h8 * 4 + 1],
                rk2 = RKs[lo][h8 * 4 + 2], rk3 = RKs[lo][h8 * 4 + 3];
    const float sli = SLs[h8][lo];
    float m = -1e30f;
    #pragma unroll
    for (int j = 0; j < 32; ++j) {
      float sc = sli + SRs[h8][j]
               + rk0 * RQs[j][h8 * 4 + 0] + rk1 * RQs[j][h8 * 4 + 1]
               + rk2 * RQs[j][h8 * 4 + 2] + rk3 * RQs[j][h8 * 4 + 3];
      p1[j] = sc; m = fmaxf(m, sc);
    }
    float sum = 0.f;
    #pragma unroll
    for (int j = 0; j < 32; ++j) { p1[j] = __expf(p1[j] - m); sum += p1[j]; }
    const float inv = 1.f / sum;
    #pragma unroll
    for (int j = 0; j < 32; ++j) p1[j] *= inv;
  }
  if (lo == 0) {
    #pragma unroll
    for (int j = 0; j < 32; ++j) p1r0[h8][j] = p1[j];
  }

  // ---- x phase (chunked, f32 LDS): stats only; row 0 stashed pre-LN ----
  {
    float xsum = 0.f, xsq = 0.f;
    const float4* gp4 = reinterpret_cast<const float4*>(&gh[(size_t)idx[lo] * 256 + c0]);
    #pragma unroll
    for (int ch = 0; ch < 4; ++ch) {
      float a[8];
      #pragma unroll
      for (int q = 0; q < 8; ++q) a[q] = 0.f;
      #pragma unroll 8
      for (int j = 0; j < 32; ++j) {
        const float pj = p1[j];
        const float4* rx = reinterpret_cast<const float4*>(&GWsF[j][c0 + ch * 8]);
        const float4 xa = rx[0], xb = rx[1];
        a[0] = fmaf(pj, xa.x, a[0]); a[1] = fmaf(pj, xa.y, a[1]);
        a[2] = fmaf(pj, xa.z, a[2]); a[3] = fmaf(pj, xa.w, a[3]);
        a[4] = fmaf(pj, xb.x, a[4]); a[5] = fmaf(pj, xb.y, a[5]);
        a[6] = fmaf(pj, xb.z, a[6]); a[7] = fmaf(pj, xb.w, a[7]);
      }
      const float4 g0 = gp4[ch * 2], g1 = gp4[ch * 2 + 1];
      a[0] += g0.x; a[1] += g0.y; a[2] += g0.z; a[3] += g0.w;
      a[4] += g1.x; a[5] += g1.y; a[6] += g1.z; a[7] += g1.w;
      #pragma unroll
      for (int q = 0; q < 8; ++q) { xsum += a[q]; xsq = fmaf(a[q], a[q], xsq); }
      if (lo == 0) {
        #pragma unroll
        for (int q = 0; q < 8; ++q) h1r0s[c0 + ch * 8 + q] = a[q];
      }
    }
    part[lo][h8]  = xsum;
    partq[lo][h8] = xsq;
  }
  __syncthreads();                                             // B3

  if (t < 32) {
    float sm = 0.f, sq = 0.f;
    #pragma unroll
    for (int h = 0; h < 8; ++h) { sm += part[t][h]; sq += partq[t][h]; }
    const float m = sm * (1.f / 256.f);
    const float v = fmaxf(sq * (1.f / 256.f) - m * m, 0.f);
    mu_s[t] = m;
    rs_s[t] = rsqrtf(v + LN_EPS);
  }
  __syncthreads();                                             // B4

  // ---- stage GW2 (f32) into GWsF, RQ2 into RQs; h1 row0 LN + ret1 partials ----
  {
    const uintT* GW2u = reinterpret_cast<const uintT*>(GW2);
    #pragma unroll
    for (int rep = 0; rep < 16; ++rep) {
      int flat = rep * 256 + t;
      int r = flat >> 7, c = flat & 127;
      const uintT u = GW2u[(size_t)idx[r] * 128 + c];
      float2 f2; f2.x = blo(u); f2.y = bhi(u);
      *reinterpret_cast<float2*>(&GWsF[r][2 * c]) = f2;
    }
  }
  #pragma unroll
  for (int rep = 0; rep < 4; ++rep) {
    int flat = rep * 256 + t, s3 = flat >> 5, c3 = flat & 31;
    RQs[s3][c3] = RKQ[(size_t)idx[s3] * 128 + 96 + c3];
  }
  {
    const float mu0 = mu_s[0], rs0 = rs_s[0];
    float hv = fmaf((h1r0s[t] - mu0) * rs0, ln_g[t], ln_b[t]);
    h1r0buf[(size_t)b * 256 + t] = hv;
    float sq = red64(hv * hv);
    h1r0s[t] = hv;                       // own col only; safe overwrite
    if ((t & 63) == 0) wred4[t >> 6] = sq;
  }
  __syncthreads();                                             // B5

  // ---- y phase (chunked, f32 LDS): FR2 bf16 + SR2 ----
  {
    const float rs = rs_s[lo];
    const float rm = rs * mu_s[lo];
    float sr2 = 0.f;
    #pragma unroll
    for (int ch = 0; ch < 4; ++ch) {
      float a[8];
      #pragma unroll
      for (int q = 0; q < 8; ++q) a[q] = 0.f;
      #pragma unroll 8
      for (int j = 0; j < 32; ++j) {
        const float pj = p1[j];
        const float4* ry = reinterpret_cast<const float4*>(&GWsF[j][c0 + ch * 8]);
        const float4 ya = ry[0], yb = ry[1];
        a[0] = fmaf(pj, ya.x, a[0]); a[1] = fmaf(pj, ya.y, a[1]);
        a[2] = fmaf(pj, ya.z, a[2]); a[3] = fmaf(pj, ya.w, a[3]);
        a[4] = fmaf(pj, yb.x, a[4]); a[5] = fmaf(pj, yb.y, a[5]);
        a[6] = fmaf(pj, yb.z, a[6]); a[7] = fmaf(pj, yb.w, a[7]);
      }
      const uintT* hg = reinterpret_cast<const uintT*>(&GHG[(size_t)idx[lo] * 256 + c0 + ch * 8]);
      #pragma unroll
      for (int q = 0; q < 4; ++q) {
        const uintT h2 = hg[q];
        a[2 * q + 0] += blo(h2);
        a[2 * q + 1] += bhi(h2);
      }
      uintT* fw = reinterpret_cast<uintT*>(&FR2s[lo][0]) + ((c0 + ch * 8) >> 1);
      #pragma unroll
      for (int q = 0; q < 4; ++q) {
        const int c = c0 + ch * 8 + 2 * q;
        const float fa = fmaf(rs, a[2 * q + 0], fmaf(-rm, vs[c],     vs[256 + c]));
        const float fb = fmaf(rs, a[2 * q + 1], fmaf(-rm, vs[c + 1], vs[256 + c + 1]));
        fw[q] = (uintT)f2bu(fa) | ((uintT)f2bu(fb) << 16);
        const float la = fa > 0.f ? fa : SLOPE * fa;
        const float lb = fb > 0.f ? fb : SLOPE * fb;
        sr2 = fmaf(la, ar2[ch * 8 + 2 * q], fmaf(lb, ar2[ch * 8 + 2 * q + 1], sr2));
      }
    }
    SR2s[h8][lo] = sr2;
  }

  // ---- fl2 row0 via tables: z0 = p1r0◦GWL + GHL[idx0] ; sl2 per head ----
  {
    float z0 = 0.f;
    #pragma unroll 8
    for (int j = 0; j < 32; ++j)
      z0 = fmaf(p1r0[h8][j], b2f(GWL[(size_t)idx[j] * 256 + t]), z0);
    z0 += b2f(GHL[(size_t)idx[0] * 256 + t]);
    const float rs0 = rs_s[0], rm0 = rs_s[0] * mu_s[0];
    const float fl = fmaf(rs0, z0, fmaf(-rm0, vs[512 + t], vs[768 + t]));
    float lr = (fl > 0.f ? fl : SLOPE * fl) * al2[lo];
    lr = red32(lr);
    if (lo == 0) sl2s[h8] = lr;
  }
  if (t == 0) nrm1s = 1.f / fmaxf(sqrtf(wred4[0] + wred4[1] + wred4[2] + wred4[3]), 1e-12f);
  __syncthreads();                                             // B6

  // ---- attn2 row0 scores (thread = (h8, key lo)) ----
  {
    float s2 = sl2s[h8] + SR2s[h8][lo]
             + rk2s[h8 * 4 + 0] * RQs[lo][h8 * 4 + 0]
             + rk2s[h8 * 4 + 1] * RQs[lo][h8 * 4 + 1]
             + rk2s[h8 * 4 + 2] * RQs[lo][h8 * 4 + 2]
             + rk2s[h8 * 4 + 3] * RQs[lo][h8 * 4 + 3];
    const float m2 = max32(s2);
    const float e = __expf(s2 - m2);
    const float su = red32(e);
    scp[h8][lo] = e / su;
  }
  __syncthreads();                                             // B7

  // ---- ctx2 = p2 ◦ FR2 (thread = col t) ; ret1 write ----
  {
    float a = 0.f;
    #pragma unroll
    for (int j = 0; j < 32; ++j) a = fmaf(scp[h8][j], b2f(FR2s[j][t]), a);
    ctx2buf[(size_t)b * 256 + t] = a;
  }
  out[(size_t)b * 768 + 256 + t] = h1r0s[t] * nrm1s;
}

// ---------------------------------------------------------------------------
// Epilogue: ret2 = l2n(LN(h1row0 + ctx2 @ Wfin2))  — 64 rows/block
// ---------------------------------------------------------------------------
__global__ __launch_bounds__(256) void final_ln_kernel(
    const float* __restrict__ A,       // ctx2buf [8192,256]
    const float* __restrict__ W,       // Wfin2
    const float* __restrict__ res,     // h1r0buf [8192,256]
    const float* __restrict__ lng, const float* __restrict__ lnb,
    float* __restrict__ out)
{
  const int m0 = blockIdx.x * 64;
  const int t  = threadIdx.x;
  const int tr = t & 15, tc = t >> 4;
  __shared__ alignas(16) float As[32][68];
  __shared__ alignas(16) float Bs[32][264];
  __shared__ float red[64][16];
  __shared__ float stat[64];
  float acc[4][16] = {};

  for (int ks = 0; ks < 8; ++ks) {
    const int k0 = ks * 32;
    #pragma unroll
    for (int rep = 0; rep < 8; ++rep) {
      int flat = rep * 256 + t;
      int r = flat >> 5, c = flat & 31;
      As[c][r] = A[(size_t)(m0 + r) * 256 + (k0 + c)];
    }
    #pragma unroll
    for (int rep = 0; rep < 32; ++rep) {
      int flat = rep * 256 + t;
      int rb = flat >> 8, cb = flat & 255;
      Bs[rb][cb] = W[(size_t)(k0 + rb) * 256 + cb];
    }
    __syncthreads();
    #pragma unroll
    for (int k = 0; k < 32; ++k) {
      const float4 a4 = *reinterpret_cast<const float4*>(&As[k][tr * 4]);
      const float av[4] = {a4.x, a4.y, a4.z, a4.w};
      #pragma unroll
      for (int q = 0; q < 4; ++q) {
        const float4 b4 = *reinterpret_cast<const float4*>(&Bs[k][tc * 16 + q * 4]);
        const float bv[4] = {b4.x, b4.y, b4.z, b4.w};
        #pragma unroll
        for (int u = 0; u < 4; ++u)
          #pragma unroll
          for (int v = 0; v < 4; ++v)
            acc[u][q * 4 + v] = fmaf(av[u], bv[v], acc[u][q * 4 + v]);
      }
    }
    __syncthreads();
  }

  int rows[4];
  #pragma unroll
  for (int u = 0; u < 4; ++u) rows[u] = m0 + tr * 4 + u;

  #pragma unroll
  for (int u = 0; u < 4; ++u) {
    const float* rp = &res[(size_t)rows[u] * 256 + tc * 16];
    #pragma unroll
    for (int v = 0; v < 16; ++v) acc[u][v] += rp[v];
  }
  #pragma unroll
  for (int u = 0; u < 4; ++u) {
    float s = 0.f;
    #pragma unroll
    for (int v = 0; v < 16; ++v) s += acc[u][v];
    red[tr * 4 + u][tc] = s;
  }
  __syncthreads();
  if (t < 64) {
    float s = 0.f;
    #pragma unroll
    for (int g = 0; g < 16; ++g) s += red[t][g];
    stat[t] = s * (1.0f / 256.0f);
  }
  __syncthreads();
  float mu[4];
  #pragma unroll
  for (int u = 0; u < 4; ++u) mu[u] = stat[tr * 4 + u];
  #pragma unroll
  for (int u = 0; u < 4; ++u) {
    float s = 0.f;
    #pragma unroll
    for (int v = 0; v < 16; ++v) { float d = acc[u][v] - mu[u]; s += d * d; }
    red[tr * 4 + u][tc] = s;
  }
  __syncthreads();
  if (t < 64) {
    float s = 0.f;
    #pragma unroll
    for (int g = 0; g < 16; ++g) s += red[t][g];
    stat[t] = rsqrtf(s * (1.0f / 256.0f) + LN_EPS);
  }
  __syncthreads();
  float rst[4];
  #pragma unroll
  for (int u = 0; u < 4; ++u) rst[u] = stat[tr * 4 + u];
  #pragma unroll
  for (int u = 0; u < 4; ++u) {
    float s = 0.f;
    #pragma unroll
    for (int v = 0; v < 16; ++v) {
      int col = tc * 16 + v;
      float yv = fmaf((acc[u][v] - mu[u]) * rst[u], lng[col], lnb[col]);
      acc[u][v] = yv;
      s += yv * yv;
    }
    red[tr * 4 + u][tc] = s;
  }
  __syncthreads();
  if (t < 64) {
    float s = 0.f;
    #pragma unroll
    for (int g = 0; g < 16; ++g) s += red[t][g];
    stat[t] = 1.0f / fmaxf(sqrtf(s), 1e-12f);
  }
  __syncthreads();
  #pragma unroll
  for (int u = 0; u < 4; ++u) {
    float rn = stat[tr * 4 + u];
    #pragma unroll
    for (int v = 0; v < 16; ++v)
      out[(size_t)rows[u] * 768 + 512 + tc * 16 + v] = acc[u][v] * rn;
  }
}

// ---------------------------------------------------------------------------
extern "C" void kernel_launch(void* const* d_in, const int* in_sizes, int n_in,
                              void* d_out, int out_size, void* d_ws, size_t ws_size,
                              hipStream_t stream)
{
  (void)in_sizes; (void)n_in; (void)out_size; (void)ws_size;

  const float* feat[4]; const float* wfc[4]; const float* bfc[4];
  for (int i = 0; i < 4; ++i) {
    feat[i] = (const float*)d_in[i * 3 + 0];
    wfc[i]  = (const float*)d_in[i * 3 + 1];
    bfc[i]  = (const float*)d_in[i * 3 + 2];
  }
  const float* type_emb = (const float*)d_in[12];
  const float* Wgcn = (const float*)d_in[13];
  const float* bgcn = (const float*)d_in[14];
  const float* Wre  = (const float*)d_in[15];
  const float* bre  = (const float*)d_in[16];
  const float* wtre = (const float*)d_in[17];
  const float* Wl   = (const float*)d_in[18];
  const float* Wr   = (const float*)d_in[19];
  const float* al   = (const float*)d_in[20];
  const float* ar   = (const float*)d_in[21];
  const float* Wrs  = (const float*)d_in[22];
  const float* Wrt  = (const float*)d_in[23];
  const float* Wfin = (const float*)d_in[24];
  const float* ln_g = (const float*)d_in[25];
  const float* ln_b = (const float*)d_in[26];
  const int* src       = (const int*)d_in[27];
  const int* dst       = (const int*)d_in[28];
  const int* node_type = (const int*)d_in[29];
  const int* seqs      = (const int*)d_in[30];
  float* out = (float*)d_out;

  // workspace carve-up (~50 MB)
  char* p = (char*)d_ws;
  auto take = [&](size_t n) { char* q = p; p += (n + 255) & ~(size_t)255; return q; };
  float* gh    = (float*)take((size_t)NN * 256 * 4);
  float* Xbuf  = (float*)take((size_t)NN * 256 * 4);   // GCN scratch, then ctx2buf
  float* GR1   = (float*)take((size_t)NN * 256 * 4);   // gh@Wr1, then h1r0buf
  float* RKQ   = (float*)take((size_t)NN * 128 * 4);
  float* SLg   = (float*)take((size_t)NN * 8 * 4);
  float* SRg   = (float*)take((size_t)NN * 8 * 4);
  float* n_out = (float*)take((size_t)NN * 4);
  float* n_in_ = (float*)take((size_t)NN * 4);
  int*   outc  = (int*)take((size_t)NN * 4);
  int*   inc   = (int*)take((size_t)NN * 4);
  int*   offs  = (int*)take((size_t)(NN + 1) * 4);
  int*   cur   = (int*)take((size_t)NN * 4);
  int*   csr   = (int*)take((size_t)(EE + NN) * 4);
  float* R     = (float*)take((size_t)NN * 4 * 4);
  float* rtmp  = (float*)take((size_t)NN * 4 * 4);
  ushortT* GW  = (ushortT*)take((size_t)NN * 256 * 2);
  ushortT* GW2 = (ushortT*)take((size_t)NN * 256 * 2);
  ushortT* GWL = (ushortT*)take((size_t)NN * 256 * 2);
  ushortT* GHG = (ushortT*)take((size_t)NN * 256 * 2);
  ushortT* GHL = (ushortT*)take((size_t)NN * 256 * 2);
  float* Wg2   = (float*)take((size_t)65536 * 4);
  float* Wgl2  = (float*)take((size_t)65536 * 4);
  float* Wc2   = (float*)take((size_t)65536 * 4);
  float* Wcl   = (float*)take((size_t)65536 * 4);
  float* vecs  = (float*)take((size_t)4 * 256 * 4);
  float* ctx2buf = Xbuf;   // alias: Xbuf dead after GCN
  float* h1r0buf = GR1;    // alias: GR1 dead after table GEMMs

  const float* Wr2 = Wr + 65536;
  const float* Wl2 = Wl + 65536;

  // 1) FC + ret0
  fc_kernel<<<256, 256, 0, stream>>>(feat[0], feat[1], feat[2], feat[3],
                                     wfc[0], wfc[1], wfc[2], wfc[3],
                                     bfc[0], bfc[1], bfc[2], bfc[3], gh, out);
  // 2) degrees + CSR
  zero_counts<<<64, 256, 0, stream>>>(outc, inc);
  count_deg<<<512, 256, 0, stream>>>(src, dst, outc, inc);
  norm_kernel<<<32, 256, 0, stream>>>(outc, inc, n_out, n_in_);
  scan_kernel<<<1, 1024, 0, stream>>>(inc, offs);
  copy_cur<<<32, 256, 0, stream>>>(offs, cur);
  fill_csr<<<544, 256, 0, stream>>>(src, dst, cur, csr);
  init_R<<<128, 256, 0, stream>>>(type_emb, node_type, R);

  // weight prep (independent of graph work)
  scale_w_kernel<<<256, 256, 0, stream>>>(ln_g, Wr2, Wl2, Wg2, Wgl2);
  vec4_kernel<<<4, 256, 0, stream>>>(ln_g, ln_b, Wr2, Wl2, vecs);
  gemm64_kernel<false, true, false, float>
      <<<dim3(4, 4), 256, 0, stream>>>(Wfin, Wg2, nullptr, Wc2, nullptr, nullptr);
  gemm64_kernel<false, true, false, float>
      <<<dim3(4, 4), 256, 0, stream>>>(Wfin, Wgl2, nullptr, Wcl, nullptr, nullptr);

  // 3) GCN + REConv, K=2
  for (int k = 0; k < 2; ++k) {
    gemm64_kernel<true, true, false, float>
        <<<dim3(128, 4), 256, 0, stream>>>(gh, Wgcn + (size_t)k * 65536,
                                           n_out, Xbuf, nullptr, nullptr);
    agg_kernel<<<NN, 256, 0, stream>>>(offs, csr, Xbuf, n_in_, bgcn + k * 256, gh);
    re_proj<<<128, 256, 0, stream>>>(R, n_out, Wre + k * 16, wtre + k * 4, node_type, rtmp);
    re_agg<<<128, 256, 0, stream>>>(offs, csr, rtmp, n_in_, bre + k * 4, R);
  }

  // 4) attention precomputes + node tables (tables via MFMA)
  rkq_kernel<<<4096, 256, 0, stream>>>(R, Wrs, Wrt, RKQ);
  gemm64_kernel<false, false, true, float>
      <<<dim3(128, 4), 256, 0, stream>>>(gh, Wl, nullptr, (float*)nullptr, al, SLg);
  gemm64_kernel<false, true, true, float>
      <<<dim3(128, 4), 256, 0, stream>>>(gh, Wr, nullptr, GR1, ar, SRg);
  mfma_tab_kernel<<<dim3(128, 4, 5), 256, 0, stream>>>(
      GR1, gh, Wfin, Wc2, Wcl, Wg2, Wgl2, GW, GW2, GWL, GHG, GHL);

  // 5) fused transformer (tables) -> ret1, h1r0, ctx2
  mega2_kernel<<<NN, 256, 0, stream>>>(seqs, gh, GW, GW2, GWL, GHG, GHL,
                                       SLg, SRg, RKQ, vecs,
                                       al + 32, ar + 32, ln_g, ln_b,
                                       h1r0buf, ctx2buf, out);

  // 6) epilogue: ret2 = l2n(LN(h1r0 + ctx2@Wfin2))
  final_ln_kernel<<<128, 256, 0, stream>>>(ctx2buf, Wfin + 65536, h1r0buf,
                                           ln_g + 256, ln_b + 256, out);
}

// Round 10
// 654.855 us; speedup vs baseline: 4.2208x; 1.0992x over previous
//
#include <hip/hip_runtime.h>
#include <hip/hip_bf16.h>
#include <cstdint>
#include <cstddef>

typedef unsigned short ushortT;
typedef unsigned int uintT;

using bf16x8 = __attribute__((ext_vector_type(8))) short;
using f32x4  = __attribute__((ext_vector_type(4))) float;

static constexpr int NN  = 8192;    // total nodes
static constexpr int EE  = 131072;  // edges
static constexpr float SLOPE  = 0.2f;
static constexpr float LN_EPS = 1e-5f;

#define DEVI __device__ __forceinline__

DEVI float red32(float v) {   // sum within 32-lane half
  #pragma unroll
  for (int m = 16; m >= 1; m >>= 1) v += __shfl_xor(v, m, 64);
  return v;
}
DEVI float red64(float v) {   // sum over full wave
  #pragma unroll
  for (int m = 32; m >= 1; m >>= 1) v += __shfl_xor(v, m, 64);
  return v;
}
DEVI float max32(float v) {
  #pragma unroll
  for (int m = 16; m >= 1; m >>= 1) v = fmaxf(v, __shfl_xor(v, m, 64));
  return v;
}
DEVI float blo(uintT u) { union { uintT i; float f; } c; c.i = u << 16; return c.f; }
DEVI float bhi(uintT u) { union { uintT i; float f; } c; c.i = u & 0xffff0000u; return c.f; }
DEVI float b2f(ushortT u) { union { uintT i; float f; } c; c.i = ((uintT)u) << 16; return c.f; }
DEVI ushortT f2bu(float f) {
  __hip_bfloat16 h = __float2bfloat16(f);
  return *reinterpret_cast<ushortT*>(&h);
}
DEVI void storeC(float* p, float v) { *p = v; }
DEVI void storeC(ushortT* p, float v) { *p = f2bu(v); }

// ---------------------------------------------------------------------------
// FC: gh[n] = feat_t[n] @ Wfc_t + bfc_t ; out[n,0:256] = l2n(gh[n])
// ---------------------------------------------------------------------------
__global__ __launch_bounds__(256) void fc_kernel(
    const float* __restrict__ f0, const float* __restrict__ f1,
    const float* __restrict__ f2, const float* __restrict__ f3,
    const float* __restrict__ w0, const float* __restrict__ w1,
    const float* __restrict__ w2, const float* __restrict__ w3,
    const float* __restrict__ b0, const float* __restrict__ b1,
    const float* __restrict__ b2, const float* __restrict__ b3,
    float* __restrict__ gh, float* __restrict__ out)
{
  const int nb = blockIdx.x * 32;
  const int t  = threadIdx.x;
  int base, D;
  const float *F, *W, *Bv;
  if (nb < 4096)      { base = 0;    D = 128; F = f0; W = w0; Bv = b0; }
  else if (nb < 6144) { base = 4096; D = 64;  F = f1; W = w1; Bv = b1; }
  else if (nb < 7168) { base = 6144; D = 32;  F = f2; W = w2; Bv = b2; }
  else                { base = 7168; D = 16;  F = f3; W = w3; Bv = b3; }

  __shared__ float Fs[32 * 128];
  __shared__ float red[32][4];
  __shared__ float nrm[32];

  const int total = 32 * D;
  for (int i = t; i < total; i += 256) Fs[i] = F[(size_t)(nb - base) * D + i];
  __syncthreads();

  float acc[32];
  #pragma unroll
  for (int r = 0; r < 32; ++r) acc[r] = Bv[t];
  for (int d = 0; d < D; ++d) {
    float w = W[(size_t)d * 256 + t];
    #pragma unroll
    for (int r = 0; r < 32; ++r) acc[r] = fmaf(Fs[r * D + d], w, acc[r]);
  }

  const int lane = t & 63, wid = t >> 6;
  #pragma unroll
  for (int r = 0; r < 32; ++r) {
    float v = acc[r] * acc[r];
    for (int o = 32; o > 0; o >>= 1) v += __shfl_down(v, o, 64);
    if (lane == 0) red[r][wid] = v;
  }
  __syncthreads();
  if (t < 32) {
    float s = red[t][0] + red[t][1] + red[t][2] + red[t][3];
    nrm[t] = 1.0f / fmaxf(sqrtf(s), 1e-12f);
  }
  __syncthreads();
  #pragma unroll
  for (int r = 0; r < 32; ++r) {
    gh[(size_t)(nb + r) * 256 + t]  = acc[r];
    out[(size_t)(nb + r) * 768 + t] = acc[r] * nrm[r];
  }
}

// ---------------------------------------------------------------------------
// degree / CSR build
// ---------------------------------------------------------------------------
__global__ __launch_bounds__(256) void zero_counts(int* outc, int* inc) {
  int g = blockIdx.x * 256 + threadIdx.x;
  if (g < NN) outc[g] = 0; else inc[g - NN] = 0;
}
__global__ __launch_bounds__(256) void count_deg(const int* __restrict__ src,
                                                 const int* __restrict__ dst,
                                                 int* outc, int* inc) {
  int g = blockIdx.x * 256 + threadIdx.x;
  atomicAdd(&outc[src[g]], 1);
  atomicAdd(&inc[dst[g]], 1);
}
__global__ __launch_bounds__(256) void norm_kernel(const int* __restrict__ outc,
                                                   const int* __restrict__ inc,
                                                   float* n_out, float* n_in) {
  int g = blockIdx.x * 256 + threadIdx.x;
  n_out[g] = rsqrtf((float)outc[g] + 1.0f);
  n_in[g]  = rsqrtf((float)inc[g] + 1.0f);
}
__global__ __launch_bounds__(1024) void scan_kernel(const int* __restrict__ inc,
                                                    int* __restrict__ offs) {
  __shared__ int sums[1024];
  const int t = threadIdx.x;
  int x[8];
  const int base = t * 8;
  int s = 0;
  #pragma unroll
  for (int i = 0; i < 8; ++i) { int v = inc[base + i] + 1; x[i] = s; s += v; }
  sums[t] = s;
  __syncthreads();
  for (int off = 1; off < 1024; off <<= 1) {
    int a = (t >= off) ? sums[t - off] : 0;
    __syncthreads();
    sums[t] += a;
    __syncthreads();
  }
  const int pre = (t > 0) ? sums[t - 1] : 0;
  #pragma unroll
  for (int i = 0; i < 8; ++i) offs[base + i] = pre + x[i];
  if (t == 1023) offs[NN] = sums[1023];
}
__global__ __launch_bounds__(256) void copy_cur(const int* __restrict__ offs, int* cur) {
  int g = blockIdx.x * 256 + threadIdx.x;
  cur[g] = offs[g];
}
__global__ __launch_bounds__(256) void fill_csr(const int* __restrict__ src,
                                                const int* __restrict__ dst,
                                                int* cur, int* __restrict__ csr) {
  int g = blockIdx.x * 256 + threadIdx.x;   // EE + NN total
  int s, d;
  if (g < EE) { s = src[g]; d = dst[g]; }
  else        { s = g - EE; d = g - EE; }   // self-loops
  int pos = atomicAdd(&cur[d], 1);
  csr[pos] = s;
}
__global__ __launch_bounds__(256) void init_R(const float* __restrict__ type_emb,
                                              const int* __restrict__ nt,
                                              float* __restrict__ R) {
  int g = blockIdx.x * 256 + threadIdx.x;   // NN*4
  int n = g >> 2, c = g & 3;
  R[g] = type_emb[nt[n] * 4 + c];
}

// ---------------------------------------------------------------------------
// [M,256] @ [256,256] f32 register-tiled GEMM, 64x64 tile, 256 thr.
// ---------------------------------------------------------------------------
template<bool ROWSCALE, bool STORE, bool RED, typename CT>
__global__ __launch_bounds__(256) void gemm64_kernel(
    const float* __restrict__ A,
    const float* __restrict__ W,
    const float* __restrict__ rowscale,
    CT* __restrict__ C,
    const float* __restrict__ avec,
    float* __restrict__ SSo)
{
  const int m0 = blockIdx.x * 64;
  const int n0 = blockIdx.y * 64;
  const int t  = threadIdx.x;
  const int tr = t & 15, tc = t >> 4;
  __shared__ alignas(16) float As[32][68];
  __shared__ alignas(16) float Bs[32][68];
  __shared__ float red[64][2];
  float acc[4][4] = {};

  for (int ks = 0; ks < 8; ++ks) {
    const int k0 = ks * 32;
    #pragma unroll
    for (int rep = 0; rep < 8; ++rep) {
      int flat = rep * 256 + t;
      int r = flat >> 5, c = flat & 31;
      As[c][r] = A[(size_t)(m0 + r) * 256 + (k0 + c)];
      int rb = flat >> 6, cb = flat & 63;
      Bs[rb][cb] = W[(size_t)(k0 + rb) * 256 + (n0 + cb)];
    }
    __syncthreads();
    #pragma unroll
    for (int k = 0; k < 32; ++k) {
      const float4 a4 = *reinterpret_cast<const float4*>(&As[k][tr * 4]);
      const float4 b4 = *reinterpret_cast<const float4*>(&Bs[k][tc * 4]);
      const float av[4] = {a4.x, a4.y, a4.z, a4.w};
      const float bv[4] = {b4.x, b4.y, b4.z, b4.w};
      #pragma unroll
      for (int u = 0; u < 4; ++u)
        #pragma unroll
        for (int v = 0; v < 4; ++v)
          acc[u][v] = fmaf(av[u], bv[v], acc[u][v]);
    }
    __syncthreads();
  }

  if constexpr (ROWSCALE) {
    #pragma unroll
    for (int u = 0; u < 4; ++u) {
      float s = rowscale[m0 + tr * 4 + u];
      #pragma unroll
      for (int v = 0; v < 4; ++v) acc[u][v] *= s;
    }
  }
  if constexpr (STORE) {
    #pragma unroll
    for (int u = 0; u < 4; ++u) {
      size_t row = (size_t)(m0 + tr * 4 + u);
      #pragma unroll
      for (int v = 0; v < 4; ++v)
        storeC(&C[row * 256 + (n0 + tc * 4 + v)], acc[u][v]);
    }
  }
  if constexpr (RED) {
    if (t < 128) red[t >> 1][t & 1] = 0.f;
    __syncthreads();
    #pragma unroll
    for (int u = 0; u < 4; ++u) {
      float s = 0.f;
      #pragma unroll
      for (int v = 0; v < 4; ++v) {
        float x = acc[u][v];
        float lr = x > 0.f ? x : SLOPE * x;
        s += lr * avec[(tc * 4 + v) & 31];
      }
      atomicAdd(&red[tr * 4 + u][tc >> 3], s);
    }
    __syncthreads();
    if (t < 128) {
      int r = t >> 1, hh = t & 1;
      SSo[(size_t)(m0 + r) * 8 + blockIdx.y * 2 + hh] = red[r][hh];
    }
  }
}

// ---------------------------------------------------------------------------
// MFMA table GEMMs: C_z[8192,256](bf16) = A_z[8192,256](f32->bf16) @ W_z
// ---------------------------------------------------------------------------
__global__ __launch_bounds__(256) void mfma_tab_kernel(
    const float* __restrict__ GR1, const float* __restrict__ gh,
    const float* __restrict__ Wfin, const float* __restrict__ Wc2,
    const float* __restrict__ Wcl, const float* __restrict__ Wg2,
    const float* __restrict__ Wgl2,
    ushortT* __restrict__ GWo, ushortT* __restrict__ GW2o,
    ushortT* __restrict__ GWLo, ushortT* __restrict__ GHGo,
    ushortT* __restrict__ GHLo)
{
  const int z = blockIdx.z;
  const float* A = (z < 3) ? GR1 : gh;
  const float* W = (z == 0) ? Wfin : (z == 1) ? Wc2 : (z == 2) ? Wcl
                 : (z == 3) ? Wg2 : Wgl2;
  ushortT* C = (z == 0) ? GWo : (z == 1) ? GW2o : (z == 2) ? GWLo
             : (z == 3) ? GHGo : GHLo;

  const int m0 = blockIdx.x * 64;
  const int n0 = blockIdx.y * 64;
  const int t = threadIdx.x;
  const int w = t >> 6, l = t & 63;
  const int wr = w >> 1, wc = w & 1;       // wave's 32x32 subtile coords
  const int l15 = l & 15, l16 = l >> 4;

  __shared__ alignas(16) ushortT As[64][72];   // [m][k] bf16
  __shared__ alignas(16) ushortT Bs[64][72];   // [n][k] bf16 (B transposed)

  f32x4 acc[2][2];
  #pragma unroll
  for (int mh = 0; mh < 2; ++mh)
    #pragma unroll
    for (int nh = 0; nh < 2; ++nh)
      #pragma unroll
      for (int r = 0; r < 4; ++r) acc[mh][nh][r] = 0.f;

  for (int k0 = 0; k0 < 256; k0 += 64) {
    #pragma unroll
    for (int rep = 0; rep < 16; ++rep) {       // A: 4096 elems
      int flat = rep * 256 + t;
      int r = flat >> 6, k = flat & 63;
      As[r][k] = f2bu(A[(size_t)(m0 + r) * 256 + k0 + k]);
    }
    #pragma unroll
    for (int rep = 0; rep < 16; ++rep) {       // W -> Bs transposed
      int flat = rep * 256 + t;
      int k = flat >> 6, n = flat & 63;
      Bs[n][k] = f2bu(W[(size_t)(k0 + k) * 256 + n0 + n]);
    }
    __syncthreads();
    #pragma unroll
    for (int ks = 0; ks < 2; ++ks) {           // two K=32 sub-steps
      const int kb = ks * 32 + l16 * 8;
      bf16x8 afr[2], bfr[2];
      #pragma unroll
      for (int mh = 0; mh < 2; ++mh)
        afr[mh] = *reinterpret_cast<const bf16x8*>(&As[wr * 32 + mh * 16 + l15][kb]);
      #pragma unroll
      for (int nh = 0; nh < 2; ++nh)
        bfr[nh] = *reinterpret_cast<const bf16x8*>(&Bs[wc * 32 + nh * 16 + l15][kb]);
      #pragma unroll
      for (int mh = 0; mh < 2; ++mh)
        #pragma unroll
        for (int nh = 0; nh < 2; ++nh)
          acc[mh][nh] = __builtin_amdgcn_mfma_f32_16x16x32_bf16(
              afr[mh], bfr[nh], acc[mh][nh], 0, 0, 0);
    }
    __syncthreads();
  }
  // C/D layout (m89): col = lane&15, row = (lane>>4)*4 + reg
  #pragma unroll
  for (int mh = 0; mh < 2; ++mh)
    #pragma unroll
    for (int nh = 0; nh < 2; ++nh)
      #pragma unroll
      for (int r = 0; r < 4; ++r) {
        const int row = m0 + wr * 32 + mh * 16 + l16 * 4 + r;
        const int col = n0 + wc * 32 + nh * 16 + l15;
        C[(size_t)row * 256 + col] = f2bu(acc[mh][nh][r]);
      }
}

// ---------------------------------------------------------------------------
// GCN aggregate / REConv / RKQ
// ---------------------------------------------------------------------------
__global__ __launch_bounds__(256) void agg_kernel(
    const int* __restrict__ offs, const int* __restrict__ csr,
    const float* __restrict__ X, const float* __restrict__ n_in,
    const float* __restrict__ bias, float* __restrict__ ghn)
{
  const int n = blockIdx.x, t = threadIdx.x;
  const int s0 = offs[n], s1 = offs[n + 1];
  float acc = 0.f;
  for (int i = s0; i < s1; ++i) acc += X[(size_t)csr[i] * 256 + t];
  ghn[(size_t)n * 256 + t] = fmaxf(fmaf(acc, n_in[n], bias[t]), 0.f);
}
__global__ __launch_bounds__(256) void re_proj(
    const float* __restrict__ R, const float* __restrict__ n_out,
    const float* __restrict__ Wre, const float* __restrict__ wtre,
    const int* __restrict__ nt, float* __restrict__ rtmp)
{
  int g = blockIdx.x * 256 + threadIdx.x;  // NN*4
  int n = g >> 2, j = g & 3;
  float s = 0.f;
  #pragma unroll
  for (int c = 0; c < 4; ++c) s += R[n * 4 + c] * Wre[c * 4 + j];
  rtmp[g] = s * n_out[n] * wtre[nt[n]];
}
__global__ __launch_bounds__(256) void re_agg(
    const int* __restrict__ offs, const int* __restrict__ csr,
    const float* __restrict__ rtmp, const float* __restrict__ n_in,
    const float* __restrict__ bre, float* __restrict__ Rn)
{
  int g = blockIdx.x * 256 + threadIdx.x;  // NN*4
  int n = g >> 2, j = g & 3;
  float a = 0.f;
  for (int i = offs[n]; i < offs[n + 1]; ++i) a += rtmp[csr[i] * 4 + j];
  Rn[g] = fmaxf(fmaf(a, n_in[n], bre[j]), 0.f);
}
__global__ __launch_bounds__(256) void rkq_kernel(
    const float* __restrict__ R, const float* __restrict__ Wrs,
    const float* __restrict__ Wrt, float* __restrict__ RKQ)
{
  int g = blockIdx.x * 256 + threadIdx.x;  // NN*128
  int n = g >> 7, c = g & 127;
  int which = c >> 5, cc = c & 31;
  const float* Wp = (which == 0) ? Wrs : (which == 1) ? Wrt
                   : (which == 2) ? (Wrs + 128) : (Wrt + 128);
  float s = 0.f;
  #pragma unroll
  for (int r = 0; r < 4; ++r) s += R[n * 4 + r] * Wp[r * 32 + cc];
  RKQ[g] = s;
}

// ---------------------------------------------------------------------------
// weight prep
// ---------------------------------------------------------------------------
__global__ __launch_bounds__(256) void scale_w_kernel(
    const float* __restrict__ ln_g, const float* __restrict__ Wr2,
    const float* __restrict__ Wl2, float* __restrict__ Wg2,
    float* __restrict__ Wgl2)
{
  int g = blockIdx.x * 256 + threadIdx.x;  // 65536
  float s = ln_g[g >> 8];
  Wg2[g]  = s * Wr2[g];
  Wgl2[g] = s * Wl2[g];
}
__global__ __launch_bounds__(256) void vec4_kernel(
    const float* __restrict__ ln_g, const float* __restrict__ ln_b,
    const float* __restrict__ Wr2, const float* __restrict__ Wl2,
    float* __restrict__ vecs)
{
  const int which = blockIdx.x, t = threadIdx.x;
  const float* W = (which < 2) ? Wr2 : Wl2;
  const float* s = (which & 1) ? ln_b : ln_g;
  float a = 0.f;
  for (int k = 0; k < 256; ++k) a = fmaf(s[k], W[(size_t)k * 256 + t], a);
  vecs[which * 256 + t] = a;
}

// ---------------------------------------------------------------------------
// MEGA3: combines on MFMA. P (bf16) in LDS as A; GW/GW2 staged TRANSPOSED
// [col][j] bf16 as B. Per wave: 2 heads x 4 MFMA x 2 phases = 16 MFMA,
// replacing 512 ds_read_b128 + 2048 VALU FMA per thread. ~78 KB LDS.
// ---------------------------------------------------------------------------
__global__ __launch_bounds__(256) void mega3_kernel(
    const int* __restrict__ seqs,
    const float* __restrict__ gh,
    const ushortT* __restrict__ GW, const ushortT* __restrict__ GW2,
    const ushortT* __restrict__ GWL, const ushortT* __restrict__ GHG,
    const ushortT* __restrict__ GHL,
    const float* __restrict__ SLg, const float* __restrict__ SRg,
    const float* __restrict__ RKQ,
    const float* __restrict__ vecs,           // v1,v2,vl1,vl2
    const float* __restrict__ al2, const float* __restrict__ ar2,
    const float* __restrict__ ln_g, const float* __restrict__ ln_b,
    float* __restrict__ h1r0buf, float* __restrict__ ctx2buf,
    float* __restrict__ out)
{
  __shared__ int idx[32];
  __shared__ alignas(16) ushortT GT[256][40];   // GW^T then GW2^T (bf16)
  __shared__ alignas(16) ushortT Pl[8][32][40]; // P bf16 [head][row][j]
  __shared__ ushortT FR2s[32][268];
  __shared__ float SLs[8][32], SRs[8][32];
  __shared__ float RKs[32][36];
  __shared__ float RQs[32][36];      // RQ1, then RQ2
  __shared__ float rk2s[32];
  __shared__ float part[32][4], partq[32][4];
  __shared__ float mu_s[32], rs_s[32];
  __shared__ float SR2s[8][32];
  __shared__ float sl2s[8];
  __shared__ float scp[8][32];
  __shared__ float h1r0s[256];
  __shared__ float vs[1024];
  __shared__ float wred4[4];
  __shared__ float nrm1s;

  const int b = blockIdx.x, t = threadIdx.x;
  const int h8 = t >> 5, lo = t & 31;
  const int w = t >> 6, l = t & 63;
  const int l15 = l & 15, l16 = l >> 4;

  if (t < 32) idx[t] = seqs[b * 32 + t];
  __syncthreads();                                             // B1

  // ---- stage GT = GW^T (bf16), SL/SR, RK/RQ1, rk2, vs ----
  {
    const uintT* GWu = reinterpret_cast<const uintT*>(GW);
    #pragma unroll
    for (int rep = 0; rep < 16; ++rep) {
      int flat = rep * 256 + t;             // 4096 u32
      int j = flat >> 7, cp = flat & 127;
      const uintT u = GWu[(size_t)idx[j] * 128 + cp];
      GT[2 * cp][j]     = (ushortT)(u & 0xffffu);
      GT[2 * cp + 1][j] = (ushortT)(u >> 16);
    }
  }
  SLs[h8][lo] = SLg[(size_t)idx[lo] * 8 + h8];
  SRs[h8][lo] = SRg[(size_t)idx[lo] * 8 + h8];
  #pragma unroll
  for (int rep = 0; rep < 4; ++rep) {
    int flat = rep * 256 + t, s3 = flat >> 5, c3 = flat & 31;
    RKs[s3][c3] = RKQ[(size_t)idx[s3] * 128 + c3];
    RQs[s3][c3] = RKQ[(size_t)idx[s3] * 128 + 32 + c3];
    vs[flat] = vecs[flat];
  }
  if (t < 32) rk2s[t] = RKQ[(size_t)idx[0] * 128 + 64 + t];
  __syncthreads();                                             // B2

  // ---- attn1 scores+softmax: thread = (head h8, query row lo) -> Pl ----
  {
    float p1[32];
    const float rk0 = RKs[lo][h8 * 4 + 0], rk1 = RKs[lo][h8 * 4 + 1],
                rk2 = RKs[lo][h8 * 4 + 2], rk3 = RKs[lo][h8 * 4 + 3];
    const float sli = SLs[h8][lo];
    float m = -1e30f;
    #pragma unroll
    for (int j = 0; j < 32; ++j) {
      float sc = sli + SRs[h8][j]
               + rk0 * RQs[j][h8 * 4 + 0] + rk1 * RQs[j][h8 * 4 + 1]
               + rk2 * RQs[j][h8 * 4 + 2] + rk3 * RQs[j][h8 * 4 + 3];
      p1[j] = sc; m = fmaxf(m, sc);
    }
    float sum = 0.f;
    #pragma unroll
    for (int j = 0; j < 32; ++j) { p1[j] = __expf(p1[j] - m); sum += p1[j]; }
    const float inv = 1.f / sum;
    uintT* pw = reinterpret_cast<uintT*>(&Pl[h8][lo][0]);
    #pragma unroll
    for (int q = 0; q < 16; ++q)
      pw[q] = (uintT)f2bu(p1[2 * q] * inv) | ((uintT)f2bu(p1[2 * q + 1] * inv) << 16);
  }
  __syncthreads();                                             // B3

  // per-lane row indices (rows this lane's C-fragments touch)
  int irow[2][4];
  #pragma unroll
  for (int mh = 0; mh < 2; ++mh)
    #pragma unroll
    for (int r = 0; r < 4; ++r)
      irow[mh][r] = idx[mh * 16 + l16 * 4 + r];

  f32x4 acc[2][2][2];   // [head-half hh][mh][nh]

  // ---- x phase: MFMA combine + gh residual + LN stats + h1row0 stash ----
  #pragma unroll
  for (int hh = 0; hh < 2; ++hh) {
    const int h = 2 * w + hh;
    bf16x8 af[2], bf[2];
    #pragma unroll
    for (int mh = 0; mh < 2; ++mh)
      af[mh] = *reinterpret_cast<const bf16x8*>(&Pl[h][mh * 16 + l15][l16 * 8]);
    #pragma unroll
    for (int nh = 0; nh < 2; ++nh)
      bf[nh] = *reinterpret_cast<const bf16x8*>(&GT[h * 32 + nh * 16 + l15][l16 * 8]);
    #pragma unroll
    for (int mh = 0; mh < 2; ++mh)
      #pragma unroll
      for (int nh = 0; nh < 2; ++nh) {
        f32x4 z = {0.f, 0.f, 0.f, 0.f};
        acc[hh][mh][nh] = __builtin_amdgcn_mfma_f32_16x16x32_bf16(af[mh], bf[nh], z, 0, 0, 0);
      }
  }
  {
    float sum_[2][4], sq_[2][4];
    #pragma unroll
    for (int mh = 0; mh < 2; ++mh)
      #pragma unroll
      for (int r = 0; r < 4; ++r) { sum_[mh][r] = 0.f; sq_[mh][r] = 0.f; }
    #pragma unroll
    for (int hh = 0; hh < 2; ++hh)
      #pragma unroll
      for (int mh = 0; mh < 2; ++mh)
        #pragma unroll
        for (int nh = 0; nh < 2; ++nh) {
          const int col = (2 * w + hh) * 32 + nh * 16 + l15;
          #pragma unroll
          for (int r = 0; r < 4; ++r) {
            float v = acc[hh][mh][nh][r] + gh[(size_t)irow[mh][r] * 256 + col];
            acc[hh][mh][nh][r] = v;
            sum_[mh][r] += v;
            sq_[mh][r] = fmaf(v, v, sq_[mh][r]);
          }
        }
    #pragma unroll
    for (int mh = 0; mh < 2; ++mh)
      #pragma unroll
      for (int r = 0; r < 4; ++r) {
        float s = sum_[mh][r], q = sq_[mh][r];
        #pragma unroll
        for (int m = 8; m >= 1; m >>= 1) {
          s += __shfl_xor(s, m, 64);
          q += __shfl_xor(q, m, 64);
        }
        if (l15 == 0) {
          part[mh * 16 + l16 * 4 + r][w]  = s;
          partq[mh * 16 + l16 * 4 + r][w] = q;
        }
      }
    if (l16 == 0) {
      #pragma unroll
      for (int hh = 0; hh < 2; ++hh)
        #pragma unroll
        for (int nh = 0; nh < 2; ++nh)
          h1r0s[(2 * w + hh) * 32 + nh * 16 + l15] = acc[hh][0][nh][0];
    }
  }
  __syncthreads();                                             // B4

  if (t < 32) {
    float sm = part[t][0] + part[t][1] + part[t][2] + part[t][3];
    float sq = partq[t][0] + partq[t][1] + partq[t][2] + partq[t][3];
    const float m = sm * (1.f / 256.f);
    const float v = fmaxf(sq * (1.f / 256.f) - m * m, 0.f);
    mu_s[t] = m;
    rs_s[t] = rsqrtf(v + LN_EPS);
  }
  // restage GT = GW2^T; RQ2
  {
    const uintT* GW2u = reinterpret_cast<const uintT*>(GW2);
    #pragma unroll
    for (int rep = 0; rep < 16; ++rep) {
      int flat = rep * 256 + t;
      int j = flat >> 7, cp = flat & 127;
      const uintT u = GW2u[(size_t)idx[j] * 128 + cp];
      GT[2 * cp][j]     = (ushortT)(u & 0xffffu);
      GT[2 * cp + 1][j] = (ushortT)(u >> 16);
    }
  }
  #pragma unroll
  for (int rep = 0; rep < 4; ++rep) {
    int flat = rep * 256 + t, s3 = flat >> 5, c3 = flat & 31;
    RQs[s3][c3] = RKQ[(size_t)idx[s3] * 128 + 96 + c3];
  }
  __syncthreads();                                             // B5

  // ---- h1 row0 LN + ret1 partials ----
  {
    const float mu0 = mu_s[0], rs0 = rs_s[0];
    float hv = fmaf((h1r0s[t] - mu0) * rs0, ln_g[t], ln_b[t]);
    h1r0buf[(size_t)b * 256 + t] = hv;
    float sq = red64(hv * hv);
    h1r0s[t] = hv;
    if ((t & 63) == 0) wred4[t >> 6] = sq;
  }

  // ---- y phase: MFMA + GHG residual -> FR2 bf16 + SR2 ----
  #pragma unroll
  for (int hh = 0; hh < 2; ++hh) {
    const int h = 2 * w + hh;
    bf16x8 af[2], bf[2];
    #pragma unroll
    for (int mh = 0; mh < 2; ++mh)
      af[mh] = *reinterpret_cast<const bf16x8*>(&Pl[h][mh * 16 + l15][l16 * 8]);
    #pragma unroll
    for (int nh = 0; nh < 2; ++nh)
      bf[nh] = *reinterpret_cast<const bf16x8*>(&GT[h * 32 + nh * 16 + l15][l16 * 8]);
    #pragma unroll
    for (int mh = 0; mh < 2; ++mh)
      #pragma unroll
      for (int nh = 0; nh < 2; ++nh) {
        f32x4 z = {0.f, 0.f, 0.f, 0.f};
        acc[hh][mh][nh] = __builtin_amdgcn_mfma_f32_16x16x32_bf16(af[mh], bf[nh], z, 0, 0, 0);
      }
  }
  {
    float rsv[2][4], rmv[2][4];
    #pragma unroll
    for (int mh = 0; mh < 2; ++mh)
      #pragma unroll
      for (int r = 0; r < 4; ++r) {
        const int row = mh * 16 + l16 * 4 + r;
        rsv[mh][r] = rs_s[row];
        rmv[mh][r] = rsv[mh][r] * mu_s[row];
      }
    float ar2v[2];
    ar2v[0] = ar2[l15];
    ar2v[1] = ar2[16 + l15];
    float sacc[2][2][4];
    #pragma unroll
    for (int hh = 0; hh < 2; ++hh)
      #pragma unroll
      for (int mh = 0; mh < 2; ++mh)
        #pragma unroll
        for (int r = 0; r < 4; ++r) sacc[hh][mh][r] = 0.f;

    #pragma unroll
    for (int hh = 0; hh < 2; ++hh)
      #pragma unroll
      for (int mh = 0; mh < 2; ++mh)
        #pragma unroll
        for (int nh = 0; nh < 2; ++nh) {
          const int col = (2 * w + hh) * 32 + nh * 16 + l15;
          #pragma unroll
          for (int r = 0; r < 4; ++r) {
            const int row = mh * 16 + l16 * 4 + r;
            float yv = acc[hh][mh][nh][r] + b2f(GHG[(size_t)irow[mh][r] * 256 + col]);
            float fa = fmaf(rsv[mh][r], yv, fmaf(-rmv[mh][r], vs[col], vs[256 + col]));
            FR2s[row][col] = f2bu(fa);
            float lr = fa > 0.f ? fa : SLOPE * fa;
            sacc[hh][mh][r] = fmaf(lr, ar2v[nh], sacc[hh][mh][r]);
          }
        }
    #pragma unroll
    for (int hh = 0; hh < 2; ++hh)
      #pragma unroll
      for (int mh = 0; mh < 2; ++mh)
        #pragma unroll
        for (int r = 0; r < 4; ++r) {
          float s = sacc[hh][mh][r];
          #pragma unroll
          for (int m = 8; m >= 1; m >>= 1) s += __shfl_xor(s, m, 64);
          if (l15 == 0) SR2s[2 * w + hh][mh * 16 + l16 * 4 + r] = s;
        }
  }

  // ---- fl2 row0: z0 = P[h][0]◦GWL + GHL[idx0] ; sl2 per head ----
  {
    float z0 = 0.f;
    #pragma unroll 8
    for (int j = 0; j < 32; ++j)
      z0 = fmaf(b2f(Pl[h8][0][j]), b2f(GWL[(size_t)idx[j] * 256 + t]), z0);
    z0 += b2f(GHL[(size_t)idx[0] * 256 + t]);
    const float rs0 = rs_s[0], rm0 = rs_s[0] * mu_s[0];
    const float fl = fmaf(rs0, z0, fmaf(-rm0, vs[512 + t], vs[768 + t]));
    float lr = (fl > 0.f ? fl : SLOPE * fl) * al2[lo];
    lr = red32(lr);
    if (lo == 0) sl2s[h8] = lr;
  }
  __syncthreads();                                             // B6

  if (t == 0) nrm1s = 1.f / fmaxf(sqrtf(wred4[0] + wred4[1] + wred4[2] + wred4[3]), 1e-12f);
  // ---- attn2 row0 scores (thread = (h8, key lo)) ----
  {
    float s2 = sl2s[h8] + SR2s[h8][lo]
             + rk2s[h8 * 4 + 0] * RQs[lo][h8 * 4 + 0]
             + rk2s[h8 * 4 + 1] * RQs[lo][h8 * 4 + 1]
             + rk2s[h8 * 4 + 2] * RQs[lo][h8 * 4 + 2]
             + rk2s[h8 * 4 + 3] * RQs[lo][h8 * 4 + 3];
    const float m2 = max32(s2);
    const float e = __expf(s2 - m2);
    const float su = red32(e);
    scp[h8][lo] = e / su;
  }
  __syncthreads();                                             // B7

  // ---- ctx2 = p2 ◦ FR2 ; ret1 write ----
  {
    float a = 0.f;
    #pragma unroll
    for (int j = 0; j < 32; ++j) a = fmaf(scp[h8][j], b2f(FR2s[j][t]), a);
    ctx2buf[(size_t)b * 256 + t] = a;
  }
  out[(size_t)b * 768 + 256 + t] = h1r0s[t] * nrm1s;
}

// ---------------------------------------------------------------------------
// Epilogue: ret2 = l2n(LN(h1row0 + ctx2 @ Wfin2))  — 64 rows/block
// ---------------------------------------------------------------------------
__global__ __launch_bounds__(256) void final_ln_kernel(
    const float* __restrict__ A,
    const float* __restrict__ W,
    const float* __restrict__ res,
    const float* __restrict__ lng, const float* __restrict__ lnb,
    float* __restrict__ out)
{
  const int m0 = blockIdx.x * 64;
  const int t  = threadIdx.x;
  const int tr = t & 15, tc = t >> 4;
  __shared__ alignas(16) float As[32][68];
  __shared__ alignas(16) float Bs[32][264];
  __shared__ float red[64][16];
  __shared__ float stat[64];
  float acc[4][16] = {};

  for (int ks = 0; ks < 8; ++ks) {
    const int k0 = ks * 32;
    #pragma unroll
    for (int rep = 0; rep < 8; ++rep) {
      int flat = rep * 256 + t;
      int r = flat >> 5, c = flat & 31;
      As[c][r] = A[(size_t)(m0 + r) * 256 + (k0 + c)];
    }
    #pragma unroll
    for (int rep = 0; rep < 32; ++rep) {
      int flat = rep * 256 + t;
      int rb = flat >> 8, cb = flat & 255;
      Bs[rb][cb] = W[(size_t)(k0 + rb) * 256 + cb];
    }
    __syncthreads();
    #pragma unroll
    for (int k = 0; k < 32; ++k) {
      const float4 a4 = *reinterpret_cast<const float4*>(&As[k][tr * 4]);
      const float av[4] = {a4.x, a4.y, a4.z, a4.w};
      #pragma unroll
      for (int q = 0; q < 4; ++q) {
        const float4 b4 = *reinterpret_cast<const float4*>(&Bs[k][tc * 16 + q * 4]);
        const float bv[4] = {b4.x, b4.y, b4.z, b4.w};
        #pragma unroll
        for (int u = 0; u < 4; ++u)
          #pragma unroll
          for (int v = 0; v < 4; ++v)
            acc[u][q * 4 + v] = fmaf(av[u], bv[v], acc[u][q * 4 + v]);
      }
    }
    __syncthreads();
  }

  int rows[4];
  #pragma unroll
  for (int u = 0; u < 4; ++u) rows[u] = m0 + tr * 4 + u;

  #pragma unroll
  for (int u = 0; u < 4; ++u) {
    const float* rp = &res[(size_t)rows[u] * 256 + tc * 16];
    #pragma unroll
    for (int v = 0; v < 16; ++v) acc[u][v] += rp[v];
  }
  #pragma unroll
  for (int u = 0; u < 4; ++u) {
    float s = 0.f;
    #pragma unroll
    for (int v = 0; v < 16; ++v) s += acc[u][v];
    red[tr * 4 + u][tc] = s;
  }
  __syncthreads();
  if (t < 64) {
    float s = 0.f;
    #pragma unroll
    for (int g = 0; g < 16; ++g) s += red[t][g];
    stat[t] = s * (1.0f / 256.0f);
  }
  __syncthreads();
  float mu[4];
  #pragma unroll
  for (int u = 0; u < 4; ++u) mu[u] = stat[tr * 4 + u];
  #pragma unroll
  for (int u = 0; u < 4; ++u) {
    float s = 0.f;
    #pragma unroll
    for (int v = 0; v < 16; ++v) { float d = acc[u][v] - mu[u]; s += d * d; }
    red[tr * 4 + u][tc] = s;
  }
  __syncthreads();
  if (t < 64) {
    float s = 0.f;
    #pragma unroll
    for (int g = 0; g < 16; ++g) s += red[t][g];
    stat[t] = rsqrtf(s * (1.0f / 256.0f) + LN_EPS);
  }
  __syncthreads();
  float rst[4];
  #pragma unroll
  for (int u = 0; u < 4; ++u) rst[u] = stat[tr * 4 + u];
  #pragma unroll
  for (int u = 0; u < 4; ++u) {
    float s = 0.f;
    #pragma unroll
    for (int v = 0; v < 16; ++v) {
      int col = tc * 16 + v;
      float yv = fmaf((acc[u][v] - mu[u]) * rst[u], lng[col], lnb[col]);
      acc[u][v] = yv;
      s += yv * yv;
    }
    red[tr * 4 + u][tc] = s;
  }
  __syncthreads();
  if (t < 64) {
    float s = 0.f;
    #pragma unroll
    for (int g = 0; g < 16; ++g) s += red[t][g];
    stat[t] = 1.0f / fmaxf(sqrtf(s), 1e-12f);
  }
  __syncthreads();
  #pragma unroll
  for (int u = 0; u < 4; ++u) {
    float rn = stat[tr * 4 + u];
    #pragma unroll
    for (int v = 0; v < 16; ++v)
      out[(size_t)rows[u] * 768 + 512 + tc * 16 + v] = acc[u][v] * rn;
  }
}

// ---------------------------------------------------------------------------
extern "C" void kernel_launch(void* const* d_in, const int* in_sizes, int n_in,
                              void* d_out, int out_size, void* d_ws, size_t ws_size,
                              hipStream_t stream)
{
  (void)in_sizes; (void)n_in; (void)out_size; (void)ws_size;

  const float* feat[4]; const float* wfc[4]; const float* bfc[4];
  for (int i = 0; i < 4; ++i) {
    feat[i] = (const float*)d_in[i * 3 + 0];
    wfc[i]  = (const float*)d_in[i * 3 + 1];
    bfc[i]  = (const float*)d_in[i * 3 + 2];
  }
  const float* type_emb = (const float*)d_in[12];
  const float* Wgcn = (const float*)d_in[13];
  const float* bgcn = (const float*)d_in[14];
  const float* Wre  = (const float*)d_in[15];
  const float* bre  = (const float*)d_in[16];
  const float* wtre = (const float*)d_in[17];
  const float* Wl   = (const float*)d_in[18];
  const float* Wr   = (const float*)d_in[19];
  const float* al   = (const float*)d_in[20];
  const float* ar   = (const float*)d_in[21];
  const float* Wrs  = (const float*)d_in[22];
  const float* Wrt  = (const float*)d_in[23];
  const float* Wfin = (const float*)d_in[24];
  const float* ln_g = (const float*)d_in[25];
  const float* ln_b = (const float*)d_in[26];
  const int* src       = (const int*)d_in[27];
  const int* dst       = (const int*)d_in[28];
  const int* node_type = (const int*)d_in[29];
  const int* seqs      = (const int*)d_in[30];
  float* out = (float*)d_out;

  // workspace carve-up (~50 MB)
  char* p = (char*)d_ws;
  auto take = [&](size_t n) { char* q = p; p += (n + 255) & ~(size_t)255; return q; };
  float* gh    = (float*)take((size_t)NN * 256 * 4);
  float* Xbuf  = (float*)take((size_t)NN * 256 * 4);   // GCN scratch, then ctx2buf
  float* GR1   = (float*)take((size_t)NN * 256 * 4);   // gh@Wr1, then h1r0buf
  float* RKQ   = (float*)take((size_t)NN * 128 * 4);
  float* SLg   = (float*)take((size_t)NN * 8 * 4);
  float* SRg   = (float*)take((size_t)NN * 8 * 4);
  float* n_out = (float*)take((size_t)NN * 4);
  float* n_in_ = (float*)take((size_t)NN * 4);
  int*   outc  = (int*)take((size_t)NN * 4);
  int*   inc   = (int*)take((size_t)NN * 4);
  int*   offs  = (int*)take((size_t)(NN + 1) * 4);
  int*   cur   = (int*)take((size_t)NN * 4);
  int*   csr   = (int*)take((size_t)(EE + NN) * 4);
  float* R     = (float*)take((size_t)NN * 4 * 4);
  float* rtmp  = (float*)take((size_t)NN * 4 * 4);
  ushortT* GW  = (ushortT*)take((size_t)NN * 256 * 2);
  ushortT* GW2 = (ushortT*)take((size_t)NN * 256 * 2);
  ushortT* GWL = (ushortT*)take((size_t)NN * 256 * 2);
  ushortT* GHG = (ushortT*)take((size_t)NN * 256 * 2);
  ushortT* GHL = (ushortT*)take((size_t)NN * 256 * 2);
  float* Wg2   = (float*)take((size_t)65536 * 4);
  float* Wgl2  = (float*)take((size_t)65536 * 4);
  float* Wc2   = (float*)take((size_t)65536 * 4);
  float* Wcl   = (float*)take((size_t)65536 * 4);
  float* vecs  = (float*)take((size_t)4 * 256 * 4);
  float* ctx2buf = Xbuf;   // alias: Xbuf dead after GCN
  float* h1r0buf = GR1;    // alias: GR1 dead after table GEMMs

  const float* Wr2 = Wr + 65536;
  const float* Wl2 = Wl + 65536;

  // 1) FC + ret0
  fc_kernel<<<256, 256, 0, stream>>>(feat[0], feat[1], feat[2], feat[3],
                                     wfc[0], wfc[1], wfc[2], wfc[3],
                                     bfc[0], bfc[1], bfc[2], bfc[3], gh, out);
  // 2) degrees + CSR
  zero_counts<<<64, 256, 0, stream>>>(outc, inc);
  count_deg<<<512, 256, 0, stream>>>(src, dst, outc, inc);
  norm_kernel<<<32, 256, 0, stream>>>(outc, inc, n_out, n_in_);
  scan_kernel<<<1, 1024, 0, stream>>>(inc, offs);
  copy_cur<<<32, 256, 0, stream>>>(offs, cur);
  fill_csr<<<544, 256, 0, stream>>>(src, dst, cur, csr);
  init_R<<<128, 256, 0, stream>>>(type_emb, node_type, R);

  // weight prep (independent of graph work)
  scale_w_kernel<<<256, 256, 0, stream>>>(ln_g, Wr2, Wl2, Wg2, Wgl2);
  vec4_kernel<<<4, 256, 0, stream>>>(ln_g, ln_b, Wr2, Wl2, vecs);
  gemm64_kernel<false, true, false, float>
      <<<dim3(4, 4), 256, 0, stream>>>(Wfin, Wg2, nullptr, Wc2, nullptr, nullptr);
  gemm64_kernel<false, true, false, float>
      <<<dim3(4, 4), 256, 0, stream>>>(Wfin, Wgl2, nullptr, Wcl, nullptr, nullptr);

  // 3) GCN + REConv, K=2
  for (int k = 0; k < 2; ++k) {
    gemm64_kernel<true, true, false, float>
        <<<dim3(128, 4), 256, 0, stream>>>(gh, Wgcn + (size_t)k * 65536,
                                           n_out, Xbuf, nullptr, nullptr);
    agg_kernel<<<NN, 256, 0, stream>>>(offs, csr, Xbuf, n_in_, bgcn + k * 256, gh);
    re_proj<<<128, 256, 0, stream>>>(R, n_out, Wre + k * 16, wtre + k * 4, node_type, rtmp);
    re_agg<<<128, 256, 0, stream>>>(offs, csr, rtmp, n_in_, bre + k * 4, R);
  }

  // 4) attention precomputes + node tables (tables via MFMA)
  rkq_kernel<<<4096, 256, 0, stream>>>(R, Wrs, Wrt, RKQ);
  gemm64_kernel<false, false, true, float>
      <<<dim3(128, 4), 256, 0, stream>>>(gh, Wl, nullptr, (float*)nullptr, al, SLg);
  gemm64_kernel<false, true, true, float>
      <<<dim3(128, 4), 256, 0, stream>>>(gh, Wr, nullptr, GR1, ar, SRg);
  mfma_tab_kernel<<<dim3(128, 4, 5), 256, 0, stream>>>(
      GR1, gh, Wfin, Wc2, Wcl, Wg2, Wgl2, GW, GW2, GWL, GHG, GHL);

  // 5) fused transformer (MFMA combines) -> ret1, h1r0, ctx2
  mega3_kernel<<<NN, 256, 0, stream>>>(seqs, gh, GW, GW2, GWL, GHG, GHL,
                                       SLg, SRg, RKQ, vecs,
                                       al + 32, ar + 32, ln_g, ln_b,
                                       h1r0buf, ctx2buf, out);

  // 6) epilogue: ret2 = l2n(LN(h1r0 + ctx2@Wfin2))
  final_ln_kernel<<<128, 256, 0, stream>>>(ctx2buf, Wfin + 65536, h1r0buf,
                                           ln_g + 256, ln_b + 256, out);
}

// Round 11
// 627.189 us; speedup vs baseline: 4.4070x; 1.0441x over previous
//
#include <hip/hip_runtime.h>
#include <hip/hip_bf16.h>
#include <cstdint>
#include <cstddef>

typedef unsigned short ushortT;
typedef unsigned int uintT;

using bf16x8 = __attribute__((ext_vector_type(8))) short;
using f32x4  = __attribute__((ext_vector_type(4))) float;

static constexpr int NN  = 8192;    // total nodes
static constexpr int EE  = 131072;  // edges
static constexpr float SLOPE  = 0.2f;
static constexpr float LN_EPS = 1e-5f;

#define DEVI __device__ __forceinline__

DEVI float red32(float v) {   // sum within 32-lane half
  #pragma unroll
  for (int m = 16; m >= 1; m >>= 1) v += __shfl_xor(v, m, 64);
  return v;
}
DEVI float red64(float v) {   // sum over full wave
  #pragma unroll
  for (int m = 32; m >= 1; m >>= 1) v += __shfl_xor(v, m, 64);
  return v;
}
DEVI float max32(float v) {
  #pragma unroll
  for (int m = 16; m >= 1; m >>= 1) v = fmaxf(v, __shfl_xor(v, m, 64));
  return v;
}
DEVI float blo(uintT u) { union { uintT i; float f; } c; c.i = u << 16; return c.f; }
DEVI float bhi(uintT u) { union { uintT i; float f; } c; c.i = u & 0xffff0000u; return c.f; }
DEVI float b2f(ushortT u) { union { uintT i; float f; } c; c.i = ((uintT)u) << 16; return c.f; }
DEVI ushortT f2bu(float f) {
  __hip_bfloat16 h = __float2bfloat16(f);
  return *reinterpret_cast<ushortT*>(&h);
}
DEVI void storeC(float* p, float v) { *p = v; }
DEVI void storeC(ushortT* p, float v) { *p = f2bu(v); }

// ---------------------------------------------------------------------------
// FC: gh[n] = feat_t[n] @ Wfc_t + bfc_t ; out[n,0:256] = l2n(gh[n])
// ---------------------------------------------------------------------------
__global__ __launch_bounds__(256) void fc_kernel(
    const float* __restrict__ f0, const float* __restrict__ f1,
    const float* __restrict__ f2, const float* __restrict__ f3,
    const float* __restrict__ w0, const float* __restrict__ w1,
    const float* __restrict__ w2, const float* __restrict__ w3,
    const float* __restrict__ b0, const float* __restrict__ b1,
    const float* __restrict__ b2, const float* __restrict__ b3,
    float* __restrict__ gh, float* __restrict__ out)
{
  const int nb = blockIdx.x * 32;
  const int t  = threadIdx.x;
  int base, D;
  const float *F, *W, *Bv;
  if (nb < 4096)      { base = 0;    D = 128; F = f0; W = w0; Bv = b0; }
  else if (nb < 6144) { base = 4096; D = 64;  F = f1; W = w1; Bv = b1; }
  else if (nb < 7168) { base = 6144; D = 32;  F = f2; W = w2; Bv = b2; }
  else                { base = 7168; D = 16;  F = f3; W = w3; Bv = b3; }

  __shared__ float Fs[32 * 128];
  __shared__ float red[32][4];
  __shared__ float nrm[32];

  const int total = 32 * D;
  for (int i = t; i < total; i += 256) Fs[i] = F[(size_t)(nb - base) * D + i];
  __syncthreads();

  float acc[32];
  #pragma unroll
  for (int r = 0; r < 32; ++r) acc[r] = Bv[t];
  for (int d = 0; d < D; ++d) {
    float w = W[(size_t)d * 256 + t];
    #pragma unroll
    for (int r = 0; r < 32; ++r) acc[r] = fmaf(Fs[r * D + d], w, acc[r]);
  }

  const int lane = t & 63, wid = t >> 6;
  #pragma unroll
  for (int r = 0; r < 32; ++r) {
    float v = acc[r] * acc[r];
    for (int o = 32; o > 0; o >>= 1) v += __shfl_down(v, o, 64);
    if (lane == 0) red[r][wid] = v;
  }
  __syncthreads();
  if (t < 32) {
    float s = red[t][0] + red[t][1] + red[t][2] + red[t][3];
    nrm[t] = 1.0f / fmaxf(sqrtf(s), 1e-12f);
  }
  __syncthreads();
  #pragma unroll
  for (int r = 0; r < 32; ++r) {
    gh[(size_t)(nb + r) * 256 + t]  = acc[r];
    out[(size_t)(nb + r) * 768 + t] = acc[r] * nrm[r];
  }
}

// ---------------------------------------------------------------------------
// degree / CSR build
// ---------------------------------------------------------------------------
__global__ __launch_bounds__(256) void zero_counts(int* outc, int* inc) {
  int g = blockIdx.x * 256 + threadIdx.x;
  if (g < NN) outc[g] = 0; else inc[g - NN] = 0;
}
__global__ __launch_bounds__(256) void count_deg(const int* __restrict__ src,
                                                 const int* __restrict__ dst,
                                                 int* outc, int* inc) {
  int g = blockIdx.x * 256 + threadIdx.x;
  atomicAdd(&outc[src[g]], 1);
  atomicAdd(&inc[dst[g]], 1);
}
__global__ __launch_bounds__(256) void norm_kernel(const int* __restrict__ outc,
                                                   const int* __restrict__ inc,
                                                   float* n_out, float* n_in) {
  int g = blockIdx.x * 256 + threadIdx.x;
  n_out[g] = rsqrtf((float)outc[g] + 1.0f);
  n_in[g]  = rsqrtf((float)inc[g] + 1.0f);
}
__global__ __launch_bounds__(1024) void scan_kernel(const int* __restrict__ inc,
                                                    int* __restrict__ offs) {
  __shared__ int sums[1024];
  const int t = threadIdx.x;
  int x[8];
  const int base = t * 8;
  int s = 0;
  #pragma unroll
  for (int i = 0; i < 8; ++i) { int v = inc[base + i] + 1; x[i] = s; s += v; }
  sums[t] = s;
  __syncthreads();
  for (int off = 1; off < 1024; off <<= 1) {
    int a = (t >= off) ? sums[t - off] : 0;
    __syncthreads();
    sums[t] += a;
    __syncthreads();
  }
  const int pre = (t > 0) ? sums[t - 1] : 0;
  #pragma unroll
  for (int i = 0; i < 8; ++i) offs[base + i] = pre + x[i];
  if (t == 1023) offs[NN] = sums[1023];
}
__global__ __launch_bounds__(256) void copy_cur(const int* __restrict__ offs, int* cur) {
  int g = blockIdx.x * 256 + threadIdx.x;
  cur[g] = offs[g];
}
__global__ __launch_bounds__(256) void fill_csr(const int* __restrict__ src,
                                                const int* __restrict__ dst,
                                                int* cur, int* __restrict__ csr) {
  int g = blockIdx.x * 256 + threadIdx.x;   // EE + NN total
  int s, d;
  if (g < EE) { s = src[g]; d = dst[g]; }
  else        { s = g - EE; d = g - EE; }   // self-loops
  int pos = atomicAdd(&cur[d], 1);
  csr[pos] = s;
}
__global__ __launch_bounds__(256) void init_R(const float* __restrict__ type_emb,
                                              const int* __restrict__ nt,
                                              float* __restrict__ R) {
  int g = blockIdx.x * 256 + threadIdx.x;   // NN*4
  int n = g >> 2, c = g & 3;
  R[g] = type_emb[nt[n] * 4 + c];
}

// ---------------------------------------------------------------------------
// [M,256] @ [256,256] f32 register-tiled GEMM, 64x64 tile, 256 thr.
// ---------------------------------------------------------------------------
template<bool ROWSCALE, bool STORE, bool RED, typename CT>
__global__ __launch_bounds__(256) void gemm64_kernel(
    const float* __restrict__ A,
    const float* __restrict__ W,
    const float* __restrict__ rowscale,
    CT* __restrict__ C,
    const float* __restrict__ avec,
    float* __restrict__ SSo)
{
  const int m0 = blockIdx.x * 64;
  const int n0 = blockIdx.y * 64;
  const int t  = threadIdx.x;
  const int tr = t & 15, tc = t >> 4;
  __shared__ alignas(16) float As[32][68];
  __shared__ alignas(16) float Bs[32][68];
  __shared__ float red[64][2];
  float acc[4][4] = {};

  for (int ks = 0; ks < 8; ++ks) {
    const int k0 = ks * 32;
    #pragma unroll
    for (int rep = 0; rep < 8; ++rep) {
      int flat = rep * 256 + t;
      int r = flat >> 5, c = flat & 31;
      As[c][r] = A[(size_t)(m0 + r) * 256 + (k0 + c)];
      int rb = flat >> 6, cb = flat & 63;
      Bs[rb][cb] = W[(size_t)(k0 + rb) * 256 + (n0 + cb)];
    }
    __syncthreads();
    #pragma unroll
    for (int k = 0; k < 32; ++k) {
      const float4 a4 = *reinterpret_cast<const float4*>(&As[k][tr * 4]);
      const float4 b4 = *reinterpret_cast<const float4*>(&Bs[k][tc * 4]);
      const float av[4] = {a4.x, a4.y, a4.z, a4.w};
      const float bv[4] = {b4.x, b4.y, b4.z, b4.w};
      #pragma unroll
      for (int u = 0; u < 4; ++u)
        #pragma unroll
        for (int v = 0; v < 4; ++v)
          acc[u][v] = fmaf(av[u], bv[v], acc[u][v]);
    }
    __syncthreads();
  }

  if constexpr (ROWSCALE) {
    #pragma unroll
    for (int u = 0; u < 4; ++u) {
      float s = rowscale[m0 + tr * 4 + u];
      #pragma unroll
      for (int v = 0; v < 4; ++v) acc[u][v] *= s;
    }
  }
  if constexpr (STORE) {
    #pragma unroll
    for (int u = 0; u < 4; ++u) {
      size_t row = (size_t)(m0 + tr * 4 + u);
      #pragma unroll
      for (int v = 0; v < 4; ++v)
        storeC(&C[row * 256 + (n0 + tc * 4 + v)], acc[u][v]);
    }
  }
  if constexpr (RED) {
    if (t < 128) red[t >> 1][t & 1] = 0.f;
    __syncthreads();
    #pragma unroll
    for (int u = 0; u < 4; ++u) {
      float s = 0.f;
      #pragma unroll
      for (int v = 0; v < 4; ++v) {
        float x = acc[u][v];
        float lr = x > 0.f ? x : SLOPE * x;
        s += lr * avec[(tc * 4 + v) & 31];
      }
      atomicAdd(&red[tr * 4 + u][tc >> 3], s);
    }
    __syncthreads();
    if (t < 128) {
      int r = t >> 1, hh = t & 1;
      SSo[(size_t)(m0 + r) * 8 + blockIdx.y * 2 + hh] = red[r][hh];
    }
  }
}

// ---------------------------------------------------------------------------
// MFMA table GEMMs: C_z[8192,256](bf16) = A_z[8192,256](f32->bf16) @ W_z
// ---------------------------------------------------------------------------
__global__ __launch_bounds__(256) void mfma_tab_kernel(
    const float* __restrict__ GR1, const float* __restrict__ gh,
    const float* __restrict__ Wfin, const float* __restrict__ Wc2,
    const float* __restrict__ Wcl, const float* __restrict__ Wg2,
    const float* __restrict__ Wgl2,
    ushortT* __restrict__ GWo, ushortT* __restrict__ GW2o,
    ushortT* __restrict__ GWLo, ushortT* __restrict__ GHGo,
    ushortT* __restrict__ GHLo)
{
  const int z = blockIdx.z;
  const float* A = (z < 3) ? GR1 : gh;
  const float* W = (z == 0) ? Wfin : (z == 1) ? Wc2 : (z == 2) ? Wcl
                 : (z == 3) ? Wg2 : Wgl2;
  ushortT* C = (z == 0) ? GWo : (z == 1) ? GW2o : (z == 2) ? GWLo
             : (z == 3) ? GHGo : GHLo;

  const int m0 = blockIdx.x * 64;
  const int n0 = blockIdx.y * 64;
  const int t = threadIdx.x;
  const int w = t >> 6, l = t & 63;
  const int wr = w >> 1, wc = w & 1;       // wave's 32x32 subtile coords
  const int l15 = l & 15, l16 = l >> 4;

  __shared__ alignas(16) ushortT As[64][72];   // [m][k] bf16
  __shared__ alignas(16) ushortT Bs[64][72];   // [n][k] bf16 (B transposed)

  f32x4 acc[2][2];
  #pragma unroll
  for (int mh = 0; mh < 2; ++mh)
    #pragma unroll
    for (int nh = 0; nh < 2; ++nh)
      #pragma unroll
      for (int r = 0; r < 4; ++r) acc[mh][nh][r] = 0.f;

  for (int k0 = 0; k0 < 256; k0 += 64) {
    #pragma unroll
    for (int rep = 0; rep < 16; ++rep) {       // A: 4096 elems
      int flat = rep * 256 + t;
      int r = flat >> 6, k = flat & 63;
      As[r][k] = f2bu(A[(size_t)(m0 + r) * 256 + k0 + k]);
    }
    #pragma unroll
    for (int rep = 0; rep < 16; ++rep) {       // W -> Bs transposed
      int flat = rep * 256 + t;
      int k = flat >> 6, n = flat & 63;
      Bs[n][k] = f2bu(W[(size_t)(k0 + k) * 256 + n0 + n]);
    }
    __syncthreads();
    #pragma unroll
    for (int ks = 0; ks < 2; ++ks) {           // two K=32 sub-steps
      const int kb = ks * 32 + l16 * 8;
      bf16x8 afr[2], bfr[2];
      #pragma unroll
      for (int mh = 0; mh < 2; ++mh)
        afr[mh] = *reinterpret_cast<const bf16x8*>(&As[wr * 32 + mh * 16 + l15][kb]);
      #pragma unroll
      for (int nh = 0; nh < 2; ++nh)
        bfr[nh] = *reinterpret_cast<const bf16x8*>(&Bs[wc * 32 + nh * 16 + l15][kb]);
      #pragma unroll
      for (int mh = 0; mh < 2; ++mh)
        #pragma unroll
        for (int nh = 0; nh < 2; ++nh)
          acc[mh][nh] = __builtin_amdgcn_mfma_f32_16x16x32_bf16(
              afr[mh], bfr[nh], acc[mh][nh], 0, 0, 0);
    }
    __syncthreads();
  }
  // C/D layout (m89): col = lane&15, row = (lane>>4)*4 + reg
  #pragma unroll
  for (int mh = 0; mh < 2; ++mh)
    #pragma unroll
    for (int nh = 0; nh < 2; ++nh)
      #pragma unroll
      for (int r = 0; r < 4; ++r) {
        const int row = m0 + wr * 32 + mh * 16 + l16 * 4 + r;
        const int col = n0 + wc * 32 + nh * 16 + l15;
        C[(size_t)row * 256 + col] = f2bu(acc[mh][nh][r]);
      }
}

// ---------------------------------------------------------------------------
// GCN aggregate / REConv / RKQ
// ---------------------------------------------------------------------------
__global__ __launch_bounds__(256) void agg_kernel(
    const int* __restrict__ offs, const int* __restrict__ csr,
    const float* __restrict__ X, const float* __restrict__ n_in,
    const float* __restrict__ bias, float* __restrict__ ghn)
{
  const int n = blockIdx.x, t = threadIdx.x;
  const int s0 = offs[n], s1 = offs[n + 1];
  float acc = 0.f;
  for (int i = s0; i < s1; ++i) acc += X[(size_t)csr[i] * 256 + t];
  ghn[(size_t)n * 256 + t] = fmaxf(fmaf(acc, n_in[n], bias[t]), 0.f);
}
__global__ __launch_bounds__(256) void re_proj(
    const float* __restrict__ R, const float* __restrict__ n_out,
    const float* __restrict__ Wre, const float* __restrict__ wtre,
    const int* __restrict__ nt, float* __restrict__ rtmp)
{
  int g = blockIdx.x * 256 + threadIdx.x;  // NN*4
  int n = g >> 2, j = g & 3;
  float s = 0.f;
  #pragma unroll
  for (int c = 0; c < 4; ++c) s += R[n * 4 + c] * Wre[c * 4 + j];
  rtmp[g] = s * n_out[n] * wtre[nt[n]];
}
__global__ __launch_bounds__(256) void re_agg(
    const int* __restrict__ offs, const int* __restrict__ csr,
    const float* __restrict__ rtmp, const float* __restrict__ n_in,
    const float* __restrict__ bre, float* __restrict__ Rn)
{
  int g = blockIdx.x * 256 + threadIdx.x;  // NN*4
  int n = g >> 2, j = g & 3;
  float a = 0.f;
  for (int i = offs[n]; i < offs[n + 1]; ++i) a += rtmp[csr[i] * 4 + j];
  Rn[g] = fmaxf(fmaf(a, n_in[n], bre[j]), 0.f);
}
__global__ __launch_bounds__(256) void rkq_kernel(
    const float* __restrict__ R, const float* __restrict__ Wrs,
    const float* __restrict__ Wrt, float* __restrict__ RKQ)
{
  int g = blockIdx.x * 256 + threadIdx.x;  // NN*128
  int n = g >> 7, c = g & 127;
  int which = c >> 5, cc = c & 31;
  const float* Wp = (which == 0) ? Wrs : (which == 1) ? Wrt
                   : (which == 2) ? (Wrs + 128) : (Wrt + 128);
  float s = 0.f;
  #pragma unroll
  for (int r = 0; r < 4; ++r) s += R[n * 4 + r] * Wp[r * 32 + cc];
  RKQ[g] = s;
}

// ---------------------------------------------------------------------------
// weight prep
// ---------------------------------------------------------------------------
__global__ __launch_bounds__(256) void scale_w_kernel(
    const float* __restrict__ ln_g, const float* __restrict__ Wr2,
    const float* __restrict__ Wl2, float* __restrict__ Wg2,
    float* __restrict__ Wgl2)
{
  int g = blockIdx.x * 256 + threadIdx.x;  // 65536
  float s = ln_g[g >> 8];
  Wg2[g]  = s * Wr2[g];
  Wgl2[g] = s * Wl2[g];
}
__global__ __launch_bounds__(256) void vec4_kernel(
    const float* __restrict__ ln_g, const float* __restrict__ ln_b,
    const float* __restrict__ Wr2, const float* __restrict__ Wl2,
    float* __restrict__ vecs)
{
  const int which = blockIdx.x, t = threadIdx.x;
  const float* W = (which < 2) ? Wr2 : Wl2;
  const float* s = (which & 1) ? ln_b : ln_g;
  float a = 0.f;
  for (int k = 0; k < 256; ++k) a = fmaf(s[k], W[(size_t)k * 256 + t], a);
  vecs[which * 256 + t] = a;
}

// ---------------------------------------------------------------------------
// MEGA4: mega3 + (a) XOR k-octet swizzle on GT/Pl (kills 16-way staging-write
// bank conflicts; read side swizzled identically, still one aligned b128),
// (b) LDS 78->50 KB (Pl/FR2 union, fl2 moved pre-y, A-frags cached in VGPRs,
// SLs/RKs/vs dropped for direct loads) -> 3 blocks/CU.
// ---------------------------------------------------------------------------
__global__ __launch_bounds__(256) void mega4_kernel(
    const int* __restrict__ seqs,
    const float* __restrict__ gh,
    const ushortT* __restrict__ GW, const ushortT* __restrict__ GW2,
    const ushortT* __restrict__ GWL, const ushortT* __restrict__ GHG,
    const ushortT* __restrict__ GHL,
    const float* __restrict__ SLg, const float* __restrict__ SRg,
    const float* __restrict__ RKQ,
    const float* __restrict__ vecs,           // v1,v2,vl1,vl2 (L2-resident)
    const float* __restrict__ al2, const float* __restrict__ ar2,
    const float* __restrict__ ln_g, const float* __restrict__ ln_b,
    float* __restrict__ h1r0buf, float* __restrict__ ctx2buf,
    float* __restrict__ out)
{
  __shared__ int idx[32];
  __shared__ alignas(16) ushortT GT[256 * 40];   // GW^T then GW2^T, swizzled
  __shared__ alignas(16) ushortT PlF[10240];     // Pl[8][32][40] sw., then FR2s[32][268]
  __shared__ float SRs[8][32];
  __shared__ float RQs[32][36];                  // RQ1 then RQ2
  __shared__ float rk2s[32];
  __shared__ float part[32][4], partq[32][4];
  __shared__ float mu_s[32], rs_s[32];
  __shared__ float SR2s[8][32];
  __shared__ float sl2s[8];
  __shared__ float scp[8][32];
  __shared__ float h1r0s[256];
  __shared__ float wred4[4];
  __shared__ float nrm1s;

  const int b = blockIdx.x, t = threadIdx.x;
  const int h8 = t >> 5, lo = t & 31;
  const int w = t >> 6, l = t & 63;
  const int l15 = l & 15, l16 = l >> 4;

  if (t < 32) idx[t] = seqs[b * 32 + t];
  __syncthreads();                                             // B1

  // per-thread softmax inputs (issued early; latency hides under staging)
  const float sli = SLg[(size_t)idx[lo] * 8 + h8];
  const float rk0 = RKQ[(size_t)idx[lo] * 128 + h8 * 4 + 0];
  const float rk1 = RKQ[(size_t)idx[lo] * 128 + h8 * 4 + 1];
  const float rk2_ = RKQ[(size_t)idx[lo] * 128 + h8 * 4 + 2];
  const float rk3 = RKQ[(size_t)idx[lo] * 128 + h8 * 4 + 3];

  // ---- stage GT = GW^T (swizzled), SRs, RQs=RQ1, rk2s ----
  {
    const uintT* GWu = reinterpret_cast<const uintT*>(GW);
    #pragma unroll
    for (int rep = 0; rep < 16; ++rep) {
      int flat = rep * 256 + t;
      int j = flat >> 7, cp = flat & 127;
      const uintT u = GWu[(size_t)idx[j] * 128 + cp];
      const int rA = 2 * cp;
      const int k = (rA >> 3) & 3;               // same for rA, rA+1
      const int off = (((j >> 3) ^ k) << 3) + (j & 7);
      GT[rA * 40 + off]       = (ushortT)(u & 0xffffu);
      GT[(rA + 1) * 40 + off] = (ushortT)(u >> 16);
    }
  }
  SRs[h8][lo] = SRg[(size_t)idx[lo] * 8 + h8];
  #pragma unroll
  for (int rep = 0; rep < 4; ++rep) {
    int flat = rep * 256 + t, s3 = flat >> 5, c3 = flat & 31;
    RQs[s3][c3] = RKQ[(size_t)idx[s3] * 128 + 32 + c3];
  }
  if (t < 32) rk2s[t] = RKQ[(size_t)idx[0] * 128 + 64 + t];
  __syncthreads();                                             // B2

  // ---- attn1 softmax: thread (h8, row lo) -> Pl (swizzled bf16) ----
  {
    float p1[32];
    float m = -1e30f;
    #pragma unroll
    for (int j = 0; j < 32; ++j) {
      float sc = sli + SRs[h8][j]
               + rk0 * RQs[j][h8 * 4 + 0] + rk1 * RQs[j][h8 * 4 + 1]
               + rk2_ * RQs[j][h8 * 4 + 2] + rk3 * RQs[j][h8 * 4 + 3];
      p1[j] = sc; m = fmaxf(m, sc);
    }
    float sum = 0.f;
    #pragma unroll
    for (int j = 0; j < 32; ++j) { p1[j] = __expf(p1[j] - m); sum += p1[j]; }
    const float inv = 1.f / sum;
    const int row = t;                     // global Pl row = h8*32+lo = t
    const int k = (row >> 3) & 3;
    uintT* pw = reinterpret_cast<uintT*>(PlF);
    #pragma unroll
    for (int q = 0; q < 16; ++q) {
      const int pu = row * 20 + (((q >> 2) ^ k) << 2) + (q & 3);
      pw[pu] = (uintT)f2bu(p1[2 * q] * inv) | ((uintT)f2bu(p1[2 * q + 1] * inv) << 16);
    }
  }
  __syncthreads();                                             // B3

  int irow[2][4];
  #pragma unroll
  for (int mh = 0; mh < 2; ++mh)
    #pragma unroll
    for (int r = 0; r < 4; ++r)
      irow[mh][r] = idx[mh * 16 + l16 * 4 + r];

  // A-fragments cached in registers for BOTH phases
  bf16x8 af[2][2];
  #pragma unroll
  for (int hh = 0; hh < 2; ++hh) {
    const int h = 2 * w + hh;
    #pragma unroll
    for (int mh = 0; mh < 2; ++mh) {
      const int row = h * 32 + mh * 16 + l15;
      const int k = (row >> 3) & 3;
      af[hh][mh] = *reinterpret_cast<const bf16x8*>(&PlF[row * 40 + ((l16 ^ k) << 3)]);
    }
  }

  // ---- x phase: MFMA + gh residual + LN stats + h1row0 stash ----
  f32x4 acc[2][2][2];
  #pragma unroll
  for (int hh = 0; hh < 2; ++hh) {
    const int h = 2 * w + hh;
    bf16x8 bf[2];
    #pragma unroll
    for (int nh = 0; nh < 2; ++nh) {
      const int row = h * 32 + nh * 16 + l15;
      const int k = (row >> 3) & 3;
      bf[nh] = *reinterpret_cast<const bf16x8*>(&GT[row * 40 + ((l16 ^ k) << 3)]);
    }
    #pragma unroll
    for (int mh = 0; mh < 2; ++mh)
      #pragma unroll
      for (int nh = 0; nh < 2; ++nh) {
        f32x4 z = {0.f, 0.f, 0.f, 0.f};
        acc[hh][mh][nh] = __builtin_amdgcn_mfma_f32_16x16x32_bf16(af[hh][mh], bf[nh], z, 0, 0, 0);
      }
  }
  {
    float sum_[2][4], sq_[2][4];
    #pragma unroll
    for (int mh = 0; mh < 2; ++mh)
      #pragma unroll
      for (int r = 0; r < 4; ++r) { sum_[mh][r] = 0.f; sq_[mh][r] = 0.f; }
    #pragma unroll
    for (int hh = 0; hh < 2; ++hh)
      #pragma unroll
      for (int mh = 0; mh < 2; ++mh)
        #pragma unroll
        for (int nh = 0; nh < 2; ++nh) {
          const int col = (2 * w + hh) * 32 + nh * 16 + l15;
          #pragma unroll
          for (int r = 0; r < 4; ++r) {
            float v = acc[hh][mh][nh][r] + gh[(size_t)irow[mh][r] * 256 + col];
            acc[hh][mh][nh][r] = v;
            sum_[mh][r] += v;
            sq_[mh][r] = fmaf(v, v, sq_[mh][r]);
          }
        }
    #pragma unroll
    for (int mh = 0; mh < 2; ++mh)
      #pragma unroll
      for (int r = 0; r < 4; ++r) {
        float s = sum_[mh][r], q = sq_[mh][r];
        #pragma unroll
        for (int m = 8; m >= 1; m >>= 1) {
          s += __shfl_xor(s, m, 64);
          q += __shfl_xor(q, m, 64);
        }
        if (l15 == 0) {
          part[mh * 16 + l16 * 4 + r][w]  = s;
          partq[mh * 16 + l16 * 4 + r][w] = q;
        }
      }
    if (l16 == 0) {
      #pragma unroll
      for (int hh = 0; hh < 2; ++hh)
        #pragma unroll
        for (int nh = 0; nh < 2; ++nh)
          h1r0s[(2 * w + hh) * 32 + nh * 16 + l15] = acc[hh][0][nh][0];
    }
  }
  __syncthreads();                                             // B4

  if (t < 32) {
    float sm = part[t][0] + part[t][1] + part[t][2] + part[t][3];
    float sq = partq[t][0] + partq[t][1] + partq[t][2] + partq[t][3];
    const float m = sm * (1.f / 256.f);
    const float v = fmaxf(sq * (1.f / 256.f) - m * m, 0.f);
    mu_s[t] = m;
    rs_s[t] = rsqrtf(v + LN_EPS);
  }
  __syncthreads();                                             // B5

  // ---- parallel: restage GT=GW2^T; RQs=RQ2; h1row0 LN; fl2 (reads Pl) ----
  {
    const uintT* GW2u = reinterpret_cast<const uintT*>(GW2);
    #pragma unroll
    for (int rep = 0; rep < 16; ++rep) {
      int flat = rep * 256 + t;
      int j = flat >> 7, cp = flat & 127;
      const uintT u = GW2u[(size_t)idx[j] * 128 + cp];
      const int rA = 2 * cp;
      const int k = (rA >> 3) & 3;
      const int off = (((j >> 3) ^ k) << 3) + (j & 7);
      GT[rA * 40 + off]       = (ushortT)(u & 0xffffu);
      GT[(rA + 1) * 40 + off] = (ushortT)(u >> 16);
    }
  }
  #pragma unroll
  for (int rep = 0; rep < 4; ++rep) {
    int flat = rep * 256 + t, s3 = flat >> 5, c3 = flat & 31;
    RQs[s3][c3] = RKQ[(size_t)idx[s3] * 128 + 96 + c3];
  }
  {
    const float mu0 = mu_s[0], rs0 = rs_s[0];
    float hv = fmaf((h1r0s[t] - mu0) * rs0, ln_g[t], ln_b[t]);
    h1r0buf[(size_t)b * 256 + t] = hv;
    float sq = red64(hv * hv);
    h1r0s[t] = hv;                       // own col only
    if ((t & 63) == 0) wred4[t >> 6] = sq;
  }
  {
    // fl2: Pl row0 of head h8 is unswizzled (key((h8*32)>>3)&3 == 0)
    float z0 = 0.f;
    #pragma unroll 8
    for (int j = 0; j < 32; ++j)
      z0 = fmaf(b2f(PlF[(h8 * 32) * 40 + j]), b2f(GWL[(size_t)idx[j] * 256 + t]), z0);
    z0 += b2f(GHL[(size_t)idx[0] * 256 + t]);
    const float rs0 = rs_s[0], rm0 = rs_s[0] * mu_s[0];
    const float fl = fmaf(rs0, z0, fmaf(-rm0, vecs[512 + t], vecs[768 + t]));
    float lr = (fl > 0.f ? fl : SLOPE * fl) * al2[lo];
    lr = red32(lr);
    if (lo == 0) sl2s[h8] = lr;
  }
  __syncthreads();                                             // B6  (Pl dead)

  if (t == 0) nrm1s = 1.f / fmaxf(sqrtf(wred4[0] + wred4[1] + wred4[2] + wred4[3]), 1e-12f);

  // ---- y phase: MFMA (af regs) + GHG residual -> FR2 (into PlF) + SR2 ----
  {
    f32x4 acc2[2][2][2];
    #pragma unroll
    for (int hh = 0; hh < 2; ++hh) {
      const int h = 2 * w + hh;
      bf16x8 bf[2];
      #pragma unroll
      for (int nh = 0; nh < 2; ++nh) {
        const int row = h * 32 + nh * 16 + l15;
        const int k = (row >> 3) & 3;
        bf[nh] = *reinterpret_cast<const bf16x8*>(&GT[row * 40 + ((l16 ^ k) << 3)]);
      }
      #pragma unroll
      for (int mh = 0; mh < 2; ++mh)
        #pragma unroll
        for (int nh = 0; nh < 2; ++nh) {
          f32x4 z = {0.f, 0.f, 0.f, 0.f};
          acc2[hh][mh][nh] = __builtin_amdgcn_mfma_f32_16x16x32_bf16(af[hh][mh], bf[nh], z, 0, 0, 0);
        }
    }
    float rsv[2][4], rmv[2][4];
    #pragma unroll
    for (int mh = 0; mh < 2; ++mh)
      #pragma unroll
      for (int r = 0; r < 4; ++r) {
        const int row = mh * 16 + l16 * 4 + r;
        rsv[mh][r] = rs_s[row];
        rmv[mh][r] = rsv[mh][r] * mu_s[row];
      }
    float ar2v[2] = { ar2[l15], ar2[16 + l15] };
    float v1c[2][2], v2c[2][2];
    #pragma unroll
    for (int hh = 0; hh < 2; ++hh)
      #pragma unroll
      for (int nh = 0; nh < 2; ++nh) {
        const int col = (2 * w + hh) * 32 + nh * 16 + l15;
        v1c[hh][nh] = vecs[col];
        v2c[hh][nh] = vecs[256 + col];
      }
    float sacc[2][2][4];
    #pragma unroll
    for (int hh = 0; hh < 2; ++hh)
      #pragma unroll
      for (int mh = 0; mh < 2; ++mh)
        #pragma unroll
        for (int r = 0; r < 4; ++r) sacc[hh][mh][r] = 0.f;

    #pragma unroll
    for (int hh = 0; hh < 2; ++hh)
      #pragma unroll
      for (int mh = 0; mh < 2; ++mh)
        #pragma unroll
        for (int nh = 0; nh < 2; ++nh) {
          const int col = (2 * w + hh) * 32 + nh * 16 + l15;
          #pragma unroll
          for (int r = 0; r < 4; ++r) {
            const int row = mh * 16 + l16 * 4 + r;
            float yv = acc2[hh][mh][nh][r] + b2f(GHG[(size_t)irow[mh][r] * 256 + col]);
            float fa = fmaf(rsv[mh][r], yv, fmaf(-rmv[mh][r], v1c[hh][nh], v2c[hh][nh]));
            PlF[row * 268 + col] = f2bu(fa);       // FR2s[row][col]
            float lr = fa > 0.f ? fa : SLOPE * fa;
            sacc[hh][mh][r] = fmaf(lr, ar2v[nh], sacc[hh][mh][r]);
          }
        }
    #pragma unroll
    for (int hh = 0; hh < 2; ++hh)
      #pragma unroll
      for (int mh = 0; mh < 2; ++mh)
        #pragma unroll
        for (int r = 0; r < 4; ++r) {
          float s = sacc[hh][mh][r];
          #pragma unroll
          for (int m = 8; m >= 1; m >>= 1) s += __shfl_xor(s, m, 64);
          if (l15 == 0) SR2s[2 * w + hh][mh * 16 + l16 * 4 + r] = s;
        }
  }
  __syncthreads();                                             // B7

  // ---- attn2 row0 scores (thread = (h8, key lo)) ----
  {
    float s2 = sl2s[h8] + SR2s[h8][lo]
             + rk2s[h8 * 4 + 0] * RQs[lo][h8 * 4 + 0]
             + rk2s[h8 * 4 + 1] * RQs[lo][h8 * 4 + 1]
             + rk2s[h8 * 4 + 2] * RQs[lo][h8 * 4 + 2]
             + rk2s[h8 * 4 + 3] * RQs[lo][h8 * 4 + 3];
    const float m2 = max32(s2);
    const float e = __expf(s2 - m2);
    const float su = red32(e);
    scp[h8][lo] = e / su;
  }
  __syncthreads();                                             // B8

  // ---- ctx2 = p2 ◦ FR2 ; ret1 write ----
  {
    float a = 0.f;
    #pragma unroll
    for (int j = 0; j < 32; ++j) a = fmaf(scp[h8][j], b2f(PlF[j * 268 + t]), a);
    ctx2buf[(size_t)b * 256 + t] = a;
  }
  out[(size_t)b * 768 + 256 + t] = h1r0s[t] * nrm1s;
}

// ---------------------------------------------------------------------------
// Epilogue: ret2 = l2n(LN(h1row0 + ctx2 @ Wfin2))  — 64 rows/block
// ---------------------------------------------------------------------------
__global__ __launch_bounds__(256) void final_ln_kernel(
    const float* __restrict__ A,
    const float* __restrict__ W,
    const float* __restrict__ res,
    const float* __restrict__ lng, const float* __restrict__ lnb,
    float* __restrict__ out)
{
  const int m0 = blockIdx.x * 64;
  const int t  = threadIdx.x;
  const int tr = t & 15, tc = t >> 4;
  __shared__ alignas(16) float As[32][68];
  __shared__ alignas(16) float Bs[32][264];
  __shared__ float red[64][16];
  __shared__ float stat[64];
  float acc[4][16] = {};

  for (int ks = 0; ks < 8; ++ks) {
    const int k0 = ks * 32;
    #pragma unroll
    for (int rep = 0; rep < 8; ++rep) {
      int flat = rep * 256 + t;
      int r = flat >> 5, c = flat & 31;
      As[c][r] = A[(size_t)(m0 + r) * 256 + (k0 + c)];
    }
    #pragma unroll
    for (int rep = 0; rep < 32; ++rep) {
      int flat = rep * 256 + t;
      int rb = flat >> 8, cb = flat & 255;
      Bs[rb][cb] = W[(size_t)(k0 + rb) * 256 + cb];
    }
    __syncthreads();
    #pragma unroll
    for (int k = 0; k < 32; ++k) {
      const float4 a4 = *reinterpret_cast<const float4*>(&As[k][tr * 4]);
      const float av[4] = {a4.x, a4.y, a4.z, a4.w};
      #pragma unroll
      for (int q = 0; q < 4; ++q) {
        const float4 b4 = *reinterpret_cast<const float4*>(&Bs[k][tc * 16 + q * 4]);
        const float bv[4] = {b4.x, b4.y, b4.z, b4.w};
        #pragma unroll
        for (int u = 0; u < 4; ++u)
          #pragma unroll
          for (int v = 0; v < 4; ++v)
            acc[u][q * 4 + v] = fmaf(av[u], bv[v], acc[u][q * 4 + v]);
      }
    }
    __syncthreads();
  }

  int rows[4];
  #pragma unroll
  for (int u = 0; u < 4; ++u) rows[u] = m0 + tr * 4 + u;

  #pragma unroll
  for (int u = 0; u < 4; ++u) {
    const float* rp = &res[(size_t)rows[u] * 256 + tc * 16];
    #pragma unroll
    for (int v = 0; v < 16; ++v) acc[u][v] += rp[v];
  }
  #pragma unroll
  for (int u = 0; u < 4; ++u) {
    float s = 0.f;
    #pragma unroll
    for (int v = 0; v < 16; ++v) s += acc[u][v];
    red[tr * 4 + u][tc] = s;
  }
  __syncthreads();
  if (t < 64) {
    float s = 0.f;
    #pragma unroll
    for (int g = 0; g < 16; ++g) s += red[t][g];
    stat[t] = s * (1.0f / 256.0f);
  }
  __syncthreads();
  float mu[4];
  #pragma unroll
  for (int u = 0; u < 4; ++u) mu[u] = stat[tr * 4 + u];
  #pragma unroll
  for (int u = 0; u < 4; ++u) {
    float s = 0.f;
    #pragma unroll
    for (int v = 0; v < 16; ++v) { float d = acc[u][v] - mu[u]; s += d * d; }
    red[tr * 4 + u][tc] = s;
  }
  __syncthreads();
  if (t < 64) {
    float s = 0.f;
    #pragma unroll
    for (int g = 0; g < 16; ++g) s += red[t][g];
    stat[t] = rsqrtf(s * (1.0f / 256.0f) + LN_EPS);
  }
  __syncthreads();
  float rst[4];
  #pragma unroll
  for (int u = 0; u < 4; ++u) rst[u] = stat[tr * 4 + u];
  #pragma unroll
  for (int u = 0; u < 4; ++u) {
    float s = 0.f;
    #pragma unroll
    for (int v = 0; v < 16; ++v) {
      int col = tc * 16 + v;
      float yv = fmaf((acc[u][v] - mu[u]) * rst[u], lng[col], lnb[col]);
      acc[u][v] = yv;
      s += yv * yv;
    }
    red[tr * 4 + u][tc] = s;
  }
  __syncthreads();
  if (t < 64) {
    float s = 0.f;
    #pragma unroll
    for (int g = 0; g < 16; ++g) s += red[t][g];
    stat[t] = 1.0f / fmaxf(sqrtf(s), 1e-12f);
  }
  __syncthreads();
  #pragma unroll
  for (int u = 0; u < 4; ++u) {
    float rn = stat[tr * 4 + u];
    #pragma unroll
    for (int v = 0; v < 16; ++v)
      out[(size_t)rows[u] * 768 + 512 + tc * 16 + v] = acc[u][v] * rn;
  }
}

// ---------------------------------------------------------------------------
extern "C" void kernel_launch(void* const* d_in, const int* in_sizes, int n_in,
                              void* d_out, int out_size, void* d_ws, size_t ws_size,
                              hipStream_t stream)
{
  (void)in_sizes; (void)n_in; (void)out_size; (void)ws_size;

  const float* feat[4]; const float* wfc[4]; const float* bfc[4];
  for (int i = 0; i < 4; ++i) {
    feat[i] = (const float*)d_in[i * 3 + 0];
    wfc[i]  = (const float*)d_in[i * 3 + 1];
    bfc[i]  = (const float*)d_in[i * 3 + 2];
  }
  const float* type_emb = (const float*)d_in[12];
  const float* Wgcn = (const float*)d_in[13];
  const float* bgcn = (const float*)d_in[14];
  const float* Wre  = (const float*)d_in[15];
  const float* bre  = (const float*)d_in[16];
  const float* wtre = (const float*)d_in[17];
  const float* Wl   = (const float*)d_in[18];
  const float* Wr   = (const float*)d_in[19];
  const float* al   = (const float*)d_in[20];
  const float* ar   = (const float*)d_in[21];
  const float* Wrs  = (const float*)d_in[22];
  const float* Wrt  = (const float*)d_in[23];
  const float* Wfin = (const float*)d_in[24];
  const float* ln_g = (const float*)d_in[25];
  const float* ln_b = (const float*)d_in[26];
  const int* src       = (const int*)d_in[27];
  const int* dst       = (const int*)d_in[28];
  const int* node_type = (const int*)d_in[29];
  const int* seqs      = (const int*)d_in[30];
  float* out = (float*)d_out;

  // workspace carve-up (~50 MB)
  char* p = (char*)d_ws;
  auto take = [&](size_t n) { char* q = p; p += (n + 255) & ~(size_t)255; return q; };
  float* gh    = (float*)take((size_t)NN * 256 * 4);
  float* Xbuf  = (float*)take((size_t)NN * 256 * 4);   // GCN scratch, then ctx2buf
  float* GR1   = (float*)take((size_t)NN * 256 * 4);   // gh@Wr1, then h1r0buf
  float* RKQ   = (float*)take((size_t)NN * 128 * 4);
  float* SLg   = (float*)take((size_t)NN * 8 * 4);
  float* SRg   = (float*)take((size_t)NN * 8 * 4);
  float* n_out = (float*)take((size_t)NN * 4);
  float* n_in_ = (float*)take((size_t)NN * 4);
  int*   outc  = (int*)take((size_t)NN * 4);
  int*   inc   = (int*)take((size_t)NN * 4);
  int*   offs  = (int*)take((size_t)(NN + 1) * 4);
  int*   cur   = (int*)take((size_t)NN * 4);
  int*   csr   = (int*)take((size_t)(EE + NN) * 4);
  float* R     = (float*)take((size_t)NN * 4 * 4);
  float* rtmp  = (float*)take((size_t)NN * 4 * 4);
  ushortT* GW  = (ushortT*)take((size_t)NN * 256 * 2);
  ushortT* GW2 = (ushortT*)take((size_t)NN * 256 * 2);
  ushortT* GWL = (ushortT*)take((size_t)NN * 256 * 2);
  ushortT* GHG = (ushortT*)take((size_t)NN * 256 * 2);
  ushortT* GHL = (ushortT*)take((size_t)NN * 256 * 2);
  float* Wg2   = (float*)take((size_t)65536 * 4);
  float* Wgl2  = (float*)take((size_t)65536 * 4);
  float* Wc2   = (float*)take((size_t)65536 * 4);
  float* Wcl   = (float*)take((size_t)65536 * 4);
  float* vecs  = (float*)take((size_t)4 * 256 * 4);
  float* ctx2buf = Xbuf;   // alias: Xbuf dead after GCN
  float* h1r0buf = GR1;    // alias: GR1 dead after table GEMMs

  const float* Wr2 = Wr + 65536;
  const float* Wl2 = Wl + 65536;

  // 1) FC + ret0
  fc_kernel<<<256, 256, 0, stream>>>(feat[0], feat[1], feat[2], feat[3],
                                     wfc[0], wfc[1], wfc[2], wfc[3],
                                     bfc[0], bfc[1], bfc[2], bfc[3], gh, out);
  // 2) degrees + CSR
  zero_counts<<<64, 256, 0, stream>>>(outc, inc);
  count_deg<<<512, 256, 0, stream>>>(src, dst, outc, inc);
  norm_kernel<<<32, 256, 0, stream>>>(outc, inc, n_out, n_in_);
  scan_kernel<<<1, 1024, 0, stream>>>(inc, offs);
  copy_cur<<<32, 256, 0, stream>>>(offs, cur);
  fill_csr<<<544, 256, 0, stream>>>(src, dst, cur, csr);
  init_R<<<128, 256, 0, stream>>>(type_emb, node_type, R);

  // weight prep (independent of graph work)
  scale_w_kernel<<<256, 256, 0, stream>>>(ln_g, Wr2, Wl2, Wg2, Wgl2);
  vec4_kernel<<<4, 256, 0, stream>>>(ln_g, ln_b, Wr2, Wl2, vecs);
  gemm64_kernel<false, true, false, float>
      <<<dim3(4, 4), 256, 0, stream>>>(Wfin, Wg2, nullptr, Wc2, nullptr, nullptr);
  gemm64_kernel<false, true, false, float>
      <<<dim3(4, 4), 256, 0, stream>>>(Wfin, Wgl2, nullptr, Wcl, nullptr, nullptr);

  // 3) GCN + REConv, K=2
  for (int k = 0; k < 2; ++k) {
    gemm64_kernel<true, true, false, float>
        <<<dim3(128, 4), 256, 0, stream>>>(gh, Wgcn + (size_t)k * 65536,
                                           n_out, Xbuf, nullptr, nullptr);
    agg_kernel<<<NN, 256, 0, stream>>>(offs, csr, Xbuf, n_in_, bgcn + k * 256, gh);
    re_proj<<<128, 256, 0, stream>>>(R, n_out, Wre + k * 16, wtre + k * 4, node_type, rtmp);
    re_agg<<<128, 256, 0, stream>>>(offs, csr, rtmp, n_in_, bre + k * 4, R);
  }

  // 4) attention precomputes + node tables (tables via MFMA)
  rkq_kernel<<<4096, 256, 0, stream>>>(R, Wrs, Wrt, RKQ);
  gemm64_kernel<false, false, true, float>
      <<<dim3(128, 4), 256, 0, stream>>>(gh, Wl, nullptr, (float*)nullptr, al, SLg);
  gemm64_kernel<false, true, true, float>
      <<<dim3(128, 4), 256, 0, stream>>>(gh, Wr, nullptr, GR1, ar, SRg);
  mfma_tab_kernel<<<dim3(128, 4, 5), 256, 0, stream>>>(
      GR1, gh, Wfin, Wc2, Wcl, Wg2, Wgl2, GW, GW2, GWL, GHG, GHL);

  // 5) fused transformer (MFMA + swizzle + 3 blk/CU) -> ret1, h1r0, ctx2
  mega4_kernel<<<NN, 256, 0, stream>>>(seqs, gh, GW, GW2, GWL, GHG, GHL,
                                       SLg, SRg, RKQ, vecs,
                                       al + 32, ar + 32, ln_g, ln_b,
                                       h1r0buf, ctx2buf, out);

  // 6) epilogue: ret2 = l2n(LN(h1r0 + ctx2@Wfin2))
  final_ln_kernel<<<128, 256, 0, stream>>>(ctx2buf, Wfin + 65536, h1r0buf,
                                           ln_g + 256, ln_b + 256, out);
}

// Round 13
// 604.676 us; speedup vs baseline: 4.5711x; 1.0372x over previous
//
#include <hip/hip_runtime.h>
#include <hip/hip_bf16.h>
#include <cstdint>
#include <cstddef>

typedef unsigned short ushortT;
typedef unsigned int uintT;

using bf16x8 = __attribute__((ext_vector_type(8))) short;
using f32x4  = __attribute__((ext_vector_type(4))) float;

static constexpr int NN  = 8192;    // total nodes
static constexpr int EE  = 131072;  // edges
static constexpr float SLOPE  = 0.2f;
static constexpr float LN_EPS = 1e-5f;

#define DEVI __device__ __forceinline__

DEVI float red32(float v) {
  #pragma unroll
  for (int m = 16; m >= 1; m >>= 1) v += __shfl_xor(v, m, 64);
  return v;
}
DEVI float red64(float v) {
  #pragma unroll
  for (int m = 32; m >= 1; m >>= 1) v += __shfl_xor(v, m, 64);
  return v;
}
DEVI float max32(float v) {
  #pragma unroll
  for (int m = 16; m >= 1; m >>= 1) v = fmaxf(v, __shfl_xor(v, m, 64));
  return v;
}
DEVI float blo(uintT u) { union { uintT i; float f; } c; c.i = u << 16; return c.f; }
DEVI float bhi(uintT u) { union { uintT i; float f; } c; c.i = u & 0xffff0000u; return c.f; }
DEVI float b2f(ushortT u) { union { uintT i; float f; } c; c.i = ((uintT)u) << 16; return c.f; }
DEVI ushortT f2bu(float f) {
  __hip_bfloat16 h = __float2bfloat16(f);
  return *reinterpret_cast<ushortT*>(&h);
}
DEVI void storeC(float* p, float v) { *p = v; }
DEVI void storeC(ushortT* p, float v) { *p = f2bu(v); }

// ---------------------------------------------------------------------------
// FC: gh[n] = feat_t[n] @ Wfc_t + bfc_t ; out[n,0:256] = l2n(gh[n])
// ---------------------------------------------------------------------------
__global__ __launch_bounds__(256) void fc_kernel(
    const float* __restrict__ f0, const float* __restrict__ f1,
    const float* __restrict__ f2, const float* __restrict__ f3,
    const float* __restrict__ w0, const float* __restrict__ w1,
    const float* __restrict__ w2, const float* __restrict__ w3,
    const float* __restrict__ b0, const float* __restrict__ b1,
    const float* __restrict__ b2, const float* __restrict__ b3,
    float* __restrict__ gh, float* __restrict__ out)
{
  const int nb = blockIdx.x * 32;
  const int t  = threadIdx.x;
  int base, D;
  const float *F, *W, *Bv;
  if (nb < 4096)      { base = 0;    D = 128; F = f0; W = w0; Bv = b0; }
  else if (nb < 6144) { base = 4096; D = 64;  F = f1; W = w1; Bv = b1; }
  else if (nb < 7168) { base = 6144; D = 32;  F = f2; W = w2; Bv = b2; }
  else                { base = 7168; D = 16;  F = f3; W = w3; Bv = b3; }

  __shared__ float Fs[32 * 128];
  __shared__ float red[32][4];
  __shared__ float nrm[32];

  const int total = 32 * D;
  for (int i = t; i < total; i += 256) Fs[i] = F[(size_t)(nb - base) * D + i];
  __syncthreads();

  float acc[32];
  #pragma unroll
  for (int r = 0; r < 32; ++r) acc[r] = Bv[t];
  for (int d = 0; d < D; ++d) {
    float w = W[(size_t)d * 256 + t];
    #pragma unroll
    for (int r = 0; r < 32; ++r) acc[r] = fmaf(Fs[r * D + d], w, acc[r]);
  }

  const int lane = t & 63, wid = t >> 6;
  #pragma unroll
  for (int r = 0; r < 32; ++r) {
    float v = acc[r] * acc[r];
    for (int o = 32; o > 0; o >>= 1) v += __shfl_down(v, o, 64);
    if (lane == 0) red[r][wid] = v;
  }
  __syncthreads();
  if (t < 32) {
    float s = red[t][0] + red[t][1] + red[t][2] + red[t][3];
    nrm[t] = 1.0f / fmaxf(sqrtf(s), 1e-12f);
  }
  __syncthreads();
  #pragma unroll
  for (int r = 0; r < 32; ++r) {
    gh[(size_t)(nb + r) * 256 + t]  = acc[r];
    out[(size_t)(nb + r) * 768 + t] = acc[r] * nrm[r];
  }
}

// ---------------------------------------------------------------------------
// degree / CSR build
// ---------------------------------------------------------------------------
__global__ __launch_bounds__(256) void zero_counts(int* outc, int* inc) {
  int g = blockIdx.x * 256 + threadIdx.x;
  if (g < NN) outc[g] = 0; else inc[g - NN] = 0;
}
__global__ __launch_bounds__(256) void count_deg(const int* __restrict__ src,
                                                 const int* __restrict__ dst,
                                                 int* outc, int* inc) {
  int g = blockIdx.x * 256 + threadIdx.x;
  atomicAdd(&outc[src[g]], 1);
  atomicAdd(&inc[dst[g]], 1);
}
__global__ __launch_bounds__(256) void norm_kernel(const int* __restrict__ outc,
                                                   const int* __restrict__ inc,
                                                   float* n_out, float* n_in) {
  int g = blockIdx.x * 256 + threadIdx.x;
  n_out[g] = rsqrtf((float)outc[g] + 1.0f);
  n_in[g]  = rsqrtf((float)inc[g] + 1.0f);
}
__global__ __launch_bounds__(1024) void scan_kernel(const int* __restrict__ inc,
                                                    int* __restrict__ offs) {
  __shared__ int sums[1024];
  const int t = threadIdx.x;
  int x[8];
  const int base = t * 8;
  int s = 0;
  #pragma unroll
  for (int i = 0; i < 8; ++i) { int v = inc[base + i] + 1; x[i] = s; s += v; }
  sums[t] = s;
  __syncthreads();
  for (int off = 1; off < 1024; off <<= 1) {
    int a = (t >= off) ? sums[t - off] : 0;
    __syncthreads();
    sums[t] += a;
    __syncthreads();
  }
  const int pre = (t > 0) ? sums[t - 1] : 0;
  #pragma unroll
  for (int i = 0; i < 8; ++i) offs[base + i] = pre + x[i];
  if (t == 1023) offs[NN] = sums[1023];
}
__global__ __launch_bounds__(256) void copy_cur(const int* __restrict__ offs, int* cur) {
  int g = blockIdx.x * 256 + threadIdx.x;
  cur[g] = offs[g];
}
__global__ __launch_bounds__(256) void fill_csr(const int* __restrict__ src,
                                                const int* __restrict__ dst,
                                                int* cur, int* __restrict__ csr) {
  int g = blockIdx.x * 256 + threadIdx.x;   // EE + NN total
  int s, d;
  if (g < EE) { s = src[g]; d = dst[g]; }
  else        { s = g - EE; d = g - EE; }   // self-loops
  int pos = atomicAdd(&cur[d], 1);
  csr[pos] = s;
}
__global__ __launch_bounds__(256) void init_R(const float* __restrict__ type_emb,
                                              const int* __restrict__ nt,
                                              float* __restrict__ R) {
  int g = blockIdx.x * 256 + threadIdx.x;   // NN*4
  int n = g >> 2, c = g & 3;
  R[g] = type_emb[nt[n] * 4 + c];
}

// ---------------------------------------------------------------------------
// [M,256] @ [256,256] f32 register-tiled GEMM, 64x64 tile, 256 thr.
// ---------------------------------------------------------------------------
template<bool ROWSCALE, bool STORE, bool RED, typename CT>
__global__ __launch_bounds__(256) void gemm64_kernel(
    const float* __restrict__ A,
    const float* __restrict__ W,
    const float* __restrict__ rowscale,
    CT* __restrict__ C,
    const float* __restrict__ avec,
    float* __restrict__ SSo)
{
  const int m0 = blockIdx.x * 64;
  const int n0 = blockIdx.y * 64;
  const int t  = threadIdx.x;
  const int tr = t & 15, tc = t >> 4;
  __shared__ alignas(16) float As[32][68];
  __shared__ alignas(16) float Bs[32][68];
  __shared__ float red[64][2];
  float acc[4][4] = {};

  for (int ks = 0; ks < 8; ++ks) {
    const int k0 = ks * 32;
    #pragma unroll
    for (int rep = 0; rep < 8; ++rep) {
      int flat = rep * 256 + t;
      int r = flat >> 5, c = flat & 31;
      As[c][r] = A[(size_t)(m0 + r) * 256 + (k0 + c)];
      int rb = flat >> 6, cb = flat & 63;
      Bs[rb][cb] = W[(size_t)(k0 + rb) * 256 + (n0 + cb)];
    }
    __syncthreads();
    #pragma unroll
    for (int k = 0; k < 32; ++k) {
      const float4 a4 = *reinterpret_cast<const float4*>(&As[k][tr * 4]);
      const float4 b4 = *reinterpret_cast<const float4*>(&Bs[k][tc * 4]);
      const float av[4] = {a4.x, a4.y, a4.z, a4.w};
      const float bv[4] = {b4.x, b4.y, b4.z, b4.w};
      #pragma unroll
      for (int u = 0; u < 4; ++u)
        #pragma unroll
        for (int v = 0; v < 4; ++v)
          acc[u][v] = fmaf(av[u], bv[v], acc[u][v]);
    }
    __syncthreads();
  }

  if constexpr (ROWSCALE) {
    #pragma unroll
    for (int u = 0; u < 4; ++u) {
      float s = rowscale[m0 + tr * 4 + u];
      #pragma unroll
      for (int v = 0; v < 4; ++v) acc[u][v] *= s;
    }
  }
  if constexpr (STORE) {
    #pragma unroll
    for (int u = 0; u < 4; ++u) {
      size_t row = (size_t)(m0 + tr * 4 + u);
      #pragma unroll
      for (int v = 0; v < 4; ++v)
        storeC(&C[row * 256 + (n0 + tc * 4 + v)], acc[u][v]);
    }
  }
  if constexpr (RED) {
    if (t < 128) red[t >> 1][t & 1] = 0.f;
    __syncthreads();
    #pragma unroll
    for (int u = 0; u < 4; ++u) {
      float s = 0.f;
      #pragma unroll
      for (int v = 0; v < 4; ++v) {
        float x = acc[u][v];
        float lr = x > 0.f ? x : SLOPE * x;
        s += lr * avec[(tc * 4 + v) & 31];
      }
      atomicAdd(&red[tr * 4 + u][tc >> 3], s);
    }
    __syncthreads();
    if (t < 128) {
      int r = t >> 1, hh = t & 1;
      SSo[(size_t)(m0 + r) * 8 + blockIdx.y * 2 + hh] = red[r][hh];
    }
  }
}

// ---------------------------------------------------------------------------
// MFMA table GEMM: GW[8192,256](bf16) = GR1(f32->bf16) @ Wfin
// ---------------------------------------------------------------------------
__global__ __launch_bounds__(256) void mfma_tab_kernel(
    const float* __restrict__ A, const float* __restrict__ W,
    ushortT* __restrict__ C)
{
  const int m0 = blockIdx.x * 64;
  const int n0 = blockIdx.y * 64;
  const int t = threadIdx.x;
  const int w = t >> 6, l = t & 63;
  const int wr = w >> 1, wc = w & 1;
  const int l15 = l & 15, l16 = l >> 4;

  __shared__ alignas(16) ushortT As[64][72];   // [m][k]
  __shared__ alignas(16) ushortT Bs[64][72];   // [n][k]

  f32x4 acc[2][2];
  #pragma unroll
  for (int mh = 0; mh < 2; ++mh)
    #pragma unroll
    for (int nh = 0; nh < 2; ++nh)
      #pragma unroll
      for (int r = 0; r < 4; ++r) acc[mh][nh][r] = 0.f;

  for (int k0 = 0; k0 < 256; k0 += 64) {
    #pragma unroll
    for (int rep = 0; rep < 16; ++rep) {
      int flat = rep * 256 + t;
      int r = flat >> 6, k = flat & 63;
      As[r][k] = f2bu(A[(size_t)(m0 + r) * 256 + k0 + k]);
    }
    #pragma unroll
    for (int rep = 0; rep < 16; ++rep) {
      int flat = rep * 256 + t;
      int k = flat >> 6, n = flat & 63;
      Bs[n][k] = f2bu(W[(size_t)(k0 + k) * 256 + n0 + n]);
    }
    __syncthreads();
    #pragma unroll
    for (int ks = 0; ks < 2; ++ks) {
      const int kb = ks * 32 + l16 * 8;
      bf16x8 afr[2], bfr[2];
      #pragma unroll
      for (int mh = 0; mh < 2; ++mh)
        afr[mh] = *reinterpret_cast<const bf16x8*>(&As[wr * 32 + mh * 16 + l15][kb]);
      #pragma unroll
      for (int nh = 0; nh < 2; ++nh)
        bfr[nh] = *reinterpret_cast<const bf16x8*>(&Bs[wc * 32 + nh * 16 + l15][kb]);
      #pragma unroll
      for (int mh = 0; mh < 2; ++mh)
        #pragma unroll
        for (int nh = 0; nh < 2; ++nh)
          acc[mh][nh] = __builtin_amdgcn_mfma_f32_16x16x32_bf16(
              afr[mh], bfr[nh], acc[mh][nh], 0, 0, 0);
    }
    __syncthreads();
  }
  #pragma unroll
  for (int mh = 0; mh < 2; ++mh)
    #pragma unroll
    for (int nh = 0; nh < 2; ++nh)
      #pragma unroll
      for (int r = 0; r < 4; ++r) {
        const int row = m0 + wr * 32 + mh * 16 + l16 * 4 + r;
        const int col = n0 + wc * 32 + nh * 16 + l15;
        C[(size_t)row * 256 + col] = f2bu(acc[mh][nh][r]);
      }
}

// ---------------------------------------------------------------------------
// GCN aggregate / REConv / RKQ
// ---------------------------------------------------------------------------
__global__ __launch_bounds__(256) void agg_kernel(
    const int* __restrict__ offs, const int* __restrict__ csr,
    const float* __restrict__ X, const float* __restrict__ n_in,
    const float* __restrict__ bias, float* __restrict__ ghn)
{
  const int n = blockIdx.x, t = threadIdx.x;
  const int s0 = offs[n], s1 = offs[n + 1];
  float acc = 0.f;
  for (int i = s0; i < s1; ++i) acc += X[(size_t)csr[i] * 256 + t];
  ghn[(size_t)n * 256 + t] = fmaxf(fmaf(acc, n_in[n], bias[t]), 0.f);
}
__global__ __launch_bounds__(256) void re_proj(
    const float* __restrict__ R, const float* __restrict__ n_out,
    const float* __restrict__ Wre, const float* __restrict__ wtre,
    const int* __restrict__ nt, float* __restrict__ rtmp)
{
  int g = blockIdx.x * 256 + threadIdx.x;  // NN*4
  int n = g >> 2, j = g & 3;
  float s = 0.f;
  #pragma unroll
  for (int c = 0; c < 4; ++c) s += R[n * 4 + c] * Wre[c * 4 + j];
  rtmp[g] = s * n_out[n] * wtre[nt[n]];
}
__global__ __launch_bounds__(256) void re_agg(
    const int* __restrict__ offs, const int* __restrict__ csr,
    const float* __restrict__ rtmp, const float* __restrict__ n_in,
    const float* __restrict__ bre, float* __restrict__ Rn)
{
  int g = blockIdx.x * 256 + threadIdx.x;  // NN*4
  int n = g >> 2, j = g & 3;
  float a = 0.f;
  for (int i = offs[n]; i < offs[n + 1]; ++i) a += rtmp[csr[i] * 4 + j];
  Rn[g] = fmaxf(fmaf(a, n_in[n], bre[j]), 0.f);
}
__global__ __launch_bounds__(256) void rkq_kernel(
    const float* __restrict__ R, const float* __restrict__ Wrs,
    const float* __restrict__ Wrt, float* __restrict__ RKQ)
{
  int g = blockIdx.x * 256 + threadIdx.x;  // NN*128
  int n = g >> 7, c = g & 127;
  int which = c >> 5, cc = c & 31;
  const float* Wp = (which == 0) ? Wrs : (which == 1) ? Wrt
                   : (which == 2) ? (Wrs + 128) : (Wrt + 128);
  float s = 0.f;
  #pragma unroll
  for (int r = 0; r < 4; ++r) s += R[n * 4 + r] * Wp[r * 32 + cc];
  RKQ[g] = s;
}

// ---------------------------------------------------------------------------
// weight prep: vecs[0]=g1@Wr2, vecs[1]=b1@Wr2 (f32);
// Wg2T[col][k] = bf16(g1[k]*Wr2[k][col]); Wl2b = bf16(Wl2) (same layout)
// ---------------------------------------------------------------------------
__global__ __launch_bounds__(256) void vec4_kernel(
    const float* __restrict__ ln_g, const float* __restrict__ ln_b,
    const float* __restrict__ Wr2, float* __restrict__ vecs)
{
  const int which = blockIdx.x, t = threadIdx.x;
  const float* s = (which & 1) ? ln_b : ln_g;
  float a = 0.f;
  for (int k = 0; k < 256; ++k) a = fmaf(s[k], Wr2[(size_t)k * 256 + t], a);
  vecs[which * 256 + t] = a;
}
__global__ __launch_bounds__(256) void wg2t_kernel(
    const float* __restrict__ ln_g, const float* __restrict__ Wr2,
    const float* __restrict__ Wl2,
    ushortT* __restrict__ Wg2T, ushortT* __restrict__ Wl2b)
{
  const int c = blockIdx.x, t = threadIdx.x;
  Wg2T[(size_t)c * 256 + t] = f2bu(ln_g[t] * Wr2[(size_t)t * 256 + c]);
  Wl2b[(size_t)c * 256 + t] = f2bu(Wl2[(size_t)c * 256 + t]);
}
__global__ __launch_bounds__(256) void ghb_kernel(
    const float* __restrict__ gh, ushortT* __restrict__ ghb)
{
  int g = blockIdx.x * 256 + threadIdx.x;   // NN*256
  ghb[g] = f2bu(gh[g]);
}

// ---------------------------------------------------------------------------
// MEGA5: gathers minimized. x = P@GW + ghb (MFMA); y = x@Wg2T in-kernel MFMA
// (GW2/GHG tables gone); fl2 = h1row0@Wl2b direct (GWL/GHL gone).
// LDS: bufA = GT(GW^T) -> FR2 ; bufB = Pl -> xb. ~51 KB.
// ---------------------------------------------------------------------------
__global__ __launch_bounds__(256) void mega5_kernel(
    const int* __restrict__ seqs,
    const ushortT* __restrict__ ghb,
    const ushortT* __restrict__ GW,
    const float* __restrict__ SLg, const float* __restrict__ SRg,
    const float* __restrict__ RKQ,
    const float* __restrict__ vecs,           // v1,v2
    const ushortT* __restrict__ Wg2T,         // [col][k] bf16
    const ushortT* __restrict__ Wl2b,         // [k][col] bf16
    const float* __restrict__ al2, const float* __restrict__ ar2,
    const float* __restrict__ ln_g, const float* __restrict__ ln_b,
    float* __restrict__ h1r0buf, float* __restrict__ ctx2buf,
    float* __restrict__ out)
{
  __shared__ int idx[32];
  __shared__ alignas(16) ushortT bufA[10240];  // GT(GW^T, swz) -> FR2s[32][268]
  __shared__ alignas(16) ushortT bufB[10240];  // Pl[256][20u] swz -> xb[32][264]
  __shared__ float SRs[8][32];
  __shared__ float RQs[32][36];                // RQ1 then RQ2
  __shared__ float rk2s[32];
  __shared__ float part[32][4], partq[32][4];
  __shared__ float mu_s[32], rs_s[32];
  __shared__ float SR2s[8][32];
  __shared__ float sl2s[8];
  __shared__ float scp[8][32];
  __shared__ float h1r0s[256];
  __shared__ float wred4[4];
  __shared__ float nrm1s;

  const int b = blockIdx.x, t = threadIdx.x;
  const int h8 = t >> 5, lo = t & 31;
  const int w = t >> 6, l = t & 63;
  const int l15 = l & 15, l16 = l >> 4;

  if (t < 32) idx[t] = seqs[b * 32 + t];
  __syncthreads();                                             // B1

  const float sli = SLg[(size_t)idx[lo] * 8 + h8];
  const float rk0 = RKQ[(size_t)idx[lo] * 128 + h8 * 4 + 0];
  const float rk1 = RKQ[(size_t)idx[lo] * 128 + h8 * 4 + 1];
  const float rk2_ = RKQ[(size_t)idx[lo] * 128 + h8 * 4 + 2];
  const float rk3 = RKQ[(size_t)idx[lo] * 128 + h8 * 4 + 3];

  // ---- stage GT = GW^T (swizzled), SRs, RQ1, rk2s ----
  {
    const uintT* GWu = reinterpret_cast<const uintT*>(GW);
    #pragma unroll
    for (int rep = 0; rep < 16; ++rep) {
      int flat = rep * 256 + t;
      int j = flat >> 7, cp = flat & 127;
      const uintT u = GWu[(size_t)idx[j] * 128 + cp];
      const int rA = 2 * cp;
      const int k = (rA >> 3) & 3;
      const int off = (((j >> 3) ^ k) << 3) + (j & 7);
      bufA[rA * 40 + off]       = (ushortT)(u & 0xffffu);
      bufA[(rA + 1) * 40 + off] = (ushortT)(u >> 16);
    }
  }
  SRs[h8][lo] = SRg[(size_t)idx[lo] * 8 + h8];
  #pragma unroll
  for (int rep = 0; rep < 4; ++rep) {
    int flat = rep * 256 + t, s3 = flat >> 5, c3 = flat & 31;
    RQs[s3][c3] = RKQ[(size_t)idx[s3] * 128 + 32 + c3];
  }
  if (t < 32) rk2s[t] = RKQ[(size_t)idx[0] * 128 + 64 + t];
  __syncthreads();                                             // B2

  // ---- attn1 softmax -> Pl (swizzled bf16 into bufB) ----
  {
    float p1[32];
    float m = -1e30f;
    #pragma unroll
    for (int j = 0; j < 32; ++j) {
      float sc = sli + SRs[h8][j]
               + rk0 * RQs[j][h8 * 4 + 0] + rk1 * RQs[j][h8 * 4 + 1]
               + rk2_ * RQs[j][h8 * 4 + 2] + rk3 * RQs[j][h8 * 4 + 3];
      p1[j] = sc; m = fmaxf(m, sc);
    }
    float sum = 0.f;
    #pragma unroll
    for (int j = 0; j < 32; ++j) { p1[j] = __expf(p1[j] - m); sum += p1[j]; }
    const float inv = 1.f / sum;
    const int row = t;
    const int k = (row >> 3) & 3;
    uintT* pw = reinterpret_cast<uintT*>(bufB);
    #pragma unroll
    for (int q = 0; q < 16; ++q) {
      const int pu = row * 20 + (((q >> 2) ^ k) << 2) + (q & 3);
      pw[pu] = (uintT)f2bu(p1[2 * q] * inv) | ((uintT)f2bu(p1[2 * q + 1] * inv) << 16);
    }
  }
  __syncthreads();                                             // B3

  int irow[2][4];
  #pragma unroll
  for (int mh = 0; mh < 2; ++mh)
    #pragma unroll
    for (int r = 0; r < 4; ++r)
      irow[mh][r] = idx[mh * 16 + l16 * 4 + r];

  // A-fragments (P) cached in registers
  bf16x8 af[2][2];
  #pragma unroll
  for (int hh = 0; hh < 2; ++hh) {
    const int h = 2 * w + hh;
    #pragma unroll
    for (int mh = 0; mh < 2; ++mh) {
      const int row = h * 32 + mh * 16 + l15;
      const int k = (row >> 3) & 3;
      af[hh][mh] = *reinterpret_cast<const bf16x8*>(&bufB[row * 40 + ((l16 ^ k) << 3)]);
    }
  }

  // ---- x phase: MFMA + ghb residual + LN stats + h1row0 stash ----
  f32x4 acc[2][2][2];
  #pragma unroll
  for (int hh = 0; hh < 2; ++hh) {
    const int h = 2 * w + hh;
    bf16x8 bf[2];
    #pragma unroll
    for (int nh = 0; nh < 2; ++nh) {
      const int row = h * 32 + nh * 16 + l15;
      const int k = (row >> 3) & 3;
      bf[nh] = *reinterpret_cast<const bf16x8*>(&bufA[row * 40 + ((l16 ^ k) << 3)]);
    }
    #pragma unroll
    for (int mh = 0; mh < 2; ++mh)
      #pragma unroll
      for (int nh = 0; nh < 2; ++nh) {
        f32x4 z = {0.f, 0.f, 0.f, 0.f};
        acc[hh][mh][nh] = __builtin_amdgcn_mfma_f32_16x16x32_bf16(af[hh][mh], bf[nh], z, 0, 0, 0);
      }
  }
  {
    float sum_[2][4], sq_[2][4];
    #pragma unroll
    for (int mh = 0; mh < 2; ++mh)
      #pragma unroll
      for (int r = 0; r < 4; ++r) { sum_[mh][r] = 0.f; sq_[mh][r] = 0.f; }
    #pragma unroll
    for (int hh = 0; hh < 2; ++hh)
      #pragma unroll
      for (int mh = 0; mh < 2; ++mh)
        #pragma unroll
        for (int nh = 0; nh < 2; ++nh) {
          const int col = (2 * w + hh) * 32 + nh * 16 + l15;
          #pragma unroll
          for (int r = 0; r < 4; ++r) {
            float v = acc[hh][mh][nh][r] + b2f(ghb[(size_t)irow[mh][r] * 256 + col]);
            acc[hh][mh][nh][r] = v;
            sum_[mh][r] += v;
            sq_[mh][r] = fmaf(v, v, sq_[mh][r]);
          }
        }
    #pragma unroll
    for (int mh = 0; mh < 2; ++mh)
      #pragma unroll
      for (int r = 0; r < 4; ++r) {
        float s = sum_[mh][r], q = sq_[mh][r];
        #pragma unroll
        for (int m = 8; m >= 1; m >>= 1) {
          s += __shfl_xor(s, m, 64);
          q += __shfl_xor(q, m, 64);
        }
        if (l15 == 0) {
          part[mh * 16 + l16 * 4 + r][w]  = s;
          partq[mh * 16 + l16 * 4 + r][w] = q;
        }
      }
    if (l16 == 0) {
      #pragma unroll
      for (int hh = 0; hh < 2; ++hh)
        #pragma unroll
        for (int nh = 0; nh < 2; ++nh)
          h1r0s[(2 * w + hh) * 32 + nh * 16 + l15] = acc[hh][0][nh][0];
    }
  }
  __syncthreads();                                             // B4

  if (t < 32) {
    float sm = part[t][0] + part[t][1] + part[t][2] + part[t][3];
    float sq = partq[t][0] + partq[t][1] + partq[t][2] + partq[t][3];
    const float m = sm * (1.f / 256.f);
    const float v = fmaxf(sq * (1.f / 256.f) - m * m, 0.f);
    mu_s[t] = m;
    rs_s[t] = rsqrtf(v + LN_EPS);
  }
  __syncthreads();                                             // B5

  // ---- xb = bf16(x) into bufB (Pl dead); RQ2; h1row0 LN + ret1 partials ----
  #pragma unroll
  for (int hh = 0; hh < 2; ++hh)
    #pragma unroll
    for (int mh = 0; mh < 2; ++mh)
      #pragma unroll
      for (int nh = 0; nh < 2; ++nh) {
        const int col = (2 * w + hh) * 32 + nh * 16 + l15;
        #pragma unroll
        for (int r = 0; r < 4; ++r) {
          const int row = mh * 16 + l16 * 4 + r;
          bufB[row * 264 + col] = f2bu(acc[hh][mh][nh][r]);
        }
      }
  #pragma unroll
  for (int rep = 0; rep < 4; ++rep) {
    int flat = rep * 256 + t, s3 = flat >> 5, c3 = flat & 31;
    RQs[s3][c3] = RKQ[(size_t)idx[s3] * 128 + 96 + c3];
  }
  {
    const float mu0 = mu_s[0], rs0 = rs_s[0];
    float hv = fmaf((h1r0s[t] - mu0) * rs0, ln_g[t], ln_b[t]);
    h1r0buf[(size_t)b * 256 + t] = hv;
    float sq = red64(hv * hv);
    h1r0s[t] = hv;
    if ((t & 63) == 0) wred4[t >> 6] = sq;
  }
  __syncthreads();                                             // B6

  if (t == 0) nrm1s = 1.f / fmaxf(sqrtf(wred4[0] + wred4[1] + wred4[2] + wred4[3]), 1e-12f);

  // ---- y phase: y = x @ Wg2T (MFMA, K=256, B streamed from L2) ----
  {
    f32x4 acc2[2][4];   // [mh][cg]  (wave owns cols w*64 .. w*64+63)
    #pragma unroll
    for (int mh = 0; mh < 2; ++mh)
      #pragma unroll
      for (int cg = 0; cg < 4; ++cg)
        #pragma unroll
        for (int r = 0; r < 4; ++r) acc2[mh][cg][r] = 0.f;
    #pragma unroll
    for (int ks = 0; ks < 8; ++ks) {
      const int ko = ks * 32 + l16 * 8;
      bf16x8 a2[2];
      #pragma unroll
      for (int mh = 0; mh < 2; ++mh)
        a2[mh] = *reinterpret_cast<const bf16x8*>(&bufB[(mh * 16 + l15) * 264 + ko]);
      #pragma unroll
      for (int cg = 0; cg < 4; ++cg) {
        const int col = w * 64 + cg * 16 + l15;
        bf16x8 b2 = *reinterpret_cast<const bf16x8*>(&Wg2T[(size_t)col * 256 + ko]);
        #pragma unroll
        for (int mh = 0; mh < 2; ++mh)
          acc2[mh][cg] = __builtin_amdgcn_mfma_f32_16x16x32_bf16(a2[mh], b2, acc2[mh][cg], 0, 0, 0);
      }
    }
    // epilogue: FR2 + SR2
    float rsv[2][4], rmv[2][4];
    #pragma unroll
    for (int mh = 0; mh < 2; ++mh)
      #pragma unroll
      for (int r = 0; r < 4; ++r) {
        const int row = mh * 16 + l16 * 4 + r;
        rsv[mh][r] = rs_s[row];
        rmv[mh][r] = rsv[mh][r] * mu_s[row];
      }
    float sacc[2][2][4];   // [head-half][mh][r]
    #pragma unroll
    for (int hh = 0; hh < 2; ++hh)
      #pragma unroll
      for (int mh = 0; mh < 2; ++mh)
        #pragma unroll
        for (int r = 0; r < 4; ++r) sacc[hh][mh][r] = 0.f;
    float ar2v[2] = { ar2[l15], ar2[16 + l15] };
    #pragma unroll
    for (int cg = 0; cg < 4; ++cg) {
      const int col = w * 64 + cg * 16 + l15;
      const float v1c = vecs[col], v2c = vecs[256 + col];
      const int hh = cg >> 1;
      #pragma unroll
      for (int mh = 0; mh < 2; ++mh)
        #pragma unroll
        for (int r = 0; r < 4; ++r) {
          const int row = mh * 16 + l16 * 4 + r;
          float fa = fmaf(rsv[mh][r], acc2[mh][cg][r], fmaf(-rmv[mh][r], v1c, v2c));
          bufA[row * 268 + col] = f2bu(fa);       // FR2s[row][col]
          float lr = fa > 0.f ? fa : SLOPE * fa;
          sacc[hh][mh][r] = fmaf(lr, ar2v[cg & 1], sacc[hh][mh][r]);
        }
    }
    #pragma unroll
    for (int hh = 0; hh < 2; ++hh)
      #pragma unroll
      for (int mh = 0; mh < 2; ++mh)
        #pragma unroll
        for (int r = 0; r < 4; ++r) {
          float s = sacc[hh][mh][r];
          #pragma unroll
          for (int m = 8; m >= 1; m >>= 1) s += __shfl_xor(s, m, 64);
          if (l15 == 0) SR2s[2 * w + hh][mh * 16 + l16 * 4 + r] = s;
        }
  }
  // ---- fl2 = h1row0 @ Wl2 (direct, L2-resident bf16) -> sl2 ----
  {
    float fl = 0.f;
    #pragma unroll 8
    for (int k = 0; k < 256; ++k)
      fl = fmaf(h1r0s[k], b2f(Wl2b[(size_t)k * 256 + t]), fl);
    float lr = (fl > 0.f ? fl : SLOPE * fl) * al2[lo];
    lr = red32(lr);
    if (lo == 0) sl2s[h8] = lr;
  }
  __syncthreads();                                             // B7

  // ---- attn2 row0 scores ----
  {
    float s2 = sl2s[h8] + SR2s[h8][lo]
             + rk2s[h8 * 4 + 0] * RQs[lo][h8 * 4 + 0]
             + rk2s[h8 * 4 + 1] * RQs[lo][h8 * 4 + 1]
             + rk2s[h8 * 4 + 2] * RQs[lo][h8 * 4 + 2]
             + rk2s[h8 * 4 + 3] * RQs[lo][h8 * 4 + 3];
    const float m2 = max32(s2);
    const float e = __expf(s2 - m2);
    const float su = red32(e);
    scp[h8][lo] = e / su;
  }
  __syncthreads();                                             // B8

  // ---- ctx2 = p2 ◦ FR2 ; ret1 write ----
  {
    float a = 0.f;
    #pragma unroll
    for (int j = 0; j < 32; ++j) a = fmaf(scp[h8][j], b2f(bufA[j * 268 + t]), a);
    ctx2buf[(size_t)b * 256 + t] = a;
  }
  out[(size_t)b * 768 + 256 + t] = h1r0s[t] * nrm1s;
}

// ---------------------------------------------------------------------------
// Epilogue: ret2 = l2n(LN(h1row0 + ctx2 @ Wfin2))  — 64 rows/block
// ---------------------------------------------------------------------------
__global__ __launch_bounds__(256) void final_ln_kernel(
    const float* __restrict__ A,
    const float* __restrict__ W,
    const float* __restrict__ res,
    const float* __restrict__ lng, const float* __restrict__ lnb,
    float* __restrict__ out)
{
  const int m0 = blockIdx.x * 64;
  const int t  = threadIdx.x;
  const int tr = t & 15, tc = t >> 4;
  __shared__ alignas(16) float As[32][68];
  __shared__ alignas(16) float Bs[32][264];
  __shared__ float red[64][16];
  __shared__ float stat[64];
  float acc[4][16] = {};

  for (int ks = 0; ks < 8; ++ks) {
    const int k0 = ks * 32;
    #pragma unroll
    for (int rep = 0; rep < 8; ++rep) {
      int flat = rep * 256 + t;
      int r = flat >> 5, c = flat & 31;
      As[c][r] = A[(size_t)(m0 + r) * 256 + (k0 + c)];
    }
    #pragma unroll
    for (int rep = 0; rep < 32; ++rep) {
      int flat = rep * 256 + t;
      int rb = flat >> 8, cb = flat & 255;
      Bs[rb][cb] = W[(size_t)(k0 + rb) * 256 + cb];
    }
    __syncthreads();
    #pragma unroll
    for (int k = 0; k < 32; ++k) {
      const float4 a4 = *reinterpret_cast<const float4*>(&As[k][tr * 4]);
      const float av[4] = {a4.x, a4.y, a4.z, a4.w};
      #pragma unroll
      for (int q = 0; q < 4; ++q) {
        const float4 b4 = *reinterpret_cast<const float4*>(&Bs[k][tc * 16 + q * 4]);
        const float bv[4] = {b4.x, b4.y, b4.z, b4.w};
        #pragma unroll
        for (int u = 0; u < 4; ++u)
          #pragma unroll
          for (int v = 0; v < 4; ++v)
            acc[u][q * 4 + v] = fmaf(av[u], bv[v], acc[u][q * 4 + v]);
      }
    }
    __syncthreads();
  }

  int rows[4];
  #pragma unroll
  for (int u = 0; u < 4; ++u) rows[u] = m0 + tr * 4 + u;

  #pragma unroll
  for (int u = 0; u < 4; ++u) {
    const float* rp = &res[(size_t)rows[u] * 256 + tc * 16];
    #pragma unroll
    for (int v = 0; v < 16; ++v) acc[u][v] += rp[v];
  }
  #pragma unroll
  for (int u = 0; u < 4; ++u) {
    float s = 0.f;
    #pragma unroll
    for (int v = 0; v < 16; ++v) s += acc[u][v];
    red[tr * 4 + u][tc] = s;
  }
  __syncthreads();
  if (t < 64) {
    float s = 0.f;
    #pragma unroll
    for (int g = 0; g < 16; ++g) s += red[t][g];
    stat[t] = s * (1.0f / 256.0f);
  }
  __syncthreads();
  float mu[4];
  #pragma unroll
  for (int u = 0; u < 4; ++u) mu[u] = stat[tr * 4 + u];
  #pragma unroll
  for (int u = 0; u < 4; ++u) {
    float s = 0.f;
    #pragma unroll
    for (int v = 0; v < 16; ++v) { float d = acc[u][v] - mu[u]; s += d * d; }
    red[tr * 4 + u][tc] = s;
  }
  __syncthreads();
  if (t < 64) {
    float s = 0.f;
    #pragma unroll
    for (int g = 0; g < 16; ++g) s += red[t][g];
    stat[t] = rsqrtf(s * (1.0f / 256.0f) + LN_EPS);
  }
  __syncthreads();
  float rst[4];
  #pragma unroll
  for (int u = 0; u < 4; ++u) rst[u] = stat[tr * 4 + u];
  #pragma unroll
  for (int u = 0; u < 4; ++u) {
    float s = 0.f;
    #pragma unroll
    for (int v = 0; v < 16; ++v) {
      int col = tc * 16 + v;
      float yv = fmaf((acc[u][v] - mu[u]) * rst[u], lng[col], lnb[col]);
      acc[u][v] = yv;
      s += yv * yv;
    }
    red[tr * 4 + u][tc] = s;
  }
  __syncthreads();
  if (t < 64) {
    float s = 0.f;
    #pragma unroll
    for (int g = 0; g < 16; ++g) s += red[t][g];
    stat[t] = 1.0f / fmaxf(sqrtf(s), 1e-12f);
  }
  __syncthreads();
  #pragma unroll
  for (int u = 0; u < 4; ++u) {
    float rn = stat[tr * 4 + u];
    #pragma unroll
    for (int v = 0; v < 16; ++v)
      out[(size_t)rows[u] * 768 + 512 + tc * 16 + v] = acc[u][v] * rn;
  }
}

// ---------------------------------------------------------------------------
extern "C" void kernel_launch(void* const* d_in, const int* in_sizes, int n_in,
                              void* d_out, int out_size, void* d_ws, size_t ws_size,
                              hipStream_t stream)
{
  (void)in_sizes; (void)n_in; (void)out_size; (void)ws_size;

  const float* feat[4]; const float* wfc[4]; const float* bfc[4];
  for (int i = 0; i < 4; ++i) {
    feat[i] = (const float*)d_in[i * 3 + 0];
    wfc[i]  = (const float*)d_in[i * 3 + 1];
    bfc[i]  = (const float*)d_in[i * 3 + 2];
  }
  const float* type_emb = (const float*)d_in[12];
  const float* Wgcn = (const float*)d_in[13];
  const float* bgcn = (const float*)d_in[14];
  const float* Wre  = (const float*)d_in[15];
  const float* bre  = (const float*)d_in[16];
  const float* wtre = (const float*)d_in[17];
  const float* Wl   = (const float*)d_in[18];
  const float* Wr   = (const float*)d_in[19];
  const float* al   = (const float*)d_in[20];
  const float* ar   = (const float*)d_in[21];
  const float* Wrs  = (const float*)d_in[22];
  const float* Wrt  = (const float*)d_in[23];
  const float* Wfin = (const float*)d_in[24];
  const float* ln_g = (const float*)d_in[25];
  const float* ln_b = (const float*)d_in[26];
  const int* src       = (const int*)d_in[27];
  const int* dst       = (const int*)d_in[28];
  const int* node_type = (const int*)d_in[29];
  const int* seqs      = (const int*)d_in[30];
  float* out = (float*)d_out;

  // workspace carve-up (~45 MB)
  char* p = (char*)d_ws;
  auto take = [&](size_t n) { char* q = p; p += (n + 255) & ~(size_t)255; return q; };
  float* gh    = (float*)take((size_t)NN * 256 * 4);
  float* Xbuf  = (float*)take((size_t)NN * 256 * 4);   // GCN scratch, then ctx2buf
  float* GR1   = (float*)take((size_t)NN * 256 * 4);   // gh@Wr1, then h1r0buf
  float* RKQ   = (float*)take((size_t)NN * 128 * 4);
  float* SLg   = (float*)take((size_t)NN * 8 * 4);
  float* SRg   = (float*)take((size_t)NN * 8 * 4);
  float* n_out = (float*)take((size_t)NN * 4);
  float* n_in_ = (float*)take((size_t)NN * 4);
  int*   outc  = (int*)take((size_t)NN * 4);
  int*   inc   = (int*)take((size_t)NN * 4);
  int*   offs  = (int*)take((size_t)(NN + 1) * 4);
  int*   cur   = (int*)take((size_t)NN * 4);
  int*   csr   = (int*)take((size_t)(EE + NN) * 4);
  float* R     = (float*)take((size_t)NN * 4 * 4);
  float* rtmp  = (float*)take((size_t)NN * 4 * 4);
  ushortT* GW   = (ushortT*)take((size_t)NN * 256 * 2);
  ushortT* ghb  = (ushortT*)take((size_t)NN * 256 * 2);
  ushortT* Wg2T = (ushortT*)take((size_t)65536 * 2);
  ushortT* Wl2b = (ushortT*)take((size_t)65536 * 2);
  float* vecs  = (float*)take((size_t)2 * 256 * 4);
  float* ctx2buf = Xbuf;   // alias: Xbuf dead after GCN
  float* h1r0buf = GR1;    // alias: GR1 dead after mfma_tab

  const float* Wr2 = Wr + 65536;
  const float* Wl2 = Wl + 65536;

  // 1) FC + ret0
  fc_kernel<<<256, 256, 0, stream>>>(feat[0], feat[1], feat[2], feat[3],
                                     wfc[0], wfc[1], wfc[2], wfc[3],
                                     bfc[0], bfc[1], bfc[2], bfc[3], gh, out);
  // 2) degrees + CSR
  zero_counts<<<64, 256, 0, stream>>>(outc, inc);
  count_deg<<<512, 256, 0, stream>>>(src, dst, outc, inc);
  norm_kernel<<<32, 256, 0, stream>>>(outc, inc, n_out, n_in_);
  scan_kernel<<<1, 1024, 0, stream>>>(inc, offs);
  copy_cur<<<32, 256, 0, stream>>>(offs, cur);
  fill_csr<<<544, 256, 0, stream>>>(src, dst, cur, csr);
  init_R<<<128, 256, 0, stream>>>(type_emb, node_type, R);

  // weight prep
  vec4_kernel<<<2, 256, 0, stream>>>(ln_g, ln_b, Wr2, vecs);
  wg2t_kernel<<<256, 256, 0, stream>>>(ln_g, Wr2, Wl2, Wg2T, Wl2b);

  // 3) GCN + REConv, K=2
  for (int k = 0; k < 2; ++k) {
    gemm64_kernel<true, true, false, float>
        <<<dim3(128, 4), 256, 0, stream>>>(gh, Wgcn + (size_t)k * 65536,
                                           n_out, Xbuf, nullptr, nullptr);
    agg_kernel<<<NN, 256, 0, stream>>>(offs, csr, Xbuf, n_in_, bgcn + k * 256, gh);
    re_proj<<<128, 256, 0, stream>>>(R, n_out, Wre + k * 16, wtre + k * 4, node_type, rtmp);
    re_agg<<<128, 256, 0, stream>>>(offs, csr, rtmp, n_in_, bre + k * 4, R);
  }

  // 4) attention precomputes + GW table + bf16 gh
  rkq_kernel<<<4096, 256, 0, stream>>>(R, Wrs, Wrt, RKQ);
  gemm64_kernel<false, false, true, float>
      <<<dim3(128, 4), 256, 0, stream>>>(gh, Wl, nullptr, (float*)nullptr, al, SLg);
  gemm64_kernel<false, true, true, float>
      <<<dim3(128, 4), 256, 0, stream>>>(gh, Wr, nullptr, GR1, ar, SRg);
  mfma_tab_kernel<<<dim3(128, 4), 256, 0, stream>>>(GR1, Wfin, GW);
  ghb_kernel<<<NN, 256, 0, stream>>>(gh, ghb);

  // 5) fused transformer (in-kernel y-GEMM, direct fl2) -> ret1, h1r0, ctx2
  mega5_kernel<<<NN, 256, 0, stream>>>(seqs, ghb, GW, SLg, SRg, RKQ, vecs,
                                       Wg2T, Wl2b,
                                       al + 32, ar + 32, ln_g, ln_b,
                                       h1r0buf, ctx2buf, out);

  // 6) epilogue: ret2 = l2n(LN(h1r0 + ctx2@Wfin2))
  final_ln_kernel<<<128, 256, 0, stream>>>(ctx2buf, Wfin + 65536, h1r0buf,
                                           ln_g + 256, ln_b + 256, out);
}